// Round 1
// baseline (6356.618 us; speedup 1.0000x reference)
//
#include <hip/hip_runtime.h>
#include <math.h>
#include <float.h>

// DGCNN forward, MI355X. All f32. Workspace budget ~140MB.
// Decomposition: h_edge = (W1-W2)@x_i + W2@x_j  => u + v[idx] (9x less GEMM work).

#define LEAKY(y) ((y) >= 0.f ? (y) : 0.2f * (y))

// ---------------------------------------------------------------- kNN -------
template<int C>
__global__ __launch_bounds__(256) void knn_kernel(const float* __restrict__ xin,
                                                  long bstride, int N,
                                                  int* __restrict__ idx_out) {
  __shared__ float rowF[C][64];
  __shared__ float colF[C][64];
  __shared__ float xxr[64];
  __shared__ float xxc[64];
  __shared__ float dtile[64][68];
  __shared__ float mergeD[64][37];
  __shared__ int   mergeI[64][37];

  const int tid  = threadIdx.x;
  const int b    = blockIdx.y;
  const int row0 = blockIdx.x * 64;
  const float* xb = xin + (long)b * bstride;

  for (int i = tid; i < C * 64; i += 256) {
    int c = i >> 6, j = i & 63;
    rowF[c][j] = xb[(long)c * N + row0 + j];
  }
  __syncthreads();
  if (tid < 64) {
    float s = 0.f;
    for (int c = 0; c < C; ++c) { float t = rowF[c][tid]; s += t * t; }
    xxr[tid] = s;
  }

  float td[9]; int ti[9];
  #pragma unroll
  for (int s = 0; s < 9; ++s) { td[s] = 3.0e38f; ti[s] = 0x7fffffff; }

  const int tr = tid >> 4, tc = tid & 15;   // gemm mapping: rows 4tr.., cols 4tc..
  const int rsel = tid >> 2, q = tid & 3;   // selection mapping: 4 threads per row

  const int ntiles = N >> 6;
  for (int ct = 0; ct < ntiles; ++ct) {
    const int c0 = ct * 64;
    __syncthreads();  // prev selection done (dtile free), xxr ready on iter 0
    for (int i = tid; i < C * 64; i += 256) {
      int c = i >> 6, j = i & 63;
      colF[c][j] = xb[(long)c * N + c0 + j];
    }
    __syncthreads();
    if (tid < 64) {
      float s = 0.f;
      for (int c = 0; c < C; ++c) { float t = colF[c][tid]; s += t * t; }
      xxc[tid] = s;
    }
    __syncthreads();

    float acc[4][4];
    #pragma unroll
    for (int i = 0; i < 4; ++i)
      #pragma unroll
      for (int j = 0; j < 4; ++j) acc[i][j] = 0.f;

    for (int c = 0; c < C; ++c) {
      float4 a4 = *reinterpret_cast<const float4*>(&rowF[c][4 * tr]);
      float4 b4 = *reinterpret_cast<const float4*>(&colF[c][4 * tc]);
      float av[4] = {a4.x, a4.y, a4.z, a4.w};
      float bv[4] = {b4.x, b4.y, b4.z, b4.w};
      #pragma unroll
      for (int i = 0; i < 4; ++i)
        #pragma unroll
        for (int j = 0; j < 4; ++j) acc[i][j] = fmaf(av[i], bv[j], acc[i][j]);
    }
    #pragma unroll
    for (int i = 0; i < 4; ++i) {
      int r = 4 * tr + i;
      float xr = xxr[r];
      #pragma unroll
      for (int j = 0; j < 4; ++j) {
        int cl = 4 * tc + j;
        float d = (xr - 2.0f * acc[i][j]) + xxc[cl];  // ref rounding order
        if (row0 + r == c0 + cl) d = 3.0e38f;         // self-mask
        dtile[r][cl] = d;
      }
    }
    __syncthreads();
    // top-9 maintenance, static-index insertion (keep register-resident)
    #pragma unroll
    for (int t = 0; t < 16; ++t) {
      int cl = q * 16 + t;
      float d = dtile[rsel][cl];
      int gi = c0 + cl;
      if (d < td[8] || (d == td[8] && gi < ti[8])) {
        td[8] = d; ti[8] = gi;
        #pragma unroll
        for (int s = 8; s > 0; --s) {
          bool sw = (td[s] < td[s - 1]) || (td[s] == td[s - 1] && ti[s] < ti[s - 1]);
          if (sw) {
            float tf = td[s]; td[s] = td[s - 1]; td[s - 1] = tf;
            int tn = ti[s]; ti[s] = ti[s - 1]; ti[s - 1] = tn;
          }
        }
      }
    }
  }

  __syncthreads();
  #pragma unroll
  for (int s = 0; s < 9; ++s) {
    mergeD[rsel][q * 9 + s] = td[s];
    mergeI[rsel][q * 9 + s] = ti[s];
  }
  __syncthreads();
  if (tid < 64) {
    const int row = tid;
    const long ob = ((long)b * N + row0 + row) * 9;
    for (int s = 0; s < 9; ++s) {
      float bd = mergeD[row][0]; int bi = mergeI[row][0]; int bp = 0;
      for (int t = 1; t < 36; ++t) {
        float dd = mergeD[row][t]; int ii = mergeI[row][t];
        if (dd < bd || (dd == bd && ii < bi)) { bd = dd; bi = ii; bp = t; }
      }
      idx_out[ob + s] = bi;
      mergeD[row][bp] = 3.2e38f;
    }
  }
}

// --------------------------------------------------- small GEMM: out(B,N,O) --
// out[b][n][o] = sum_c W[o*wstride + c] * in[b*in_bstride + c*N + n]
__global__ __launch_bounds__(256) void gemm_cn_no(const float* __restrict__ W, int wstride,
                                                  int C, int O,
                                                  const float* __restrict__ in,
                                                  long in_bstride, int N,
                                                  float* __restrict__ out) {
  const int tid = threadIdx.x;
  const int n0 = blockIdx.x * 64, o0 = blockIdx.y * 64, b = blockIdx.z;
  __shared__ float wT[128][64];   // [c][o]
  __shared__ float inT[128][64];  // [c][n]
  for (int i = tid; i < C * 64; i += 256) {
    int c = i >> 6, j = i & 63;
    wT[c][j]  = W[(long)(o0 + j) * wstride + c];
    inT[c][j] = in[(long)b * in_bstride + (long)c * N + n0 + j];
  }
  __syncthreads();
  const int tr = tid >> 4, tc = tid & 15;
  float acc[4][4];
  #pragma unroll
  for (int i = 0; i < 4; ++i)
    #pragma unroll
    for (int j = 0; j < 4; ++j) acc[i][j] = 0.f;
  for (int c = 0; c < C; ++c) {
    float4 a4 = *reinterpret_cast<const float4*>(&wT[c][4 * tr]);
    float4 b4 = *reinterpret_cast<const float4*>(&inT[c][4 * tc]);
    float av[4] = {a4.x, a4.y, a4.z, a4.w};
    float bv[4] = {b4.x, b4.y, b4.z, b4.w};
    #pragma unroll
    for (int i = 0; i < 4; ++i)
      #pragma unroll
      for (int j = 0; j < 4; ++j) acc[i][j] = fmaf(av[i], bv[j], acc[i][j]);
  }
  #pragma unroll
  for (int j = 0; j < 4; ++j) {
    float4 st = make_float4(acc[0][j], acc[1][j], acc[2][j], acc[3][j]);
    *reinterpret_cast<float4*>(&out[((long)b * N + n0 + 4 * tc + j) * O + o0 + 4 * tr]) = st;
  }
}

// A = W[:, :C] - W[:, C:2C]
__global__ void prep_A(const float* __restrict__ W, int Cin, int O, float* __restrict__ A) {
  int i = blockIdx.x * 256 + threadIdx.x;
  if (i < O * Cin) {
    int o = i / Cin, c = i - o * Cin;
    A[i] = W[(long)o * 2 * Cin + c] - W[(long)o * 2 * Cin + Cin + c];
  }
}

// ------------------------------------------- edge conv stats / finalize -----
__global__ __launch_bounds__(256) void edge_stats(const float* __restrict__ u,
                                                  const float* __restrict__ v,
                                                  const int* __restrict__ idx, int O, int N,
                                                  double* __restrict__ S1,
                                                  double* __restrict__ S2) {
  const int tid = threadIdx.x;
  const int b = blockIdx.y, n0 = blockIdx.x * 64;
  __shared__ int sidx[64][9];
  __shared__ float red1[4][64];
  __shared__ float red2[4][64];
  for (int i = tid; i < 576; i += 256) sidx[i / 9][i % 9] = idx[((long)b * N + n0 + i / 9) * 9 + i % 9];
  __syncthreads();
  const int ol = tid & 63, nl = tid >> 6;
  const long base = (long)b * N;
  for (int oc = 0; oc < O; oc += 64) {
    int o = oc + ol;
    float s1 = 0.f, s2 = 0.f;
    for (int ng = 0; ng < 16; ++ng) {
      int n = ng * 4 + nl;
      float uu = u[(base + n0 + n) * O + o];
      #pragma unroll
      for (int kk = 0; kk < 9; ++kk) {
        int m = sidx[n][kk];
        float h = uu + v[(base + m) * O + o];
        s1 += h; s2 += h * h;
      }
    }
    red1[nl][ol] = s1; red2[nl][ol] = s2;
    __syncthreads();
    if (nl == 0) {
      float t1 = red1[0][ol] + red1[1][ol] + red1[2][ol] + red1[3][ol];
      float t2 = red2[0][ol] + red2[1][ol] + red2[2][ol] + red2[3][ol];
      atomicAdd(&S1[o], (double)t1);
      atomicAdd(&S2[o], (double)t2);
    }
    __syncthreads();
  }
}

__global__ void finalize_scale(const double* __restrict__ S1, const double* __restrict__ S2,
                               const float* __restrict__ g, const float* __restrict__ beta,
                               double invM, int O, float* __restrict__ scale,
                               float* __restrict__ shift) {
  int o = blockIdx.x * 256 + threadIdx.x;
  if (o < O) {
    double mean = S1[o] * invM;
    double var = S2[o] * invM - mean * mean;
    double sc = (double)g[o] / sqrt(var + 1e-5);
    scale[o] = (float)sc;
    shift[o] = (float)((double)beta[o] - mean * sc);
  }
}

__global__ __launch_bounds__(256) void edge_final(const float* __restrict__ u,
                                                  const float* __restrict__ v,
                                                  const int* __restrict__ idx,
                                                  const float* __restrict__ scale,
                                                  const float* __restrict__ shift,
                                                  int O, int N, float* __restrict__ outp,
                                                  long out_bstride) {
  const int tid = threadIdx.x;
  const int b = blockIdx.y, n0 = blockIdx.x * 64;
  __shared__ int sidx[64][9];
  __shared__ float ytile[64][65];
  for (int i = tid; i < 576; i += 256) sidx[i / 9][i % 9] = idx[((long)b * N + n0 + i / 9) * 9 + i % 9];
  const int ol = tid & 63, nl = tid >> 6;
  const long base = (long)b * N;
  for (int oc = 0; oc < O; oc += 64) {
    int o = oc + ol;
    float sc = scale[o], sh = shift[o];
    __syncthreads();  // sidx ready (iter0) / ytile consumed (later iters)
    for (int ng = 0; ng < 16; ++ng) {
      int n = ng * 4 + nl;
      float uu = u[(base + n0 + n) * O + o];
      float ymax = -3.0e38f;
      #pragma unroll
      for (int kk = 0; kk < 9; ++kk) {
        int m = sidx[n][kk];
        float h = uu + v[(base + m) * O + o];
        float y = sc * h + sh;
        y = LEAKY(y);
        ymax = fmaxf(ymax, y);
      }
      ytile[ol][n] = ymax;
    }
    __syncthreads();
    for (int rr = 0; rr < 16; ++rr) {
      int r = rr * 4 + nl;
      outp[(long)b * out_bstride + (long)(oc + r) * N + n0 + ol] = ytile[r][ol];
    }
  }
}

// ------------------------------------------------------- fusion 512->1024 ---
__global__ __launch_bounds__(256) void fusion_stats(const float* __restrict__ wf,
                                                    const float* __restrict__ bfb,
                                                    const float* __restrict__ feat, int N,
                                                    double* __restrict__ S1,
                                                    double* __restrict__ S2) {
  const int tid = threadIdx.x;
  const int n0 = blockIdx.x * 64, o0 = blockIdx.y * 64, b = blockIdx.z;
  __shared__ float wT[64][64];
  __shared__ float fT[64][64];
  const int tr = tid >> 4, tc = tid & 15;
  float acc[4][4];
  #pragma unroll
  for (int i = 0; i < 4; ++i)
    #pragma unroll
    for (int j = 0; j < 4; ++j) acc[i][j] = 0.f;
  for (int cc = 0; cc < 8; ++cc) {
    __syncthreads();
    for (int i = tid; i < 4096; i += 256) {
      int ci = i >> 6, j = i & 63;
      wT[ci][j] = wf[(long)(o0 + j) * 512 + cc * 64 + ci];
      fT[ci][j] = feat[((long)b * 512 + cc * 64 + ci) * N + n0 + j];
    }
    __syncthreads();
    #pragma unroll
    for (int ci = 0; ci < 64; ++ci) {
      float4 a4 = *reinterpret_cast<const float4*>(&wT[ci][4 * tr]);
      float4 b4 = *reinterpret_cast<const float4*>(&fT[ci][4 * tc]);
      float av[4] = {a4.x, a4.y, a4.z, a4.w};
      float bv[4] = {b4.x, b4.y, b4.z, b4.w};
      #pragma unroll
      for (int i = 0; i < 4; ++i)
        #pragma unroll
        for (int j = 0; j < 4; ++j) acc[i][j] = fmaf(av[i], bv[j], acc[i][j]);
    }
  }
  #pragma unroll
  for (int i = 0; i < 4; ++i) {
    int o = o0 + 4 * tr + i;
    float bias = bfb[o];
    float s1 = 0.f, s2 = 0.f;
    #pragma unroll
    for (int j = 0; j < 4; ++j) { float h = acc[i][j] + bias; s1 += h; s2 += h * h; }
    for (int off = 1; off < 16; off <<= 1) {
      s1 += __shfl_xor(s1, off, 16);
      s2 += __shfl_xor(s2, off, 16);
    }
    if (tc == 0) { atomicAdd(&S1[o], (double)s1); atomicAdd(&S2[o], (double)s2); }
  }
}

__global__ __launch_bounds__(256) void fusion_pool(const float* __restrict__ wf,
                                                   const float* __restrict__ bfb,
                                                   const float* __restrict__ feat, int N,
                                                   const float* __restrict__ scale,
                                                   const float* __restrict__ shift,
                                                   float* __restrict__ pmax,
                                                   float* __restrict__ psum) {
  const int tid = threadIdx.x;
  const int n0 = blockIdx.x * 64, o0 = blockIdx.y * 64, b = blockIdx.z;
  __shared__ float wT[64][64];
  __shared__ float fT[64][64];
  const int tr = tid >> 4, tc = tid & 15;
  float acc[4][4];
  #pragma unroll
  for (int i = 0; i < 4; ++i)
    #pragma unroll
    for (int j = 0; j < 4; ++j) acc[i][j] = 0.f;
  for (int cc = 0; cc < 8; ++cc) {
    __syncthreads();
    for (int i = tid; i < 4096; i += 256) {
      int ci = i >> 6, j = i & 63;
      wT[ci][j] = wf[(long)(o0 + j) * 512 + cc * 64 + ci];
      fT[ci][j] = feat[((long)b * 512 + cc * 64 + ci) * N + n0 + j];
    }
    __syncthreads();
    #pragma unroll
    for (int ci = 0; ci < 64; ++ci) {
      float4 a4 = *reinterpret_cast<const float4*>(&wT[ci][4 * tr]);
      float4 b4 = *reinterpret_cast<const float4*>(&fT[ci][4 * tc]);
      float av[4] = {a4.x, a4.y, a4.z, a4.w};
      float bv[4] = {b4.x, b4.y, b4.z, b4.w};
      #pragma unroll
      for (int i = 0; i < 4; ++i)
        #pragma unroll
        for (int j = 0; j < 4; ++j) acc[i][j] = fmaf(av[i], bv[j], acc[i][j]);
    }
  }
  #pragma unroll
  for (int i = 0; i < 4; ++i) {
    int o = o0 + 4 * tr + i;
    float bias = bfb[o], sc = scale[o], sh = shift[o];
    float mx = -3.0e38f, sm = 0.f;
    #pragma unroll
    for (int j = 0; j < 4; ++j) {
      float h = acc[i][j] + bias;
      float y = sc * h + sh;
      y = LEAKY(y);
      mx = fmaxf(mx, y); sm += y;
    }
    for (int off = 1; off < 16; off <<= 1) {
      mx = fmaxf(mx, __shfl_xor(mx, off, 16));
      sm += __shfl_xor(sm, off, 16);
    }
    if (tc == 0) {
      pmax[((long)b * 1024 + o) * 64 + blockIdx.x] = mx;
      psum[((long)b * 1024 + o) * 64 + blockIdx.x] = sm;
    }
  }
}

__global__ void pool_reduce(const float* __restrict__ pmax, const float* __restrict__ psum,
                            float* __restrict__ x1x2, float invN) {
  int id = blockIdx.x * 256 + threadIdx.x;
  if (id < 8 * 1024) {
    int b = id >> 10, o = id & 1023;
    float mx = -3.0e38f, sm = 0.f;
    for (int t = 0; t < 64; ++t) {
      mx = fmaxf(mx, pmax[(long)id * 64 + t]);
      sm += psum[(long)id * 64 + t];
    }
    x1x2[(long)b * 2048 + o] = mx;
    x1x2[(long)b * 2048 + 1024 + o] = sm * invN;
  }
}

// ----------------------------------------------------------- classifier -----
__global__ __launch_bounds__(256) void fc_kernel(const float* __restrict__ in, int Cin, int O,
                                                 const float* __restrict__ W,
                                                 const float* __restrict__ bias,
                                                 const float* __restrict__ g,
                                                 const float* __restrict__ beta,
                                                 float* __restrict__ outp, int do_bn) {
  const int tid = threadIdx.x;
  const int o = blockIdx.x * 32 + (tid >> 3);
  const int bb = tid & 7;
  const int oc = (o < O) ? o : (O - 1);
  const float* ir = in + (long)bb * Cin;
  const float* wr = W + (long)oc * Cin;
  float dot = 0.f;
  for (int c = 0; c < Cin; c += 4) {
    float4 a = *reinterpret_cast<const float4*>(&ir[c]);
    float4 w = *reinterpret_cast<const float4*>(&wr[c]);
    dot += a.x * w.x + a.y * w.y + a.z * w.z + a.w * w.w;
  }
  float h = dot + bias[oc];
  if (do_bn) {
    float s = h;
    s += __shfl_xor(s, 1, 8); s += __shfl_xor(s, 2, 8); s += __shfl_xor(s, 4, 8);
    float mean = s * 0.125f;
    float dv = (h - mean) * (h - mean);
    dv += __shfl_xor(dv, 1, 8); dv += __shfl_xor(dv, 2, 8); dv += __shfl_xor(dv, 4, 8);
    float var = dv * 0.125f;
    float y = (h - mean) * (float)(1.0 / sqrt((double)var + 1e-5)) * g[oc] + beta[oc];
    h = LEAKY(y);
  }
  if (o < O) outp[(long)bb * O + o] = h;
}

// ---------------------------------------------------------------- driver ----
extern "C" void kernel_launch(void* const* d_in, const int* in_sizes, int n_in,
                              void* d_out, int out_size, void* d_ws, size_t ws_size,
                              hipStream_t stream) {
  const int B = 8, N = 4096;
  const float* x      = (const float*)d_in[0];
  const float* w1 = (const float*)d_in[2];  const float* g1 = (const float*)d_in[3];  const float* b1 = (const float*)d_in[4];
  const float* w2 = (const float*)d_in[5];  const float* g2 = (const float*)d_in[6];  const float* b2 = (const float*)d_in[7];
  const float* w3 = (const float*)d_in[8];  const float* g3 = (const float*)d_in[9];  const float* b3 = (const float*)d_in[10];
  const float* w4 = (const float*)d_in[11]; const float* g4 = (const float*)d_in[12]; const float* b4 = (const float*)d_in[13];
  const float* wf = (const float*)d_in[14]; const float* bfv = (const float*)d_in[15];
  const float* gf = (const float*)d_in[16]; const float* betaf = (const float*)d_in[17];
  const float* wc1 = (const float*)d_in[18]; const float* bc1 = (const float*)d_in[19];
  const float* gc1 = (const float*)d_in[20]; const float* betac1 = (const float*)d_in[21];
  const float* wc2 = (const float*)d_in[22]; const float* bc2 = (const float*)d_in[23];
  const float* gc2 = (const float*)d_in[24]; const float* betac2 = (const float*)d_in[25];
  const float* wc3 = (const float*)d_in[26]; const float* bc3 = (const float*)d_in[27];

  char* p = (char*)d_ws;
  auto alloc = [&](size_t bytes) -> char* {
    char* r = p;
    p += (bytes + 255) & ~(size_t)255;
    return r;
  };
  float* feat  = (float*)alloc((size_t)B * 512 * N * 4);   // 67MB: concat(out1..4)
  int*   idx   = (int*)  alloc((size_t)B * N * 9 * 4);
  float* u     = (float*)alloc((size_t)B * N * 256 * 4);   // (B,N,O) layouts
  float* v     = (float*)alloc((size_t)B * N * 256 * 4);
  float* Amat  = (float*)alloc(256 * 128 * 4);
  double* S1   = (double*)alloc(1024 * 8);
  double* S2   = (double*)alloc(1024 * 8);
  float* scale = (float*)alloc(1024 * 4);
  float* shift = (float*)alloc(1024 * 4);
  float* pmax  = (float*)alloc((size_t)B * 1024 * 64 * 4);
  float* psum  = (float*)alloc((size_t)B * 1024 * 64 * 4);
  float* x1x2  = (float*)alloc((size_t)B * 2048 * 4);
  float* h1    = (float*)alloc((size_t)B * 512 * 4);
  float* h2    = (float*)alloc((size_t)B * 256 * 4);

  dim3 gknn(N / 64, B);

  auto edge = [&](const float* inp, long in_bstride, int Cin, int O, const float* W,
                  const float* g, const float* beta, int c0) {
    prep_A<<<(O * Cin + 255) / 256, 256, 0, stream>>>(W, Cin, O, Amat);
    dim3 gg(N / 64, O / 64, B);
    gemm_cn_no<<<gg, 256, 0, stream>>>(Amat, Cin, Cin, O, inp, in_bstride, N, u);
    gemm_cn_no<<<gg, 256, 0, stream>>>(W + Cin, 2 * Cin, Cin, O, inp, in_bstride, N, v);
    hipMemsetAsync(S1, 0, O * 8, stream);
    hipMemsetAsync(S2, 0, O * 8, stream);
    edge_stats<<<gknn, 256, 0, stream>>>(u, v, idx, O, N, S1, S2);
    finalize_scale<<<(O + 255) / 256, 256, 0, stream>>>(S1, S2, g, beta,
                                                        1.0 / ((double)B * N * 9), O, scale, shift);
    edge_final<<<gknn, 256, 0, stream>>>(u, v, idx, scale, shift, O, N,
                                         feat + (long)c0 * N, (long)512 * N);
  };

  knn_kernel<3><<<gknn, 256, 0, stream>>>(x, (long)3 * N, N, idx);
  edge(x, (long)3 * N, 3, 64, w1, g1, b1, 0);

  knn_kernel<64><<<gknn, 256, 0, stream>>>(feat, (long)512 * N, N, idx);
  edge(feat, (long)512 * N, 64, 64, w2, g2, b2, 64);

  knn_kernel<64><<<gknn, 256, 0, stream>>>(feat + (long)64 * N, (long)512 * N, N, idx);
  edge(feat + (long)64 * N, (long)512 * N, 64, 128, w3, g3, b3, 128);

  knn_kernel<128><<<gknn, 256, 0, stream>>>(feat + (long)128 * N, (long)512 * N, N, idx);
  edge(feat + (long)128 * N, (long)512 * N, 128, 256, w4, g4, b4, 256);

  // fusion conv 512->1024, BN over (B,N), leaky, then max+mean pool over N
  hipMemsetAsync(S1, 0, 1024 * 8, stream);
  hipMemsetAsync(S2, 0, 1024 * 8, stream);
  dim3 gf_(N / 64, 16, B);
  fusion_stats<<<gf_, 256, 0, stream>>>(wf, bfv, feat, N, S1, S2);
  finalize_scale<<<4, 256, 0, stream>>>(S1, S2, gf, betaf, 1.0 / ((double)B * N), 1024, scale, shift);
  fusion_pool<<<gf_, 256, 0, stream>>>(wf, bfv, feat, N, scale, shift, pmax, psum);
  pool_reduce<<<32, 256, 0, stream>>>(pmax, psum, x1x2, 1.0f / N);

  fc_kernel<<<16, 256, 0, stream>>>(x1x2, 2048, 512, wc1, bc1, gc1, betac1, h1, 1);
  fc_kernel<<<8, 256, 0, stream>>>(h1, 512, 256, wc2, bc2, gc2, betac2, h2, 1);
  fc_kernel<<<2, 256, 0, stream>>>(h2, 256, 40, wc3, bc3, nullptr, nullptr, (float*)d_out, 0);
}

// Round 2
// 4594.017 us; speedup vs baseline: 1.3837x; 1.3837x over previous
//
#include <hip/hip_runtime.h>
#include <math.h>
#include <float.h>

// DGCNN forward, MI355X, all f32.
// h_edge = (W1-W2)@x_i + W2@x_j = u + v[idx]  (9x less GEMM work).
// BN+leaky monotone per channel => max_k over h via hmax/hmin, single gather pass.
// Fusion conv computed ONCE, h stored over dead edge buffers (exact 134MB overlay).

#define LEAKY(y) ((y) >= 0.f ? (y) : 0.2f * (y))

// ------------------------------------------------------------- xx = sum x^2 --
template<int C>
__global__ void xx_kernel(const float* __restrict__ xin, long bstride, int N,
                          float* __restrict__ xxg) {
  int n = blockIdx.x * 256 + threadIdx.x;
  int b = blockIdx.y;
  if (n < N) {
    const float* xb = xin + (long)b * bstride;
    float s = 0.f;
    #pragma unroll
    for (int c = 0; c < C; ++c) { float t = xb[(long)c * N + n]; s += t * t; }
    xxg[(long)b * N + n] = s;
  }
}

// ---------------------------------------------------------------- kNN -------
// dtile: stride 76, swizzle phys_c = c ^ ((r>>2)&3) -> 2-way reads AND writes.
// selection threads scan interleaved cols c = q + 4t (conflict-free).
template<int C>
__global__ __launch_bounds__(256) void knn_kernel(const float* __restrict__ xin,
                                                  long bstride, int N,
                                                  const float* __restrict__ xxg,
                                                  int* __restrict__ idx_out) {
  constexpr int CC = (C > 64) ? 64 : C;
  constexpr int NCH = (C + CC - 1) / CC;   // 1 or 2
  __shared__ float rowF[C][64];
  __shared__ float colF[CC][64];
  __shared__ float xxr[64];
  __shared__ float xxc[64];
  __shared__ float dsh[64][76];   // union: dtile (cols 0..63 swizzled) | mergeD 0..35, mergeI 38..73

  const int tid = threadIdx.x;
  const int b = blockIdx.y;
  const int row0 = blockIdx.x * 64;
  const float* xb = xin + (long)b * bstride;

  for (int i = tid; i < C * 64; i += 256) {
    int c = i >> 6, j = i & 63;
    rowF[c][j] = xb[(long)c * N + row0 + j];
  }
  if (tid < 64) xxr[tid] = xxg[(long)b * N + row0 + tid];

  float td[9]; int ti[9];
  #pragma unroll
  for (int s = 0; s < 9; ++s) { td[s] = 3.0e38f; ti[s] = 0x7fffffff; }

  const int tr = tid >> 4, tc = tid & 15;   // GEMM mapping
  const int rsel = tid >> 2, q = tid & 3;   // selection mapping
  const int wsw = tr & 3;                   // write swizzle ((r>>2)&3 for r=4tr+i)
  const int xsw = (rsel >> 2) & 3;          // read swizzle

  const int ntiles = N >> 6;
  for (int ct = 0; ct < ntiles; ++ct) {
    const int c0 = ct << 6;
    __syncthreads();                        // dtile consumed, colF free (iter0: rowF/xxr ready)
    for (int i = tid; i < CC * 64; i += 256) {
      int c = i >> 6, j = i & 63;
      colF[c][j] = xb[(long)c * N + c0 + j];
    }
    if (tid < 64) xxc[tid] = xxg[(long)b * N + c0 + tid];
    __syncthreads();

    float acc[4][4];
    #pragma unroll
    for (int i = 0; i < 4; ++i)
      #pragma unroll
      for (int j = 0; j < 4; ++j) acc[i][j] = 0.f;

    #pragma unroll 4
    for (int c = 0; c < CC; ++c) {
      float4 a4 = *reinterpret_cast<const float4*>(&rowF[c][4 * tr]);
      float4 b4 = *reinterpret_cast<const float4*>(&colF[c][4 * tc]);
      float av[4] = {a4.x, a4.y, a4.z, a4.w};
      float bv[4] = {b4.x, b4.y, b4.z, b4.w};
      #pragma unroll
      for (int i = 0; i < 4; ++i)
        #pragma unroll
        for (int j = 0; j < 4; ++j) acc[i][j] = fmaf(av[i], bv[j], acc[i][j]);
    }
    if (NCH == 2) {
      __syncthreads();
      for (int i = tid; i < CC * 64; i += 256) {
        int c = i >> 6, j = i & 63;
        colF[c][j] = xb[(long)(CC + c) * N + c0 + j];
      }
      __syncthreads();
      #pragma unroll 4
      for (int c = 0; c < CC; ++c) {
        float4 a4 = *reinterpret_cast<const float4*>(&rowF[CC + c][4 * tr]);
        float4 b4 = *reinterpret_cast<const float4*>(&colF[c][4 * tc]);
        float av[4] = {a4.x, a4.y, a4.z, a4.w};
        float bv[4] = {b4.x, b4.y, b4.z, b4.w};
        #pragma unroll
        for (int i = 0; i < 4; ++i)
          #pragma unroll
          for (int j = 0; j < 4; ++j) acc[i][j] = fmaf(av[i], bv[j], acc[i][j]);
      }
    }
    #pragma unroll
    for (int i = 0; i < 4; ++i) {
      int r = 4 * tr + i;
      float xr = xxr[r];
      #pragma unroll
      for (int j = 0; j < 4; ++j) {
        int cl = 4 * tc + j;
        float d = (xr - 2.0f * acc[i][j]) + xxc[cl];  // ref rounding order
        if (row0 + r == c0 + cl) d = 3.0e38f;         // self-mask
        dsh[r][cl ^ wsw] = d;
      }
    }
    __syncthreads();
    #pragma unroll
    for (int t = 0; t < 16; ++t) {
      int cl = q + 4 * t;
      float d = dsh[rsel][cl ^ xsw];
      int gi = c0 + cl;
      if (d < td[8] || (d == td[8] && gi < ti[8])) {
        td[8] = d; ti[8] = gi;
        #pragma unroll
        for (int s = 8; s > 0; --s) {
          bool sw = (td[s] < td[s - 1]) || (td[s] == td[s - 1] && ti[s] < ti[s - 1]);
          if (sw) {
            float tf = td[s]; td[s] = td[s - 1]; td[s - 1] = tf;
            int tn = ti[s]; ti[s] = ti[s - 1]; ti[s - 1] = tn;
          }
        }
      }
    }
  }

  __syncthreads();
  #pragma unroll
  for (int s = 0; s < 9; ++s) {
    dsh[rsel][q * 9 + s] = td[s];
    *reinterpret_cast<int*>(&dsh[rsel][38 + q * 9 + s]) = ti[s];
  }
  __syncthreads();
  if (tid < 64) {
    const long ob = ((long)b * N + row0 + tid) * 9;
    for (int s = 0; s < 9; ++s) {
      float bd = dsh[tid][0]; int bi = *reinterpret_cast<int*>(&dsh[tid][38]); int bp = 0;
      for (int t = 1; t < 36; ++t) {
        float dd = dsh[tid][t];
        int ii = *reinterpret_cast<int*>(&dsh[tid][38 + t]);
        if (dd < bd || (dd == bd && ii < bi)) { bd = dd; bi = ii; bp = t; }
      }
      idx_out[ob + s] = bi;
      dsh[tid][bp] = 3.3e38f;
    }
  }
}

// ------------------------------------------- W transposes (coalesced GEMMs) --
__global__ void prep_wt(const float* __restrict__ W, int Cin, int O,
                        float* __restrict__ At, float* __restrict__ W2t) {
  int i = blockIdx.x * 256 + threadIdx.x;
  if (i < O * Cin) {
    int o = i % O, c = i / O;
    float w1v = W[(long)o * 2 * Cin + c];
    float w2v = W[(long)o * 2 * Cin + Cin + c];
    At[(long)c * O + o]  = w1v - w2v;
    W2t[(long)c * O + o] = w2v;
  }
}

__global__ void transpose_wf(const float* __restrict__ wf, float* __restrict__ wfT) {
  int i = blockIdx.x * 256 + threadIdx.x;
  if (i < 512 * 1024) {
    int o = i & 1023, c = i >> 10;
    wfT[(long)c * 1024 + o] = wf[(long)o * 512 + c];
  }
}

// ------------------------------ GEMM: out[b][n][o] = sum_c Wt[c][o] in[b][c][n]
__global__ __launch_bounds__(256) void gemm_cn_no(const float* __restrict__ Wt,
                                                  int C, int O,
                                                  const float* __restrict__ in,
                                                  long in_bstride, int N,
                                                  float* __restrict__ out) {
  const int tid = threadIdx.x;
  const int n0 = blockIdx.x * 64, o0 = blockIdx.y * 64, b = blockIdx.z;
  __shared__ float wT[128][64];   // [c][o]
  __shared__ float inT[128][64];  // [c][n]
  for (int i = tid; i < C * 64; i += 256) {
    int c = i >> 6, j = i & 63;
    wT[c][j]  = Wt[(long)c * O + o0 + j];
    inT[c][j] = in[(long)b * in_bstride + (long)c * N + n0 + j];
  }
  __syncthreads();
  const int tr = tid >> 4, tc = tid & 15;
  float acc[4][4];
  #pragma unroll
  for (int i = 0; i < 4; ++i)
    #pragma unroll
    for (int j = 0; j < 4; ++j) acc[i][j] = 0.f;
  for (int c = 0; c < C; ++c) {
    float4 a4 = *reinterpret_cast<const float4*>(&wT[c][4 * tr]);
    float4 b4 = *reinterpret_cast<const float4*>(&inT[c][4 * tc]);
    float av[4] = {a4.x, a4.y, a4.z, a4.w};
    float bv[4] = {b4.x, b4.y, b4.z, b4.w};
    #pragma unroll
    for (int i = 0; i < 4; ++i)
      #pragma unroll
      for (int j = 0; j < 4; ++j) acc[i][j] = fmaf(av[i], bv[j], acc[i][j]);
  }
  #pragma unroll
  for (int j = 0; j < 4; ++j) {
    float4 st = make_float4(acc[0][j], acc[1][j], acc[2][j], acc[3][j]);
    *reinterpret_cast<float4*>(&out[((long)b * N + n0 + 4 * tc + j) * O + o0 + 4 * tr]) = st;
  }
}

// ------------------- single gather pass: stats + hmax + hmin per (n,o) ------
__global__ __launch_bounds__(256) void edge_pass(const float* __restrict__ u,
                                                 const float* __restrict__ v,
                                                 const int* __restrict__ idx,
                                                 int O, int N,
                                                 float* __restrict__ hmax,
                                                 float* __restrict__ hmin,
                                                 double* __restrict__ S1,
                                                 double* __restrict__ S2) {
  const int tid = threadIdx.x;
  const int n0 = blockIdx.x * 64, o0 = blockIdx.y * 64, b = blockIdx.z;
  __shared__ int sidx[64][9];
  __shared__ float4 redA[4][16];
  __shared__ float4 redB[4][16];
  for (int i = tid; i < 576; i += 256)
    ((int*)sidx)[i] = idx[((long)b * N + n0) * 9 + i];
  __syncthreads();
  const int nl = tid >> 4, oq = tid & 15;
  const long base = (long)b * N;
  const int ocol = o0 + 4 * oq;
  float4 s1 = make_float4(0.f, 0.f, 0.f, 0.f);
  float4 s2 = make_float4(0.f, 0.f, 0.f, 0.f);
  for (int g = 0; g < 4; ++g) {
    const int n = g * 16 + nl;
    const float4 u4 = *reinterpret_cast<const float4*>(&u[(base + n0 + n) * O + ocol]);
    float4 mx = make_float4(-3.0e38f, -3.0e38f, -3.0e38f, -3.0e38f);
    float4 mn = make_float4(3.0e38f, 3.0e38f, 3.0e38f, 3.0e38f);
    #pragma unroll
    for (int k = 0; k < 9; ++k) {
      int m = sidx[n][k];
      const float4 v4 = *reinterpret_cast<const float4*>(&v[(base + m) * O + ocol]);
      float hx = u4.x + v4.x, hy = u4.y + v4.y, hz = u4.z + v4.z, hw = u4.w + v4.w;
      s1.x += hx; s1.y += hy; s1.z += hz; s1.w += hw;
      s2.x = fmaf(hx, hx, s2.x); s2.y = fmaf(hy, hy, s2.y);
      s2.z = fmaf(hz, hz, s2.z); s2.w = fmaf(hw, hw, s2.w);
      mx.x = fmaxf(mx.x, hx); mx.y = fmaxf(mx.y, hy); mx.z = fmaxf(mx.z, hz); mx.w = fmaxf(mx.w, hw);
      mn.x = fminf(mn.x, hx); mn.y = fminf(mn.y, hy); mn.z = fminf(mn.z, hz); mn.w = fminf(mn.w, hw);
    }
    *reinterpret_cast<float4*>(&hmax[(base + n0 + n) * O + ocol]) = mx;
    *reinterpret_cast<float4*>(&hmin[(base + n0 + n) * O + ocol]) = mn;
  }
  s1.x += __shfl_xor(s1.x, 16); s1.y += __shfl_xor(s1.y, 16);
  s1.z += __shfl_xor(s1.z, 16); s1.w += __shfl_xor(s1.w, 16);
  s2.x += __shfl_xor(s2.x, 16); s2.y += __shfl_xor(s2.y, 16);
  s2.z += __shfl_xor(s2.z, 16); s2.w += __shfl_xor(s2.w, 16);
  s1.x += __shfl_xor(s1.x, 32); s1.y += __shfl_xor(s1.y, 32);
  s1.z += __shfl_xor(s1.z, 32); s1.w += __shfl_xor(s1.w, 32);
  s2.x += __shfl_xor(s2.x, 32); s2.y += __shfl_xor(s2.y, 32);
  s2.z += __shfl_xor(s2.z, 32); s2.w += __shfl_xor(s2.w, 32);
  if ((tid & 48) == 0) { redA[tid >> 6][oq] = s1; redB[tid >> 6][oq] = s2; }
  __syncthreads();
  if (tid < 16) {
    float4 a = redA[0][tid], bb = redB[0][tid];
    #pragma unroll
    for (int w = 1; w < 4; ++w) {
      float4 t1 = redA[w][tid], t2 = redB[w][tid];
      a.x += t1.x; a.y += t1.y; a.z += t1.z; a.w += t1.w;
      bb.x += t2.x; bb.y += t2.y; bb.z += t2.z; bb.w += t2.w;
    }
    int o = o0 + 4 * tid;
    atomicAdd(&S1[o + 0], (double)a.x);  atomicAdd(&S1[o + 1], (double)a.y);
    atomicAdd(&S1[o + 2], (double)a.z);  atomicAdd(&S1[o + 3], (double)a.w);
    atomicAdd(&S2[o + 0], (double)bb.x); atomicAdd(&S2[o + 1], (double)bb.y);
    atomicAdd(&S2[o + 2], (double)bb.z); atomicAdd(&S2[o + 3], (double)bb.w);
  }
}

__global__ void finalize_scale(const double* __restrict__ S1, const double* __restrict__ S2,
                               const float* __restrict__ g, const float* __restrict__ beta,
                               double invM, int O, float* __restrict__ scale,
                               float* __restrict__ shift) {
  int o = blockIdx.x * 256 + threadIdx.x;
  if (o < O) {
    double mean = S1[o] * invM;
    double var = S2[o] * invM - mean * mean;
    double sc = (double)g[o] / sqrt(var + 1e-5);
    scale[o] = (float)sc;
    shift[o] = (float)((double)beta[o] - mean * sc);
  }
}

// ------------------- elementwise finalize + transpose to (B,O,N) ------------
__global__ __launch_bounds__(256) void edge_out(const float* __restrict__ hmax,
                                                const float* __restrict__ hmin,
                                                const float* __restrict__ scale,
                                                const float* __restrict__ shift,
                                                int O, int N,
                                                float* __restrict__ outp, long out_bstride) {
  const int tid = threadIdx.x;
  const int b = blockIdx.y, n0 = blockIdx.x * 64;
  __shared__ float yt[64][65];
  const int ol = tid & 63, nl = tid >> 6;
  const long base = (long)b * N;
  for (int oc = 0; oc < O; oc += 64) {
    float sc = scale[oc + ol], sh = shift[oc + ol];
    __syncthreads();
    for (int ng = 0; ng < 16; ++ng) {
      int n = ng * 4 + nl;
      long off = (base + n0 + n) * O + oc + ol;
      float hv = (sc >= 0.f) ? hmax[off] : hmin[off];
      float y = sc * hv + sh;
      yt[ol][n] = LEAKY(y);
    }
    __syncthreads();
    for (int rr = 0; rr < 16; ++rr) {
      int r = rr * 4 + nl;
      outp[(long)b * out_bstride + (long)(oc + r) * N + n0 + ol] = yt[r][ol];
    }
  }
}

// -------------------- fusion 512->1024: GEMM once, store h + stats ----------
__global__ __launch_bounds__(256) void fusion_gemm(const float* __restrict__ wfT,
                                                   const float* __restrict__ bfb,
                                                   const float* __restrict__ feat, int N,
                                                   float* __restrict__ h,
                                                   double* __restrict__ S1,
                                                   double* __restrict__ S2) {
  const int tid = threadIdx.x;
  const int n0 = blockIdx.x * 64, o0 = blockIdx.y * 64, b = blockIdx.z;
  __shared__ float wT[64][64];
  __shared__ float fT[64][64];
  const int tr = tid >> 4, tc = tid & 15;
  float acc[4][4];
  #pragma unroll
  for (int i = 0; i < 4; ++i)
    #pragma unroll
    for (int j = 0; j < 4; ++j) acc[i][j] = 0.f;
  for (int cc = 0; cc < 8; ++cc) {
    __syncthreads();
    for (int i = tid; i < 4096; i += 256) {
      int ci = i >> 6, j = i & 63;
      wT[ci][j] = wfT[(long)(cc * 64 + ci) * 1024 + o0 + j];
      fT[ci][j] = feat[((long)b * 512 + cc * 64 + ci) * N + n0 + j];
    }
    __syncthreads();
    #pragma unroll
    for (int ci = 0; ci < 64; ++ci) {
      float4 a4 = *reinterpret_cast<const float4*>(&wT[ci][4 * tr]);
      float4 b4 = *reinterpret_cast<const float4*>(&fT[ci][4 * tc]);
      float av[4] = {a4.x, a4.y, a4.z, a4.w};
      float bv[4] = {b4.x, b4.y, b4.z, b4.w};
      #pragma unroll
      for (int i = 0; i < 4; ++i)
        #pragma unroll
        for (int j = 0; j < 4; ++j) acc[i][j] = fmaf(av[i], bv[j], acc[i][j]);
    }
  }
  #pragma unroll
  for (int i = 0; i < 4; ++i) {
    int o = o0 + 4 * tr + i;
    float bias = bfb[o];
    float4 hv = make_float4(acc[i][0] + bias, acc[i][1] + bias,
                            acc[i][2] + bias, acc[i][3] + bias);
    *reinterpret_cast<float4*>(&h[((long)b * 1024 + o) * N + n0 + 4 * tc]) = hv;
    float s1 = hv.x + hv.y + hv.z + hv.w;
    float s2 = hv.x * hv.x + hv.y * hv.y + hv.z * hv.z + hv.w * hv.w;
    for (int off = 1; off < 16; off <<= 1) {
      s1 += __shfl_xor(s1, off, 16);
      s2 += __shfl_xor(s2, off, 16);
    }
    if (tc == 0) { atomicAdd(&S1[o], (double)s1); atomicAdd(&S2[o], (double)s2); }
  }
}

// --------------- BN+leaky+max/mean pool over N, one wave per (b,o) row ------
__global__ __launch_bounds__(256) void pool_kernel(const float* __restrict__ h,
                                                   const float* __restrict__ scale,
                                                   const float* __restrict__ shift,
                                                   float* __restrict__ x1x2) {
  int gw = (blockIdx.x * 256 + threadIdx.x) >> 6;
  int lane = threadIdx.x & 63;
  int b = gw >> 10, o = gw & 1023;
  const float4* row = reinterpret_cast<const float4*>(h + ((long)b * 1024 + o) * 4096);
  float sc = scale[o], sh = shift[o];
  float mx = -3.0e38f, sm = 0.f;
  for (int j = 0; j < 16; ++j) {
    float4 hv = row[j * 64 + lane];
    float y0 = LEAKY(sc * hv.x + sh), y1 = LEAKY(sc * hv.y + sh);
    float y2 = LEAKY(sc * hv.z + sh), y3 = LEAKY(sc * hv.w + sh);
    mx = fmaxf(mx, fmaxf(fmaxf(y0, y1), fmaxf(y2, y3)));
    sm += (y0 + y1) + (y2 + y3);
  }
  #pragma unroll
  for (int off = 1; off < 64; off <<= 1) {
    mx = fmaxf(mx, __shfl_xor(mx, off));
    sm += __shfl_xor(sm, off);
  }
  if (lane == 0) {
    x1x2[(long)b * 2048 + o] = mx;
    x1x2[(long)b * 2048 + 1024 + o] = sm * (1.f / 4096.f);
  }
}

// ----------------------------------------------------------- classifier -----
__global__ __launch_bounds__(256) void fc_kernel(const float* __restrict__ in, int Cin, int O,
                                                 const float* __restrict__ W,
                                                 const float* __restrict__ bias,
                                                 const float* __restrict__ g,
                                                 const float* __restrict__ beta,
                                                 float* __restrict__ outp, int do_bn) {
  const int tid = threadIdx.x;
  const int o = blockIdx.x * 32 + (tid >> 3);
  const int bb = tid & 7;
  const int oc = (o < O) ? o : (O - 1);
  const float* ir = in + (long)bb * Cin;
  const float* wr = W + (long)oc * Cin;
  float dot = 0.f;
  for (int c = 0; c < Cin; c += 4) {
    float4 a = *reinterpret_cast<const float4*>(&ir[c]);
    float4 w = *reinterpret_cast<const float4*>(&wr[c]);
    dot += a.x * w.x + a.y * w.y + a.z * w.z + a.w * w.w;
  }
  float h = dot + bias[oc];
  if (do_bn) {
    float s = h;
    s += __shfl_xor(s, 1, 8); s += __shfl_xor(s, 2, 8); s += __shfl_xor(s, 4, 8);
    float mean = s * 0.125f;
    float dv = (h - mean) * (h - mean);
    dv += __shfl_xor(dv, 1, 8); dv += __shfl_xor(dv, 2, 8); dv += __shfl_xor(dv, 4, 8);
    float var = dv * 0.125f;
    float y = (h - mean) * (float)(1.0 / sqrt((double)var + 1e-5)) * g[oc] + beta[oc];
    h = LEAKY(y);
  }
  if (o < O) outp[(long)bb * O + o] = h;
}

// ---------------------------------------------------------------- driver ----
extern "C" void kernel_launch(void* const* d_in, const int* in_sizes, int n_in,
                              void* d_out, int out_size, void* d_ws, size_t ws_size,
                              hipStream_t stream) {
  const int B = 8, N = 4096;
  const float* x   = (const float*)d_in[0];
  const float* w1 = (const float*)d_in[2];  const float* g1 = (const float*)d_in[3];  const float* b1 = (const float*)d_in[4];
  const float* w2 = (const float*)d_in[5];  const float* g2 = (const float*)d_in[6];  const float* b2 = (const float*)d_in[7];
  const float* w3 = (const float*)d_in[8];  const float* g3 = (const float*)d_in[9];  const float* b3 = (const float*)d_in[10];
  const float* w4 = (const float*)d_in[11]; const float* g4 = (const float*)d_in[12]; const float* b4 = (const float*)d_in[13];
  const float* wf = (const float*)d_in[14]; const float* bfv = (const float*)d_in[15];
  const float* gf = (const float*)d_in[16]; const float* betaf = (const float*)d_in[17];
  const float* wc1 = (const float*)d_in[18]; const float* bc1 = (const float*)d_in[19];
  const float* gc1 = (const float*)d_in[20]; const float* betac1 = (const float*)d_in[21];
  const float* wc2 = (const float*)d_in[22]; const float* bc2 = (const float*)d_in[23];
  const float* gc2 = (const float*)d_in[24]; const float* betac2 = (const float*)d_in[25];
  const float* wc3 = (const float*)d_in[26]; const float* bc3 = (const float*)d_in[27];

  char* p = (char*)d_ws;
  auto alloc = [&](size_t bytes) -> char* {
    char* r = p;
    p += (bytes + 255) & ~(size_t)255;
    return r;
  };
  float* feat  = (float*)alloc((size_t)B * 512 * N * 4);   // 67.1MB
  int*   idx   = (int*)  alloc((size_t)B * N * 9 * 4);     // 1.2MB
  float* xxg   = (float*)alloc((size_t)B * N * 4);
  // R region: u|v|hmax|hmin (edge phase) overlaid by h (fusion phase). 4x32MB exact.
  float* u     = (float*)alloc((size_t)B * N * 256 * 4);
  float* v     = (float*)alloc((size_t)B * N * 256 * 4);
  float* hmax  = (float*)alloc((size_t)B * N * 256 * 4);
  float* hmin  = (float*)alloc((size_t)B * N * 256 * 4);
  float* hbuf  = u;                                        // (B,1024,N) overlay
  float* At    = (float*)alloc(128 * 256 * 4);
  float* W2t   = (float*)alloc(128 * 256 * 4);
  float* wfT   = (float*)alloc((size_t)512 * 1024 * 4);
  double* S1   = (double*)alloc(1024 * 8);
  double* S2   = (double*)alloc(1024 * 8);
  float* scale = (float*)alloc(1024 * 4);
  float* shift = (float*)alloc(1024 * 4);
  float* x1x2  = (float*)alloc((size_t)B * 2048 * 4);
  float* h1    = (float*)alloc((size_t)B * 512 * 4);
  float* h2    = (float*)alloc((size_t)B * 256 * 4);

  dim3 gknn(N / 64, B);
  dim3 gxx(N / 256, B);

  transpose_wf<<<2048, 256, 0, stream>>>(wf, wfT);

  auto edge = [&](const float* inp, long in_bstride, int Cin, int O, const float* W,
                  const float* g, const float* beta, int c0) {
    prep_wt<<<(O * Cin + 255) / 256, 256, 0, stream>>>(W, Cin, O, At, W2t);
    dim3 gg(N / 64, O / 64, B);
    gemm_cn_no<<<gg, 256, 0, stream>>>(At, Cin, O, inp, in_bstride, N, u);
    gemm_cn_no<<<gg, 256, 0, stream>>>(W2t, Cin, O, inp, in_bstride, N, v);
    hipMemsetAsync(S1, 0, O * 8, stream);
    hipMemsetAsync(S2, 0, O * 8, stream);
    edge_pass<<<gg, 256, 0, stream>>>(u, v, idx, O, N, hmax, hmin, S1, S2);
    finalize_scale<<<(O + 255) / 256, 256, 0, stream>>>(S1, S2, g, beta,
                                                        1.0 / ((double)B * N * 9), O, scale, shift);
    edge_out<<<gknn, 256, 0, stream>>>(hmax, hmin, scale, shift, O, N,
                                       feat + (long)c0 * N, (long)512 * N);
  };

  xx_kernel<3><<<gxx, 256, 0, stream>>>(x, (long)3 * N, N, xxg);
  knn_kernel<3><<<gknn, 256, 0, stream>>>(x, (long)3 * N, N, xxg, idx);
  edge(x, (long)3 * N, 3, 64, w1, g1, b1, 0);

  xx_kernel<64><<<gxx, 256, 0, stream>>>(feat, (long)512 * N, N, xxg);
  knn_kernel<64><<<gknn, 256, 0, stream>>>(feat, (long)512 * N, N, xxg, idx);
  edge(feat, (long)512 * N, 64, 64, w2, g2, b2, 64);

  xx_kernel<64><<<gxx, 256, 0, stream>>>(feat + (long)64 * N, (long)512 * N, N, xxg);
  knn_kernel<64><<<gknn, 256, 0, stream>>>(feat + (long)64 * N, (long)512 * N, N, xxg, idx);
  edge(feat + (long)64 * N, (long)512 * N, 64, 128, w3, g3, b3, 128);

  xx_kernel<128><<<gxx, 256, 0, stream>>>(feat + (long)128 * N, (long)512 * N, N, xxg);
  knn_kernel<128><<<gknn, 256, 0, stream>>>(feat + (long)128 * N, (long)512 * N, N, xxg, idx);
  edge(feat + (long)128 * N, (long)512 * N, 128, 256, w4, g4, b4, 256);

  // fusion conv 512->1024 (single GEMM, h stored over dead edge buffers)
  hipMemsetAsync(S1, 0, 1024 * 8, stream);
  hipMemsetAsync(S2, 0, 1024 * 8, stream);
  dim3 gfu(N / 64, 16, B);
  fusion_gemm<<<gfu, 256, 0, stream>>>(wfT, bfv, feat, N, hbuf, S1, S2);
  finalize_scale<<<4, 256, 0, stream>>>(S1, S2, gf, betaf, 1.0 / ((double)B * N), 1024, scale, shift);
  pool_kernel<<<2048, 256, 0, stream>>>(hbuf, scale, shift, x1x2);

  fc_kernel<<<16, 256, 0, stream>>>(x1x2, 2048, 512, wc1, bc1, gc1, betac1, h1, 1);
  fc_kernel<<<8, 256, 0, stream>>>(h1, 512, 256, wc2, bc2, gc2, betac2, h2, 1);
  fc_kernel<<<2, 256, 0, stream>>>(h2, 256, 40, wc3, bc3, nullptr, nullptr, (float*)d_out, 0);
}

// Round 5
// 4523.669 us; speedup vs baseline: 1.4052x; 1.0156x over previous
//
#include <hip/hip_runtime.h>
#include <math.h>
#include <float.h>

// DGCNN forward, MI355X, all f32 except kNN distance GEMM (3-way-split bf16 MFMA).
// h_edge = (W1-W2)@x_i + W2@x_j = u + v[idx]  (9x less GEMM work).
// kNN two-phase: (1) MFMA approx distances -> top-16 candidates/row,
//                (2) exact f32 re-rank of the 16 (r2-proven rounding) -> top-9.

#define LEAKY(y) ((y) >= 0.f ? (y) : 0.2f * (y))

using f32x16 = __attribute__((ext_vector_type(16))) float;
using bf16x8 = __attribute__((ext_vector_type(8))) __bf16;
using short8v = __attribute__((ext_vector_type(8))) short;

__device__ inline ushort f2bf(float x) {
  unsigned u = __float_as_uint(x);
  unsigned r = (u + 0x7fff + ((u >> 16) & 1)) >> 16;
  return (ushort)r;
}

// ------------------------------------------------------------- xx = sum x^2 --
template<int C>
__global__ void xx_kernel(const float* __restrict__ xin, long bstride, int N,
                          float* __restrict__ xxg) {
  int n = blockIdx.x * 256 + threadIdx.x;
  int b = blockIdx.y;
  if (n < N) {
    const float* xb = xin + (long)b * bstride;
    float s = 0.f;
    #pragma unroll
    for (int c = 0; c < C; ++c) { float t = xb[(long)c * N + n]; s += t * t; }
    xxg[(long)b * N + n] = s;
  }
}

// ---------------------------------------- pack points into MFMA frag order ---
// layout: [(b*PB + pb)*KC + kc] * 512 + lane*8 + e ; pt = pb*32 + (lane&31),
//         k' = kc*16 + (lane>>5)*8 + e ; slice s = k'/C, channel c = k'%C.
// R slices (query):     [hi, hi, mid, mid, lo, hi]
// C slices (candidate): [hi, mid, hi, mid, hi, lo]
template<int C, int KC>
__global__ __launch_bounds__(256) void pack_kernel(const float* __restrict__ xin, long bstride,
                                                   int N, ushort* __restrict__ packR,
                                                   ushort* __restrict__ packC) {
  __shared__ float xt[C][32];
  const int tid = threadIdx.x;
  const int pb = blockIdx.x, b = blockIdx.y;
  for (int i = tid; i < C * 32; i += 256) {
    int c = i >> 5, j = i & 31;
    xt[c][j] = xin[(long)b * bstride + (long)c * N + pb * 32 + j];
  }
  __syncthreads();
  const int PB = N >> 5;
  for (int it = tid; it < KC * 64; it += 256) {
    int kc = it >> 6, l = it & 63;
    int pt = l & 31;
    union { ushort u[8]; short8v v; } R, Cc;
    #pragma unroll
    for (int e = 0; e < 8; ++e) {
      int kp = kc * 16 + ((l >> 5) << 3) + e;
      ushort rv = 0, cv = 0;
      if (kp < 6 * C) {
        int s = kp / C, c = kp % C;
        float xv = xt[c][pt];
        ushort hi = f2bf(xv);
        float hif = __uint_as_float((unsigned)hi << 16);
        float r1 = xv - hif;
        ushort mid = f2bf(r1);
        float midf = __uint_as_float((unsigned)mid << 16);
        ushort lo = f2bf(r1 - midf);
        rv = (s == 2 || s == 3) ? mid : ((s == 4) ? lo : hi);
        cv = (s == 1 || s == 3) ? mid : ((s == 5) ? lo : hi);
      }
      R.u[e] = rv; Cc.u[e] = cv;
    }
    long off = (((long)b * PB + pb) * KC + kc) * 512 + l * 8;
    *reinterpret_cast<short8v*>(&packR[off]) = R.v;
    *reinterpret_cast<short8v*>(&packC[off]) = Cc.v;
  }
}

// --------------------------------------------- kNN core (shared selection) ---
#define KNN_TOP9_UPDATE(d_, gi_)                                                 \
  if (d_ < td[8] || (d_ == td[8] && gi_ < ti[8])) {                              \
    td[8] = d_; ti[8] = gi_;                                                     \
    _Pragma("unroll")                                                            \
    for (int s_ = 8; s_ > 0; --s_) {                                             \
      bool sw_ = (td[s_] < td[s_ - 1]) || (td[s_] == td[s_ - 1] && ti[s_] < ti[s_ - 1]); \
      if (sw_) {                                                                 \
        float tf_ = td[s_]; td[s_] = td[s_ - 1]; td[s_ - 1] = tf_;               \
        int tn_ = ti[s_]; ti[s_] = ti[s_ - 1]; ti[s_ - 1] = tn_;                 \
      }                                                                          \
    }                                                                            \
  }

#define KNN_MERGE16(cand_)                                                       \
  __syncthreads();                                                               \
  _Pragma("unroll")                                                              \
  for (int s = 0; s < 9; ++s) {                                                  \
    mD[lane31][(w * 2 + hf) * 9 + s] = td[s];                                    \
    mI[lane31][(w * 2 + hf) * 9 + s] = ti[s];                                    \
  }                                                                              \
  __syncthreads();                                                               \
  if (tid < 32) {                                                                \
    int pos[8] = {0, 0, 0, 0, 0, 0, 0, 0};                                       \
    const long ob = (((long)b * N + rowblk * 32 + tid)) << 4;                    \
    for (int s = 0; s < 16; ++s) {                                               \
      float bd = 3.3e38f; int bi = 0x7fffffff; int bj = -1;                      \
      _Pragma("unroll")                                                          \
      for (int j = 0; j < 8; ++j) {                                              \
        if (pos[j] < 9) {                                                        \
          float dd = mD[tid][j * 9 + pos[j]];                                    \
          int ii = mI[tid][j * 9 + pos[j]];                                      \
          if (dd < bd || (dd == bd && ii < bi)) { bd = dd; bi = ii; bj = j; }    \
        }                                                                        \
      }                                                                          \
      cand_[ob + s] = bi;                                                        \
      _Pragma("unroll")                                                          \
      for (int j = 0; j < 8; ++j) pos[j] += (j == bj) ? 1 : 0;                   \
    }                                                                            \
  }

// ------------------------------------------- kNN, B-fragments in registers ---
template<int KC>
__global__ __launch_bounds__(256, 2) void knn_mfma_reg(const ushort* __restrict__ packR,
                                                       const ushort* __restrict__ packC,
                                                       const float* __restrict__ xxg,
                                                       int N, int* __restrict__ cand) {
  __shared__ float pool[4608];              // sxx[4096] (m-loop) U merge[32][72]x2
  float* sxx = pool;
  auto mD = (float(*)[72])pool;
  auto mI = (int(*)[72])(pool + 2304);
  const int tid = threadIdx.x;
  const int b = blockIdx.y, rowblk = blockIdx.x;
  const int w = tid >> 6, l = tid & 63;
  const int lane31 = l & 31, hf = l >> 5;
  const int PB = N >> 5;

  for (int i = tid; i < N; i += 256) sxx[i] = xxg[(long)b * N + i];

  const ushort* rp = packR + (((long)b * PB + rowblk) * (long)KC) * 512 + l * 8;
  bf16x8 bfr[KC];
  #pragma unroll
  for (int kc = 0; kc < KC; ++kc)
    bfr[kc] = *reinterpret_cast<const bf16x8*>(rp + kc * 512);

  __syncthreads();
  const int n_glob = rowblk * 32 + lane31;
  const float xr = sxx[n_glob];

  float td[9]; int ti[9];
  #pragma unroll
  for (int s = 0; s < 9; ++s) { td[s] = 3.0e38f; ti[s] = 0x7fffffff; }

  for (int mb = w; mb < PB; mb += 4) {
    const ushort* ap = packC + (((long)b * PB + mb) * (long)KC) * 512 + l * 8;
    f32x16 acc = {};
    #pragma unroll
    for (int kc = 0; kc < KC; ++kc) {
      bf16x8 af = *reinterpret_cast<const bf16x8*>(ap + kc * 512);
      acc = __builtin_amdgcn_mfma_f32_32x32x16_bf16(af, bfr[kc], acc, 0, 0, 0);
    }
    #pragma unroll
    for (int reg = 0; reg < 16; ++reg) {
      int m_loc = (reg & 3) + 8 * (reg >> 2) + 4 * hf;
      int m_glob = (mb << 5) + m_loc;
      float d = (xr - 2.0f * acc[reg]) + sxx[m_glob];
      if (m_glob == n_glob) d = 3.0e38f;
      KNN_TOP9_UPDATE(d, m_glob)
    }
  }
  KNN_MERGE16(cand)
}

// ------------------------------------------------ kNN, B-fragments in LDS ---
template<int KC>
__global__ __launch_bounds__(256, 2) void knn_mfma_lds(const ushort* __restrict__ packR,
                                                       const ushort* __restrict__ packC,
                                                       const float* __restrict__ xxg,
                                                       int N, int* __restrict__ cand) {
  __shared__ float pool[4608];
  __shared__ ushort sB[KC * 512];           // 48KB at KC=48
  float* sxx = pool;
  auto mD = (float(*)[72])pool;
  auto mI = (int(*)[72])(pool + 2304);
  const int tid = threadIdx.x;
  const int b = blockIdx.y, rowblk = blockIdx.x;
  const int w = tid >> 6, l = tid & 63;
  const int lane31 = l & 31, hf = l >> 5;
  const int PB = N >> 5;

  for (int i = tid; i < N; i += 256) sxx[i] = xxg[(long)b * N + i];
  const ushort* rp = packR + (((long)b * PB + rowblk) * (long)KC) * 512;
  for (int i = tid * 8; i < KC * 512; i += 2048)
    *reinterpret_cast<short8v*>(&sB[i]) = *reinterpret_cast<const short8v*>(rp + i);

  __syncthreads();
  const int n_glob = rowblk * 32 + lane31;
  const float xr = sxx[n_glob];

  float td[9]; int ti[9];
  #pragma unroll
  for (int s = 0; s < 9; ++s) { td[s] = 3.0e38f; ti[s] = 0x7fffffff; }

  for (int mb = w; mb < PB; mb += 4) {
    const ushort* ap = packC + (((long)b * PB + mb) * (long)KC) * 512 + l * 8;
    f32x16 acc = {};
    #pragma unroll 8
    for (int kc = 0; kc < KC; ++kc) {
      bf16x8 af = *reinterpret_cast<const bf16x8*>(ap + kc * 512);
      bf16x8 bf = *reinterpret_cast<const bf16x8*>(&sB[kc * 512 + l * 8]);
      acc = __builtin_amdgcn_mfma_f32_32x32x16_bf16(af, bf, acc, 0, 0, 0);
    }
    #pragma unroll
    for (int reg = 0; reg < 16; ++reg) {
      int m_loc = (reg & 3) + 8 * (reg >> 2) + 4 * hf;
      int m_glob = (mb << 5) + m_loc;
      float d = (xr - 2.0f * acc[reg]) + sxx[m_glob];
      if (m_glob == n_glob) d = 3.0e38f;
      KNN_TOP9_UPDATE(d, m_glob)
    }
  }
  KNN_MERGE16(cand)
}

// ---------------- exact f32 re-rank of 16 candidates -> top-9 (r2 regime) ---
template<int C>
__global__ __launch_bounds__(256) void rerank_kernel(const float* __restrict__ xin, long bstride,
                                                     int N, const float* __restrict__ xxg,
                                                     const int* __restrict__ cand,
                                                     int* __restrict__ idx_out) {
  __shared__ float xt[C][16];
  __shared__ float sd[16][17];
  __shared__ int   si[16][17];
  const int tid = threadIdx.x;
  const int b = blockIdx.y, n0 = blockIdx.x * 16;
  const float* xb = xin + (long)b * bstride;
  for (int i = tid; i < C * 16; i += 256) {
    int c = i >> 4, r = i & 15;
    xt[c][r] = xb[(long)c * N + n0 + r];
  }
  __syncthreads();
  const int r = tid >> 4, j = tid & 15;
  const int n = n0 + r;
  const int m = cand[(((long)b * N + n) << 4) + j];
  float dot = 0.f;
  #pragma unroll 4
  for (int c = 0; c < C; ++c)
    dot = fmaf(xt[c][r], xb[(long)c * N + m], dot);
  float d = (xxg[(long)b * N + n] - 2.0f * dot) + xxg[(long)b * N + m];
  if (m == n) d = 3.0e38f;
  sd[r][j] = d; si[r][j] = m;
  __syncthreads();
  int rank = 0;
  #pragma unroll
  for (int t = 0; t < 16; ++t) {
    float dd = sd[r][t]; int ii = si[r][t];
    if (dd < d || (dd == d && ii < m)) rank++;
  }
  if (rank < 9) idx_out[((long)b * N + n) * 9 + rank] = m;
}

// ------------------------------------------- W transposes (coalesced GEMMs) --
__global__ void prep_wt(const float* __restrict__ W, int Cin, int O,
                        float* __restrict__ At, float* __restrict__ W2t) {
  int i = blockIdx.x * 256 + threadIdx.x;
  if (i < O * Cin) {
    int o = i % O, c = i / O;
    float w1v = W[(long)o * 2 * Cin + c];
    float w2v = W[(long)o * 2 * Cin + Cin + c];
    At[(long)c * O + o]  = w1v - w2v;
    W2t[(long)c * O + o] = w2v;
  }
}

__global__ void transpose_wf(const float* __restrict__ wf, float* __restrict__ wfT) {
  int i = blockIdx.x * 256 + threadIdx.x;
  if (i < 512 * 1024) {
    int o = i & 1023, c = i >> 10;
    wfT[(long)c * 1024 + o] = wf[(long)o * 512 + c];
  }
}

// ------------------------------ GEMM: out[b][n][o] = sum_c Wt[c][o] in[b][c][n]
__global__ __launch_bounds__(256) void gemm_cn_no(const float* __restrict__ Wt,
                                                  int C, int O,
                                                  const float* __restrict__ in,
                                                  long in_bstride, int N,
                                                  float* __restrict__ out) {
  const int tid = threadIdx.x;
  const int n0 = blockIdx.x * 64, o0 = blockIdx.y * 64, b = blockIdx.z;
  __shared__ float wT[128][64];   // [c][o]
  __shared__ float inT[128][64];  // [c][n]
  for (int i = tid; i < C * 64; i += 256) {
    int c = i >> 6, j = i & 63;
    wT[c][j]  = Wt[(long)c * O + o0 + j];
    inT[c][j] = in[(long)b * in_bstride + (long)c * N + n0 + j];
  }
  __syncthreads();
  const int tr = tid >> 4, tc = tid & 15;
  float acc[4][4];
  #pragma unroll
  for (int i = 0; i < 4; ++i)
    #pragma unroll
    for (int j = 0; j < 4; ++j) acc[i][j] = 0.f;
  for (int c = 0; c < C; ++c) {
    float4 a4 = *reinterpret_cast<const float4*>(&wT[c][4 * tr]);
    float4 b4 = *reinterpret_cast<const float4*>(&inT[c][4 * tc]);
    float av[4] = {a4.x, a4.y, a4.z, a4.w};
    float bv[4] = {b4.x, b4.y, b4.z, b4.w};
    #pragma unroll
    for (int i = 0; i < 4; ++i)
      #pragma unroll
      for (int j = 0; j < 4; ++j) acc[i][j] = fmaf(av[i], bv[j], acc[i][j]);
  }
  #pragma unroll
  for (int j = 0; j < 4; ++j) {
    float4 st = make_float4(acc[0][j], acc[1][j], acc[2][j], acc[3][j]);
    *reinterpret_cast<float4*>(&out[((long)b * N + n0 + 4 * tc + j) * O + o0 + 4 * tr]) = st;
  }
}

// ------------------- single gather pass: stats + hmax + hmin per (n,o) ------
__global__ __launch_bounds__(256) void edge_pass(const float* __restrict__ u,
                                                 const float* __restrict__ v,
                                                 const int* __restrict__ idx,
                                                 int O, int N,
                                                 float* __restrict__ hmax,
                                                 float* __restrict__ hmin,
                                                 double* __restrict__ S1,
                                                 double* __restrict__ S2) {
  const int tid = threadIdx.x;
  const int n0 = blockIdx.x * 64, o0 = blockIdx.y * 64, b = blockIdx.z;
  __shared__ int sidx[64][9];
  __shared__ float4 redA[4][16];
  __shared__ float4 redB[4][16];
  for (int i = tid; i < 576; i += 256)
    ((int*)sidx)[i] = idx[((long)b * N + n0) * 9 + i];
  __syncthreads();
  const int nl = tid >> 4, oq = tid & 15;
  const long base = (long)b * N;
  const int ocol = o0 + 4 * oq;
  float4 s1 = make_float4(0.f, 0.f, 0.f, 0.f);
  float4 s2 = make_float4(0.f, 0.f, 0.f, 0.f);
  for (int g = 0; g < 4; ++g) {
    const int n = g * 16 + nl;
    const float4 u4 = *reinterpret_cast<const float4*>(&u[(base + n0 + n) * O + ocol]);
    float4 mx = make_float4(-3.0e38f, -3.0e38f, -3.0e38f, -3.0e38f);
    float4 mn = make_float4(3.0e38f, 3.0e38f, 3.0e38f, 3.0e38f);
    #pragma unroll
    for (int k = 0; k < 9; ++k) {
      int m = sidx[n][k];
      const float4 v4 = *reinterpret_cast<const float4*>(&v[(base + m) * O + ocol]);
      float hx = u4.x + v4.x, hy = u4.y + v4.y, hz = u4.z + v4.z, hw = u4.w + v4.w;
      s1.x += hx; s1.y += hy; s1.z += hz; s1.w += hw;
      s2.x = fmaf(hx, hx, s2.x); s2.y = fmaf(hy, hy, s2.y);
      s2.z = fmaf(hz, hz, s2.z); s2.w = fmaf(hw, hw, s2.w);
      mx.x = fmaxf(mx.x, hx); mx.y = fmaxf(mx.y, hy); mx.z = fmaxf(mx.z, hz); mx.w = fmaxf(mx.w, hw);
      mn.x = fminf(mn.x, hx); mn.y = fminf(mn.y, hy); mn.z = fminf(mn.z, hz); mn.w = fminf(mn.w, hw);
    }
    *reinterpret_cast<float4*>(&hmax[(base + n0 + n) * O + ocol]) = mx;
    *reinterpret_cast<float4*>(&hmin[(base + n0 + n) * O + ocol]) = mn;
  }
  s1.x += __shfl_xor(s1.x, 16); s1.y += __shfl_xor(s1.y, 16);
  s1.z += __shfl_xor(s1.z, 16); s1.w += __shfl_xor(s1.w, 16);
  s2.x += __shfl_xor(s2.x, 16); s2.y += __shfl_xor(s2.y, 16);
  s2.z += __shfl_xor(s2.z, 16); s2.w += __shfl_xor(s2.w, 16);
  s1.x += __shfl_xor(s1.x, 32); s1.y += __shfl_xor(s1.y, 32);
  s1.z += __shfl_xor(s1.z, 32); s1.w += __shfl_xor(s1.w, 32);
  s2.x += __shfl_xor(s2.x, 32); s2.y += __shfl_xor(s2.y, 32);
  s2.z += __shfl_xor(s2.z, 32); s2.w += __shfl_xor(s2.w, 32);
  if ((tid & 48) == 0) { redA[tid >> 6][oq] = s1; redB[tid >> 6][oq] = s2; }
  __syncthreads();
  if (tid < 16) {
    float4 a = redA[0][tid], bb = redB[0][tid];
    #pragma unroll
    for (int ww = 1; ww < 4; ++ww) {
      float4 t1 = redA[ww][tid], t2 = redB[ww][tid];
      a.x += t1.x; a.y += t1.y; a.z += t1.z; a.w += t1.w;
      bb.x += t2.x; bb.y += t2.y; bb.z += t2.z; bb.w += t2.w;
    }
    int o = o0 + 4 * tid;
    atomicAdd(&S1[o + 0], (double)a.x);  atomicAdd(&S1[o + 1], (double)a.y);
    atomicAdd(&S1[o + 2], (double)a.z);  atomicAdd(&S1[o + 3], (double)a.w);
    atomicAdd(&S2[o + 0], (double)bb.x); atomicAdd(&S2[o + 1], (double)bb.y);
    atomicAdd(&S2[o + 2], (double)bb.z); atomicAdd(&S2[o + 3], (double)bb.w);
  }
}

__global__ void finalize_scale(const double* __restrict__ S1, const double* __restrict__ S2,
                               const float* __restrict__ g, const float* __restrict__ beta,
                               double invM, int O, float* __restrict__ scale,
                               float* __restrict__ shift) {
  int o = blockIdx.x * 256 + threadIdx.x;
  if (o < O) {
    double mean = S1[o] * invM;
    double var = S2[o] * invM - mean * mean;
    double sc = (double)g[o] / sqrt(var + 1e-5);
    scale[o] = (float)sc;
    shift[o] = (float)((double)beta[o] - mean * sc);
  }
}

// ------------------- elementwise finalize + transpose to (B,O,N) ------------
__global__ __launch_bounds__(256) void edge_out(const float* __restrict__ hmax,
                                                const float* __restrict__ hmin,
                                                const float* __restrict__ scale,
                                                const float* __restrict__ shift,
                                                int O, int N,
                                                float* __restrict__ outp, long out_bstride) {
  const int tid = threadIdx.x;
  const int b = blockIdx.y, n0 = blockIdx.x * 64;
  __shared__ float yt[64][65];
  const int ol = tid & 63, nl = tid >> 6;
  const long base = (long)b * N;
  for (int oc = 0; oc < O; oc += 64) {
    float sc = scale[oc + ol], sh = shift[oc + ol];
    __syncthreads();
    for (int ng = 0; ng < 16; ++ng) {
      int n = ng * 4 + nl;
      long off = (base + n0 + n) * O + oc + ol;
      float hv = (sc >= 0.f) ? hmax[off] : hmin[off];
      float y = sc * hv + sh;
      yt[ol][n] = LEAKY(y);
    }
    __syncthreads();
    for (int rr = 0; rr < 16; ++rr) {
      int r = rr * 4 + nl;
      outp[(long)b * out_bstride + (long)(oc + r) * N + n0 + ol] = yt[r][ol];
    }
  }
}

// -------------------- fusion 512->1024: GEMM once, store h + stats ----------
__global__ __launch_bounds__(256) void fusion_gemm(const float* __restrict__ wfT,
                                                   const float* __restrict__ bfb,
                                                   const float* __restrict__ feat, int N,
                                                   float* __restrict__ h,
                                                   double* __restrict__ S1,
                                                   double* __restrict__ S2) {
  const int tid = threadIdx.x;
  const int n0 = blockIdx.x * 64, o0 = blockIdx.y * 64, b = blockIdx.z;
  __shared__ float wT[64][64];
  __shared__ float fT[64][64];
  const int tr = tid >> 4, tc = tid & 15;
  float acc[4][4];
  #pragma unroll
  for (int i = 0; i < 4; ++i)
    #pragma unroll
    for (int j = 0; j < 4; ++j) acc[i][j] = 0.f;
  for (int cc = 0; cc < 8; ++cc) {
    __syncthreads();
    for (int i = tid; i < 4096; i += 256) {
      int ci = i >> 6, j = i & 63;
      wT[ci][j] = wfT[(long)(cc * 64 + ci) * 1024 + o0 + j];
      fT[ci][j] = feat[((long)b * 512 + cc * 64 + ci) * N + n0 + j];
    }
    __syncthreads();
    #pragma unroll
    for (int ci = 0; ci < 64; ++ci) {
      float4 a4 = *reinterpret_cast<const float4*>(&wT[ci][4 * tr]);
      float4 b4 = *reinterpret_cast<const float4*>(&fT[ci][4 * tc]);
      float av[4] = {a4.x, a4.y, a4.z, a4.w};
      float bv[4] = {b4.x, b4.y, b4.z, b4.w};
      #pragma unroll
      for (int i = 0; i < 4; ++i)
        #pragma unroll
        for (int j = 0; j < 4; ++j) acc[i][j] = fmaf(av[i], bv[j], acc[i][j]);
    }
  }
  #pragma unroll
  for (int i = 0; i < 4; ++i) {
    int o = o0 + 4 * tr + i;
    float bias = bfb[o];
    float4 hv = make_float4(acc[i][0] + bias, acc[i][1] + bias,
                            acc[i][2] + bias, acc[i][3] + bias);
    *reinterpret_cast<float4*>(&h[((long)b * 1024 + o) * N + n0 + 4 * tc]) = hv;
    float s1 = hv.x + hv.y + hv.z + hv.w;
    float s2 = hv.x * hv.x + hv.y * hv.y + hv.z * hv.z + hv.w * hv.w;
    for (int off = 1; off < 16; off <<= 1) {
      s1 += __shfl_xor(s1, off, 16);
      s2 += __shfl_xor(s2, off, 16);
    }
    if (tc == 0) { atomicAdd(&S1[o], (double)s1); atomicAdd(&S2[o], (double)s2); }
  }
}

// --------------- BN+leaky+max/mean pool over N, one wave per (b,o) row ------
__global__ __launch_bounds__(256) void pool_kernel(const float* __restrict__ h,
                                                   const float* __restrict__ scale,
                                                   const float* __restrict__ shift,
                                                   float* __restrict__ x1x2) {
  int gw = (blockIdx.x * 256 + threadIdx.x) >> 6;
  int lane = threadIdx.x & 63;
  int b = gw >> 10, o = gw & 1023;
  const float4* row = reinterpret_cast<const float4*>(h + ((long)b * 1024 + o) * 4096);
  float sc = scale[o], sh = shift[o];
  float mx = -3.0e38f, sm = 0.f;
  for (int j = 0; j < 16; ++j) {
    float4 hv = row[j * 64 + lane];
    float y0 = LEAKY(sc * hv.x + sh), y1 = LEAKY(sc * hv.y + sh);
    float y2 = LEAKY(sc * hv.z + sh), y3 = LEAKY(sc * hv.w + sh);
    mx = fmaxf(mx, fmaxf(fmaxf(y0, y1), fmaxf(y2, y3)));
    sm += (y0 + y1) + (y2 + y3);
  }
  #pragma unroll
  for (int off = 1; off < 64; off <<= 1) {
    mx = fmaxf(mx, __shfl_xor(mx, off));
    sm += __shfl_xor(sm, off);
  }
  if (lane == 0) {
    x1x2[(long)b * 2048 + o] = mx;
    x1x2[(long)b * 2048 + 1024 + o] = sm * (1.f / 4096.f);
  }
}

// ----------------------------------------------------------- classifier -----
__global__ __launch_bounds__(256) void fc_kernel(const float* __restrict__ in, int Cin, int O,
                                                 const float* __restrict__ W,
                                                 const float* __restrict__ bias,
                                                 const float* __restrict__ g,
                                                 const float* __restrict__ beta,
                                                 float* __restrict__ outp, int do_bn) {
  const int tid = threadIdx.x;
  const int o = blockIdx.x * 32 + (tid >> 3);
  const int bb = tid & 7;
  const int oc = (o < O) ? o : (O - 1);
  const float* ir = in + (long)bb * Cin;
  const float* wr = W + (long)oc * Cin;
  float dot = 0.f;
  for (int c = 0; c < Cin; c += 4) {
    float4 a = *reinterpret_cast<const float4*>(&ir[c]);
    float4 w = *reinterpret_cast<const float4*>(&wr[c]);
    dot += a.x * w.x + a.y * w.y + a.z * w.z + a.w * w.w;
  }
  float h = dot + bias[oc];
  if (do_bn) {
    float s = h;
    s += __shfl_xor(s, 1, 8); s += __shfl_xor(s, 2, 8); s += __shfl_xor(s, 4, 8);
    float mean = s * 0.125f;
    float dv = (h - mean) * (h - mean);
    dv += __shfl_xor(dv, 1, 8); dv += __shfl_xor(dv, 2, 8); dv += __shfl_xor(dv, 4, 8);
    float var = dv * 0.125f;
    float y = (h - mean) * (float)(1.0 / sqrt((double)var + 1e-5)) * g[oc] + beta[oc];
    h = LEAKY(y);
  }
  if (o < O) outp[(long)bb * O + o] = h;
}

// ---------------------------------------------------------------- driver ----
extern "C" void kernel_launch(void* const* d_in, const int* in_sizes, int n_in,
                              void* d_out, int out_size, void* d_ws, size_t ws_size,
                              hipStream_t stream) {
  const int B = 8, N = 4096;
  const float* x   = (const float*)d_in[0];
  const float* w1 = (const float*)d_in[2];  const float* g1 = (const float*)d_in[3];  const float* b1 = (const float*)d_in[4];
  const float* w2 = (const float*)d_in[5];  const float* g2 = (const float*)d_in[6];  const float* b2 = (const float*)d_in[7];
  const float* w3 = (const float*)d_in[8];  const float* g3 = (const float*)d_in[9];  const float* b3 = (const float*)d_in[10];
  const float* w4 = (const float*)d_in[11]; const float* g4 = (const float*)d_in[12]; const float* b4 = (const float*)d_in[13];
  const float* wf = (const float*)d_in[14]; const float* bfv = (const float*)d_in[15];
  const float* gf = (const float*)d_in[16]; const float* betaf = (const float*)d_in[17];
  const float* wc1 = (const float*)d_in[18]; const float* bc1 = (const float*)d_in[19];
  const float* gc1 = (const float*)d_in[20]; const float* betac1 = (const float*)d_in[21];
  const float* wc2 = (const float*)d_in[22]; const float* bc2 = (const float*)d_in[23];
  const float* gc2 = (const float*)d_in[24]; const float* betac2 = (const float*)d_in[25];
  const float* wc3 = (const float*)d_in[26]; const float* bc3 = (const float*)d_in[27];

  char* p = (char*)d_ws;
  auto alloc = [&](size_t bytes) -> char* {
    char* r = p;
    p += (bytes + 255) & ~(size_t)255;
    return r;
  };
  float* feat  = (float*)alloc((size_t)B * 512 * N * 4);   // 67.1MB
  int*   idx   = (int*)  alloc((size_t)B * N * 9 * 4);
  int*   cand  = (int*)  alloc((size_t)B * N * 16 * 4);    // 2.1MB
  float* xxg   = (float*)alloc((size_t)B * N * 4);
  // R region (4 x 33.5MB): u|v|hmax|hmin during edge phase; overlays:
  //   kNN: packR spans u+v, packC spans hmax+hmin ; fusion: h spans all four
  float* u     = (float*)alloc((size_t)B * N * 256 * 4);
  float* v     = (float*)alloc((size_t)B * N * 256 * 4);
  float* hmax  = (float*)alloc((size_t)B * N * 256 * 4);
  float* hmin  = (float*)alloc((size_t)B * N * 256 * 4);
  float* hbuf  = u;
  ushort* packR = (ushort*)u;
  ushort* packC = (ushort*)hmax;
  float* At    = (float*)alloc(128 * 256 * 4);
  float* W2t   = (float*)alloc(128 * 256 * 4);
  float* wfT   = (float*)alloc((size_t)512 * 1024 * 4);
  double* S1   = (double*)alloc(1024 * 8);
  double* S2   = (double*)alloc(1024 * 8);
  float* scale = (float*)alloc(1024 * 4);
  float* shift = (float*)alloc(1024 * 4);
  float* x1x2  = (float*)alloc((size_t)B * 2048 * 4);
  float* h1    = (float*)alloc((size_t)B * 512 * 4);
  float* h2    = (float*)alloc((size_t)B * 256 * 4);

  dim3 gknn(N / 32, B);
  dim3 grr(N / 16, B);
  dim3 gxx(N / 256, B);

  transpose_wf<<<2048, 256, 0, stream>>>(wf, wfT);

  auto edge = [&](const float* inp, long in_bstride, int Cin, int O, const float* W,
                  const float* g, const float* beta, int c0) {
    prep_wt<<<(O * Cin + 255) / 256, 256, 0, stream>>>(W, Cin, O, At, W2t);
    dim3 gg(N / 64, O / 64, B);
    gemm_cn_no<<<gg, 256, 0, stream>>>(At, Cin, O, inp, in_bstride, N, u);
    gemm_cn_no<<<gg, 256, 0, stream>>>(W2t, Cin, O, inp, in_bstride, N, v);
    hipMemsetAsync(S1, 0, O * 8, stream);
    hipMemsetAsync(S2, 0, O * 8, stream);
    edge_pass<<<gg, 256, 0, stream>>>(u, v, idx, O, N, hmax, hmin, S1, S2);
    finalize_scale<<<(O + 255) / 256, 256, 0, stream>>>(S1, S2, g, beta,
                                                        1.0 / ((double)B * N * 9), O, scale, shift);
    edge_out<<<dim3(N / 64, B), 256, 0, stream>>>(hmax, hmin, scale, shift, O, N,
                                                  feat + (long)c0 * N, (long)512 * N);
  };

  // layer 1: C=3, K'=18 -> KC=2
  xx_kernel<3><<<gxx, 256, 0, stream>>>(x, (long)3 * N, N, xxg);
  pack_kernel<3, 2><<<gknn, 256, 0, stream>>>(x, (long)3 * N, N, packR, packC);
  knn_mfma_reg<2><<<gknn, 256, 0, stream>>>(packR, packC, xxg, N, cand);
  rerank_kernel<3><<<grr, 256, 0, stream>>>(x, (long)3 * N, N, xxg, cand, idx);
  edge(x, (long)3 * N, 3, 64, w1, g1, b1, 0);

  // layer 2: C=64, K'=384 -> KC=24
  xx_kernel<64><<<gxx, 256, 0, stream>>>(feat, (long)512 * N, N, xxg);
  pack_kernel<64, 24><<<gknn, 256, 0, stream>>>(feat, (long)512 * N, N, packR, packC);
  knn_mfma_reg<24><<<gknn, 256, 0, stream>>>(packR, packC, xxg, N, cand);
  rerank_kernel<64><<<grr, 256, 0, stream>>>(feat, (long)512 * N, N, xxg, cand, idx);
  edge(feat, (long)512 * N, 64, 64, w2, g2, b2, 64);

  // layer 3: C=64
  xx_kernel<64><<<gxx, 256, 0, stream>>>(feat + (long)64 * N, (long)512 * N, N, xxg);
  pack_kernel<64, 24><<<gknn, 256, 0, stream>>>(feat + (long)64 * N, (long)512 * N, N, packR, packC);
  knn_mfma_reg<24><<<gknn, 256, 0, stream>>>(packR, packC, xxg, N, cand);
  rerank_kernel<64><<<grr, 256, 0, stream>>>(feat + (long)64 * N, (long)512 * N, N, xxg, cand, idx);
  edge(feat + (long)64 * N, (long)512 * N, 64, 128, w3, g3, b3, 128);

  // layer 4: C=128, K'=768 -> KC=48 (B-frags in LDS)
  xx_kernel<128><<<gxx, 256, 0, stream>>>(feat + (long)128 * N, (long)512 * N, N, xxg);
  pack_kernel<128, 48><<<gknn, 256, 0, stream>>>(feat + (long)128 * N, (long)512 * N, N, packR, packC);
  knn_mfma_lds<48><<<gknn, 256, 0, stream>>>(packR, packC, xxg, N, cand);
  rerank_kernel<128><<<grr, 256, 0, stream>>>(feat + (long)128 * N, (long)512 * N, N, xxg, cand, idx);
  edge(feat + (long)128 * N, (long)512 * N, 128, 256, w4, g4, b4, 256);

  // fusion conv 512->1024 (single GEMM, h stored over dead edge buffers)
  hipMemsetAsync(S1, 0, 1024 * 8, stream);
  hipMemsetAsync(S2, 0, 1024 * 8, stream);
  dim3 gfu(N / 64, 16, B);
  fusion_gemm<<<gfu, 256, 0, stream>>>(wfT, bfv, feat, N, hbuf, S1, S2);
  finalize_scale<<<4, 256, 0, stream>>>(S1, S2, gf, betaf, 1.0 / ((double)B * N), 1024, scale, shift);
  pool_kernel<<<2048, 256, 0, stream>>>(hbuf, scale, shift, x1x2);

  fc_kernel<<<16, 256, 0, stream>>>(x1x2, 2048, 512, wc1, bc1, gc1, betac1, h1, 1);
  fc_kernel<<<8, 256, 0, stream>>>(h1, 512, 256, wc2, bc2, gc2, betac2, h2, 1);
  fc_kernel<<<2, 256, 0, stream>>>(h2, 256, 40, wc3, bc3, nullptr, nullptr, (float*)d_out, 0);
}

// Round 6
// 4297.687 us; speedup vs baseline: 1.4791x; 1.0526x over previous
//
#include <hip/hip_runtime.h>
#include <math.h>
#include <float.h>

// DGCNN forward, MI355X, all f32 except kNN distance GEMM (3-term split-bf16 MFMA).
// h_edge = (W1-W2)@x_i + W2@x_j = u + v[idx]  (9x less GEMM work).
// kNN two-phase: (1) MFMA approx distances (K'=3C), 32-candidate pool per row,
//                (2) exact f32 re-rank of the 32 (r2-proven rounding) -> top-9.
// knn_v2: 4 waves x 128 rows/block, B-frags in regs, A-tile dbuf-staged in LDS
//         via global_load_lds (shared by all waves), z-split over m-halves.

#define LEAKY(y) ((y) >= 0.f ? (y) : 0.2f * (y))

using f32x16 = __attribute__((ext_vector_type(16))) float;
using bf16x8 = __attribute__((ext_vector_type(8))) __bf16;
using short8v = __attribute__((ext_vector_type(8))) short;

__device__ inline ushort f2bf(float x) {
  unsigned u = __float_as_uint(x);
  unsigned r = (u + 0x7fff + ((u >> 16) & 1)) >> 16;
  return (ushort)r;
}

// ------------------------------------------------------------- xx = sum x^2 --
template<int C>
__global__ void xx_kernel(const float* __restrict__ xin, long bstride, int N,
                          float* __restrict__ xxg) {
  int n = blockIdx.x * 256 + threadIdx.x;
  int b = blockIdx.y;
  if (n < N) {
    const float* xb = xin + (long)b * bstride;
    float s = 0.f;
    #pragma unroll
    for (int c = 0; c < C; ++c) { float t = xb[(long)c * N + n]; s += t * t; }
    xxg[(long)b * N + n] = s;
  }
}

// ---------------------------------------- pack points into MFMA frag order ---
// 3-term: x = hi + mid (+eps). R slices (query): [hi, hi, mid];
//                              C slices (cand):  [hi, mid, hi].
// layout: [(b*PB + pb)*KC + kc]*512 + lane*8 + e ; pt = pb*32 + (lane&31),
//         k' = kc*16 + (lane>>5)*8 + e ; slice s = k'/C, channel c = k'%C.
template<int C, int KC>
__global__ __launch_bounds__(256) void pack3_kernel(const float* __restrict__ xin, long bstride,
                                                    int N, ushort* __restrict__ packR,
                                                    ushort* __restrict__ packC) {
  __shared__ float xt[C][32];
  const int tid = threadIdx.x;
  const int pb = blockIdx.x, b = blockIdx.y;
  for (int i = tid; i < C * 32; i += 256) {
    int c = i >> 5, j = i & 31;
    xt[c][j] = xin[(long)b * bstride + (long)c * N + pb * 32 + j];
  }
  __syncthreads();
  const int PB = N >> 5;
  for (int it = tid; it < KC * 64; it += 256) {
    int kc = it >> 6, l = it & 63;
    int pt = l & 31;
    union { ushort u[8]; short8v v; } R, Cc;
    #pragma unroll
    for (int e = 0; e < 8; ++e) {
      int kp = kc * 16 + ((l >> 5) << 3) + e;
      ushort rv = 0, cv = 0;
      if (kp < 3 * C) {
        int s = kp / C, c = kp % C;
        float xv = xt[c][pt];
        ushort hi = f2bf(xv);
        float hif = __uint_as_float((unsigned)hi << 16);
        ushort mid = f2bf(xv - hif);
        rv = (s == 2) ? mid : hi;
        cv = (s == 1) ? mid : hi;
      }
      R.u[e] = rv; Cc.u[e] = cv;
    }
    long off = (((long)b * PB + pb) * KC + kc) * 512 + l * 8;
    *reinterpret_cast<short8v*>(&packR[off]) = R.v;
    *reinterpret_cast<short8v*>(&packC[off]) = Cc.v;
  }
}

// ----------------------------------------------------- kNN phase 1 (MFMA) ---
#define KNN_TOP9_UPDATE(d_, gi_)                                                 \
  if (d_ < td[8] || (d_ == td[8] && gi_ < ti[8])) {                              \
    td[8] = d_; ti[8] = gi_;                                                     \
    _Pragma("unroll")                                                            \
    for (int s_ = 8; s_ > 0; --s_) {                                             \
      bool sw_ = (td[s_] < td[s_ - 1]) || (td[s_] == td[s_ - 1] && ti[s_] < ti[s_ - 1]); \
      if (sw_) {                                                                 \
        float tf_ = td[s_]; td[s_] = td[s_ - 1]; td[s_ - 1] = tf_;               \
        int tn_ = ti[s_]; ti[s_] = ti[s_ - 1]; ti[s_ - 1] = tn_;                 \
      }                                                                          \
    }                                                                            \
  }

// grid (N/128, B, 2): block = 4 waves x 128 query rows; z = m-half.
// Each wave: B-frags of its 32 rows in regs; A-tile (32 cands) dbuf-LDS shared.
// Emits per row: top-16 of its 18-pool into cand[row*32 + z*16 ..].
template<int KC>
__global__ __launch_bounds__(256, 2) void knn_v2(const ushort* __restrict__ packR,
                                                 const ushort* __restrict__ packC,
                                                 const float* __restrict__ xxg,
                                                 int N, int* __restrict__ cand) {
  constexpr int SA_ELEMS = KC * 512;
  __shared__ float sxx[4608];              // [0..4095] norms; post-sweep: merge pool
  __shared__ ushort sA[2][SA_ELEMS];
  const int tid = threadIdx.x;
  const int b = blockIdx.y, rowblk = blockIdx.x, z = blockIdx.z;
  const int w = tid >> 6, l = tid & 63;
  const int lane31 = l & 31, hf = l >> 5;
  const int PB = N >> 5;                   // 128 m-blocks
  const int HALF = PB >> 1;                // 64 per z

  for (int i = tid; i < N; i += 256) sxx[i] = xxg[(long)b * N + i];

  // B-fragments: wave w owns rows (rowblk*4 + w)*32 .. +31
  const ushort* rp = packR + (((long)b * PB + rowblk * 4 + w) * (long)KC) * 512 + l * 8;
  bf16x8 bfr[KC];
  #pragma unroll
  for (int kc = 0; kc < KC; ++kc)
    bfr[kc] = *reinterpret_cast<const bf16x8*>(rp + kc * 512);

  const ushort* srcb = packC + ((long)b * PB) * (long)SA_ELEMS;
  const int mb0 = z * HALF;

  // prologue: stage m-block mb0 into buf 0
  {
    const ushort* src = srcb + (long)mb0 * SA_ELEMS;
    for (int i = tid * 8; i < SA_ELEMS; i += 2048)
      __builtin_amdgcn_global_load_lds(
          (const __attribute__((address_space(1))) void*)(src + i),
          (__attribute__((address_space(3))) void*)(&sA[0][i]), 16, 0, 0);
  }
  __syncthreads();                          // drains vmcnt (syncthreads semantics)

  const int n_glob = rowblk * 128 + w * 32 + lane31;
  const float xr = sxx[n_glob];

  float td[9]; int ti[9];
  #pragma unroll
  for (int s = 0; s < 9; ++s) { td[s] = 3.0e38f; ti[s] = 0x7fffffff; }

  int cur = 0;
  for (int t = 0; t < HALF; ++t) {
    const int mb = mb0 + t;
    if (t + 1 < HALF) {                     // async prefetch next A-tile
      const ushort* src = srcb + (long)(mb + 1) * SA_ELEMS;
      for (int i = tid * 8; i < SA_ELEMS; i += 2048)
        __builtin_amdgcn_global_load_lds(
            (const __attribute__((address_space(1))) void*)(src + i),
            (__attribute__((address_space(3))) void*)(&sA[cur ^ 1][i]), 16, 0, 0);
    }
    f32x16 acc = {};
    #pragma unroll
    for (int kc = 0; kc < KC; ++kc) {
      bf16x8 af = *reinterpret_cast<const bf16x8*>(&sA[cur][kc * 512 + l * 8]);
      acc = __builtin_amdgcn_mfma_f32_32x32x16_bf16(af, bfr[kc], acc, 0, 0, 0);
    }
    #pragma unroll
    for (int reg = 0; reg < 16; ++reg) {
      int m_loc = (reg & 3) + 8 * (reg >> 2) + 4 * hf;
      int m_glob = (mb << 5) + m_loc;
      float d = (xr - 2.0f * acc[reg]) + sxx[m_glob];
      if (m_glob == n_glob) d = 3.0e38f;
      KNN_TOP9_UPDATE(d, m_glob)
    }
    __syncthreads();                        // staged tile ready; buf[cur] free
    cur ^= 1;
  }

  // merge: per row 2 lists (hf 0/1) x 9 -> top-16. Pool aliases sxx (dead now).
  float (*mD)[18] = (float(*)[18])sxx;
  int   (*mI)[18] = (int(*)[18])(sxx + 2304);
  __syncthreads();
  const int row = w * 32 + lane31;
  #pragma unroll
  for (int s = 0; s < 9; ++s) {
    mD[row][hf * 9 + s] = td[s];
    mI[row][hf * 9 + s] = ti[s];
  }
  __syncthreads();
  if (tid < 128) {
    int p0 = 0, p1 = 0;
    const long ob = ((long)b * N + rowblk * 128 + tid) * 32 + z * 16;
    for (int s = 0; s < 16; ++s) {
      float d0 = (p0 < 9) ? mD[tid][p0] : 3.3e38f;
      int   i0 = (p0 < 9) ? mI[tid][p0] : 0x7fffffff;
      float d1 = (p1 < 9) ? mD[tid][9 + p1] : 3.3e38f;
      int   i1 = (p1 < 9) ? mI[tid][9 + p1] : 0x7fffffff;
      bool t0 = (d0 < d1) || (d0 == d1 && i0 < i1);
      cand[ob + s] = t0 ? i0 : i1;
      if (t0) ++p0; else ++p1;
    }
  }
}

// ---------------- exact f32 re-rank of 32 candidates -> top-9 (r2 regime) ---
template<int C>
__global__ __launch_bounds__(256) void rerank_kernel(const float* __restrict__ xin, long bstride,
                                                     int N, const float* __restrict__ xxg,
                                                     const int* __restrict__ cand,
                                                     int* __restrict__ idx_out) {
  __shared__ float xt[C][8];
  __shared__ float sd[8][33];
  __shared__ int   si[8][33];
  const int tid = threadIdx.x;
  const int b = blockIdx.y, n0 = blockIdx.x * 8;
  const float* xb = xin + (long)b * bstride;
  for (int i = tid; i < C * 8; i += 256) {
    int c = i >> 3, r = i & 7;
    xt[c][r] = xb[(long)c * N + n0 + r];
  }
  __syncthreads();
  const int r = tid >> 5, j = tid & 31;
  const int n = n0 + r;
  const int m = cand[(((long)b * N + n) << 5) + j];
  float dot = 0.f;
  #pragma unroll 4
  for (int c = 0; c < C; ++c)
    dot = fmaf(xt[c][r], xb[(long)c * N + m], dot);
  float d = (xxg[(long)b * N + n] - 2.0f * dot) + xxg[(long)b * N + m];
  if (m == n) d = 3.0e38f;
  sd[r][j] = d; si[r][j] = m;
  __syncthreads();
  int rank = 0;
  #pragma unroll
  for (int t = 0; t < 32; ++t) {
    float dd = sd[r][t]; int ii = si[r][t];
    if (dd < d || (dd == d && ii < m)) rank++;
  }
  if (rank < 9) idx_out[((long)b * N + n) * 9 + rank] = m;
}

// ------------------------------------------- W transposes (coalesced GEMMs) --
__global__ void prep_wt(const float* __restrict__ W, int Cin, int O,
                        float* __restrict__ At, float* __restrict__ W2t) {
  int i = blockIdx.x * 256 + threadIdx.x;
  if (i < O * Cin) {
    int o = i % O, c = i / O;
    float w1v = W[(long)o * 2 * Cin + c];
    float w2v = W[(long)o * 2 * Cin + Cin + c];
    At[(long)c * O + o]  = w1v - w2v;
    W2t[(long)c * O + o] = w2v;
  }
}

__global__ void transpose_wf(const float* __restrict__ wf, float* __restrict__ wfT) {
  int i = blockIdx.x * 256 + threadIdx.x;
  if (i < 512 * 1024) {
    int o = i & 1023, c = i >> 10;
    wfT[(long)c * 1024 + o] = wf[(long)o * 512 + c];
  }
}

// ------------------------------ GEMM: out[b][n][o] = sum_c Wt[c][o] in[b][c][n]
__global__ __launch_bounds__(256) void gemm_cn_no(const float* __restrict__ Wt,
                                                  int C, int O,
                                                  const float* __restrict__ in,
                                                  long in_bstride, int N,
                                                  float* __restrict__ out) {
  const int tid = threadIdx.x;
  const int n0 = blockIdx.x * 64, o0 = blockIdx.y * 64, b = blockIdx.z;
  __shared__ float wT[128][64];   // [c][o]
  __shared__ float inT[128][64];  // [c][n]
  for (int i = tid; i < C * 64; i += 256) {
    int c = i >> 6, j = i & 63;
    wT[c][j]  = Wt[(long)c * O + o0 + j];
    inT[c][j] = in[(long)b * in_bstride + (long)c * N + n0 + j];
  }
  __syncthreads();
  const int tr = tid >> 4, tc = tid & 15;
  float acc[4][4];
  #pragma unroll
  for (int i = 0; i < 4; ++i)
    #pragma unroll
    for (int j = 0; j < 4; ++j) acc[i][j] = 0.f;
  for (int c = 0; c < C; ++c) {
    float4 a4 = *reinterpret_cast<const float4*>(&wT[c][4 * tr]);
    float4 b4 = *reinterpret_cast<const float4*>(&inT[c][4 * tc]);
    float av[4] = {a4.x, a4.y, a4.z, a4.w};
    float bv[4] = {b4.x, b4.y, b4.z, b4.w};
    #pragma unroll
    for (int i = 0; i < 4; ++i)
      #pragma unroll
      for (int j = 0; j < 4; ++j) acc[i][j] = fmaf(av[i], bv[j], acc[i][j]);
  }
  #pragma unroll
  for (int j = 0; j < 4; ++j) {
    float4 st = make_float4(acc[0][j], acc[1][j], acc[2][j], acc[3][j]);
    *reinterpret_cast<float4*>(&out[((long)b * N + n0 + 4 * tc + j) * O + o0 + 4 * tr]) = st;
  }
}

// ------------------- single gather pass: stats + hmax + hmin per (n,o) ------
__global__ __launch_bounds__(256) void edge_pass(const float* __restrict__ u,
                                                 const float* __restrict__ v,
                                                 const int* __restrict__ idx,
                                                 int O, int N,
                                                 float* __restrict__ hmax,
                                                 float* __restrict__ hmin,
                                                 double* __restrict__ S1,
                                                 double* __restrict__ S2) {
  const int tid = threadIdx.x;
  const int n0 = blockIdx.x * 64, o0 = blockIdx.y * 64, b = blockIdx.z;
  __shared__ int sidx[64][9];
  __shared__ float4 redA[4][16];
  __shared__ float4 redB[4][16];
  for (int i = tid; i < 576; i += 256)
    ((int*)sidx)[i] = idx[((long)b * N + n0) * 9 + i];
  __syncthreads();
  const int nl = tid >> 4, oq = tid & 15;
  const long base = (long)b * N;
  const int ocol = o0 + 4 * oq;
  float4 s1 = make_float4(0.f, 0.f, 0.f, 0.f);
  float4 s2 = make_float4(0.f, 0.f, 0.f, 0.f);
  for (int g = 0; g < 4; ++g) {
    const int n = g * 16 + nl;
    const float4 u4 = *reinterpret_cast<const float4*>(&u[(base + n0 + n) * O + ocol]);
    float4 mx = make_float4(-3.0e38f, -3.0e38f, -3.0e38f, -3.0e38f);
    float4 mn = make_float4(3.0e38f, 3.0e38f, 3.0e38f, 3.0e38f);
    #pragma unroll
    for (int k = 0; k < 9; ++k) {
      int m = sidx[n][k];
      const float4 v4 = *reinterpret_cast<const float4*>(&v[(base + m) * O + ocol]);
      float hx = u4.x + v4.x, hy = u4.y + v4.y, hz = u4.z + v4.z, hw = u4.w + v4.w;
      s1.x += hx; s1.y += hy; s1.z += hz; s1.w += hw;
      s2.x = fmaf(hx, hx, s2.x); s2.y = fmaf(hy, hy, s2.y);
      s2.z = fmaf(hz, hz, s2.z); s2.w = fmaf(hw, hw, s2.w);
      mx.x = fmaxf(mx.x, hx); mx.y = fmaxf(mx.y, hy); mx.z = fmaxf(mx.z, hz); mx.w = fmaxf(mx.w, hw);
      mn.x = fminf(mn.x, hx); mn.y = fminf(mn.y, hy); mn.z = fminf(mn.z, hz); mn.w = fminf(mn.w, hw);
    }
    *reinterpret_cast<float4*>(&hmax[(base + n0 + n) * O + ocol]) = mx;
    *reinterpret_cast<float4*>(&hmin[(base + n0 + n) * O + ocol]) = mn;
  }
  s1.x += __shfl_xor(s1.x, 16); s1.y += __shfl_xor(s1.y, 16);
  s1.z += __shfl_xor(s1.z, 16); s1.w += __shfl_xor(s1.w, 16);
  s2.x += __shfl_xor(s2.x, 16); s2.y += __shfl_xor(s2.y, 16);
  s2.z += __shfl_xor(s2.z, 16); s2.w += __shfl_xor(s2.w, 16);
  s1.x += __shfl_xor(s1.x, 32); s1.y += __shfl_xor(s1.y, 32);
  s1.z += __shfl_xor(s1.z, 32); s1.w += __shfl_xor(s1.w, 32);
  s2.x += __shfl_xor(s2.x, 32); s2.y += __shfl_xor(s2.y, 32);
  s2.z += __shfl_xor(s2.z, 32); s2.w += __shfl_xor(s2.w, 32);
  if ((tid & 48) == 0) { redA[tid >> 6][oq] = s1; redB[tid >> 6][oq] = s2; }
  __syncthreads();
  if (tid < 16) {
    float4 a = redA[0][tid], bb = redB[0][tid];
    #pragma unroll
    for (int ww = 1; ww < 4; ++ww) {
      float4 t1 = redA[ww][tid], t2 = redB[ww][tid];
      a.x += t1.x; a.y += t1.y; a.z += t1.z; a.w += t1.w;
      bb.x += t2.x; bb.y += t2.y; bb.z += t2.z; bb.w += t2.w;
    }
    int o = o0 + 4 * tid;
    atomicAdd(&S1[o + 0], (double)a.x);  atomicAdd(&S1[o + 1], (double)a.y);
    atomicAdd(&S1[o + 2], (double)a.z);  atomicAdd(&S1[o + 3], (double)a.w);
    atomicAdd(&S2[o + 0], (double)bb.x); atomicAdd(&S2[o + 1], (double)bb.y);
    atomicAdd(&S2[o + 2], (double)bb.z); atomicAdd(&S2[o + 3], (double)bb.w);
  }
}

__global__ void finalize_scale(const double* __restrict__ S1, const double* __restrict__ S2,
                               const float* __restrict__ g, const float* __restrict__ beta,
                               double invM, int O, float* __restrict__ scale,
                               float* __restrict__ shift) {
  int o = blockIdx.x * 256 + threadIdx.x;
  if (o < O) {
    double mean = S1[o] * invM;
    double var = S2[o] * invM - mean * mean;
    double sc = (double)g[o] / sqrt(var + 1e-5);
    scale[o] = (float)sc;
    shift[o] = (float)((double)beta[o] - mean * sc);
  }
}

// ------------------- elementwise finalize + transpose to (B,O,N) ------------
__global__ __launch_bounds__(256) void edge_out(const float* __restrict__ hmax,
                                                const float* __restrict__ hmin,
                                                const float* __restrict__ scale,
                                                const float* __restrict__ shift,
                                                int O, int N,
                                                float* __restrict__ outp, long out_bstride) {
  const int tid = threadIdx.x;
  const int b = blockIdx.y, n0 = blockIdx.x * 64;
  __shared__ float yt[64][65];
  const int ol = tid & 63, nl = tid >> 6;
  const long base = (long)b * N;
  for (int oc = 0; oc < O; oc += 64) {
    float sc = scale[oc + ol], sh = shift[oc + ol];
    __syncthreads();
    for (int ng = 0; ng < 16; ++ng) {
      int n = ng * 4 + nl;
      long off = (base + n0 + n) * O + oc + ol;
      float hv = (sc >= 0.f) ? hmax[off] : hmin[off];
      float y = sc * hv + sh;
      yt[ol][n] = LEAKY(y);
    }
    __syncthreads();
    for (int rr = 0; rr < 16; ++rr) {
      int r = rr * 4 + nl;
      outp[(long)b * out_bstride + (long)(oc + r) * N + n0 + ol] = yt[r][ol];
    }
  }
}

// -------------------- fusion 512->1024: GEMM once, store h + stats ----------
__global__ __launch_bounds__(256) void fusion_gemm(const float* __restrict__ wfT,
                                                   const float* __restrict__ bfb,
                                                   const float* __restrict__ feat, int N,
                                                   float* __restrict__ h,
                                                   double* __restrict__ S1,
                                                   double* __restrict__ S2) {
  const int tid = threadIdx.x;
  const int n0 = blockIdx.x * 64, o0 = blockIdx.y * 64, b = blockIdx.z;
  __shared__ float wT[64][64];
  __shared__ float fT[64][64];
  const int tr = tid >> 4, tc = tid & 15;
  float acc[4][4];
  #pragma unroll
  for (int i = 0; i < 4; ++i)
    #pragma unroll
    for (int j = 0; j < 4; ++j) acc[i][j] = 0.f;
  for (int cc = 0; cc < 8; ++cc) {
    __syncthreads();
    for (int i = tid; i < 4096; i += 256) {
      int ci = i >> 6, j = i & 63;
      wT[ci][j] = wfT[(long)(cc * 64 + ci) * 1024 + o0 + j];
      fT[ci][j] = feat[((long)b * 512 + cc * 64 + ci) * N + n0 + j];
    }
    __syncthreads();
    #pragma unroll
    for (int ci = 0; ci < 64; ++ci) {
      float4 a4 = *reinterpret_cast<const float4*>(&wT[ci][4 * tr]);
      float4 b4 = *reinterpret_cast<const float4*>(&fT[ci][4 * tc]);
      float av[4] = {a4.x, a4.y, a4.z, a4.w};
      float bv[4] = {b4.x, b4.y, b4.z, b4.w};
      #pragma unroll
      for (int i = 0; i < 4; ++i)
        #pragma unroll
        for (int j = 0; j < 4; ++j) acc[i][j] = fmaf(av[i], bv[j], acc[i][j]);
    }
  }
  #pragma unroll
  for (int i = 0; i < 4; ++i) {
    int o = o0 + 4 * tr + i;
    float bias = bfb[o];
    float4 hv = make_float4(acc[i][0] + bias, acc[i][1] + bias,
                            acc[i][2] + bias, acc[i][3] + bias);
    *reinterpret_cast<float4*>(&h[((long)b * 1024 + o) * N + n0 + 4 * tc]) = hv;
    float s1 = hv.x + hv.y + hv.z + hv.w;
    float s2 = hv.x * hv.x + hv.y * hv.y + hv.z * hv.z + hv.w * hv.w;
    for (int off = 1; off < 16; off <<= 1) {
      s1 += __shfl_xor(s1, off, 16);
      s2 += __shfl_xor(s2, off, 16);
    }
    if (tc == 0) { atomicAdd(&S1[o], (double)s1); atomicAdd(&S2[o], (double)s2); }
  }
}

// --------------- BN+leaky+max/mean pool over N, one wave per (b,o) row ------
__global__ __launch_bounds__(256) void pool_kernel(const float* __restrict__ h,
                                                   const float* __restrict__ scale,
                                                   const float* __restrict__ shift,
                                                   float* __restrict__ x1x2) {
  int gw = (blockIdx.x * 256 + threadIdx.x) >> 6;
  int lane = threadIdx.x & 63;
  int b = gw >> 10, o = gw & 1023;
  const float4* row = reinterpret_cast<const float4*>(h + ((long)b * 1024 + o) * 4096);
  float sc = scale[o], sh = shift[o];
  float mx = -3.0e38f, sm = 0.f;
  for (int j = 0; j < 16; ++j) {
    float4 hv = row[j * 64 + lane];
    float y0 = LEAKY(sc * hv.x + sh), y1 = LEAKY(sc * hv.y + sh);
    float y2 = LEAKY(sc * hv.z + sh), y3 = LEAKY(sc * hv.w + sh);
    mx = fmaxf(mx, fmaxf(fmaxf(y0, y1), fmaxf(y2, y3)));
    sm += (y0 + y1) + (y2 + y3);
  }
  #pragma unroll
  for (int off = 1; off < 64; off <<= 1) {
    mx = fmaxf(mx, __shfl_xor(mx, off));
    sm += __shfl_xor(sm, off);
  }
  if (lane == 0) {
    x1x2[(long)b * 2048 + o] = mx;
    x1x2[(long)b * 2048 + 1024 + o] = sm * (1.f / 4096.f);
  }
}

// ----------------------------------------------------------- classifier -----
__global__ __launch_bounds__(256) void fc_kernel(const float* __restrict__ in, int Cin, int O,
                                                 const float* __restrict__ W,
                                                 const float* __restrict__ bias,
                                                 const float* __restrict__ g,
                                                 const float* __restrict__ beta,
                                                 float* __restrict__ outp, int do_bn) {
  const int tid = threadIdx.x;
  const int o = blockIdx.x * 32 + (tid >> 3);
  const int bb = tid & 7;
  const int oc = (o < O) ? o : (O - 1);
  const float* ir = in + (long)bb * Cin;
  const float* wr = W + (long)oc * Cin;
  float dot = 0.f;
  for (int c = 0; c < Cin; c += 4) {
    float4 a = *reinterpret_cast<const float4*>(&ir[c]);
    float4 w = *reinterpret_cast<const float4*>(&wr[c]);
    dot += a.x * w.x + a.y * w.y + a.z * w.z + a.w * w.w;
  }
  float h = dot + bias[oc];
  if (do_bn) {
    float s = h;
    s += __shfl_xor(s, 1, 8); s += __shfl_xor(s, 2, 8); s += __shfl_xor(s, 4, 8);
    float mean = s * 0.125f;
    float dv = (h - mean) * (h - mean);
    dv += __shfl_xor(dv, 1, 8); dv += __shfl_xor(dv, 2, 8); dv += __shfl_xor(dv, 4, 8);
    float var = dv * 0.125f;
    float y = (h - mean) * (float)(1.0 / sqrt((double)var + 1e-5)) * g[oc] + beta[oc];
    h = LEAKY(y);
  }
  if (o < O) outp[(long)bb * O + o] = h;
}

// ---------------------------------------------------------------- driver ----
extern "C" void kernel_launch(void* const* d_in, const int* in_sizes, int n_in,
                              void* d_out, int out_size, void* d_ws, size_t ws_size,
                              hipStream_t stream) {
  const int B = 8, N = 4096;
  const float* x   = (const float*)d_in[0];
  const float* w1 = (const float*)d_in[2];  const float* g1 = (const float*)d_in[3];  const float* b1 = (const float*)d_in[4];
  const float* w2 = (const float*)d_in[5];  const float* g2 = (const float*)d_in[6];  const float* b2 = (const float*)d_in[7];
  const float* w3 = (const float*)d_in[8];  const float* g3 = (const float*)d_in[9];  const float* b3 = (const float*)d_in[10];
  const float* w4 = (const float*)d_in[11]; const float* g4 = (const float*)d_in[12]; const float* b4 = (const float*)d_in[13];
  const float* wf = (const float*)d_in[14]; const float* bfv = (const float*)d_in[15];
  const float* gf = (const float*)d_in[16]; const float* betaf = (const float*)d_in[17];
  const float* wc1 = (const float*)d_in[18]; const float* bc1 = (const float*)d_in[19];
  const float* gc1 = (const float*)d_in[20]; const float* betac1 = (const float*)d_in[21];
  const float* wc2 = (const float*)d_in[22]; const float* bc2 = (const float*)d_in[23];
  const float* gc2 = (const float*)d_in[24]; const float* betac2 = (const float*)d_in[25];
  const float* wc3 = (const float*)d_in[26]; const float* bc3 = (const float*)d_in[27];

  char* p = (char*)d_ws;
  auto alloc = [&](size_t bytes) -> char* {
    char* r = p;
    p += (bytes + 255) & ~(size_t)255;
    return r;
  };
  float* feat  = (float*)alloc((size_t)B * 512 * N * 4);   // 67.1MB
  int*   idx   = (int*)  alloc((size_t)B * N * 9 * 4);
  int*   cand  = (int*)  alloc((size_t)B * N * 32 * 4);    // 4.2MB
  float* xxg   = (float*)alloc((size_t)B * N * 4);
  // R region (4 x 33.5MB): u|v|hmax|hmin during edge phase; overlays:
  //   kNN: packR in u region, packC in hmax region ; fusion: h spans all four
  float* u     = (float*)alloc((size_t)B * N * 256 * 4);
  float* v     = (float*)alloc((size_t)B * N * 256 * 4);
  float* hmax  = (float*)alloc((size_t)B * N * 256 * 4);
  float* hmin  = (float*)alloc((size_t)B * N * 256 * 4);
  float* hbuf  = u;
  ushort* packR = (ushort*)u;
  ushort* packC = (ushort*)hmax;
  float* At    = (float*)alloc(128 * 256 * 4);
  float* W2t   = (float*)alloc(128 * 256 * 4);
  float* wfT   = (float*)alloc((size_t)512 * 1024 * 4);
  double* S1   = (double*)alloc(1024 * 8);
  double* S2   = (double*)alloc(1024 * 8);
  float* scale = (float*)alloc(1024 * 4);
  float* shift = (float*)alloc(1024 * 4);
  float* x1x2  = (float*)alloc((size_t)B * 2048 * 4);
  float* h1    = (float*)alloc((size_t)B * 512 * 4);
  float* h2    = (float*)alloc((size_t)B * 256 * 4);

  dim3 gpack(N / 32, B);
  dim3 gknn(N / 128, B, 2);
  dim3 grr(N / 8, B);
  dim3 gxx(N / 256, B);

  transpose_wf<<<2048, 256, 0, stream>>>(wf, wfT);

  auto edge = [&](const float* inp, long in_bstride, int Cin, int O, const float* W,
                  const float* g, const float* beta, int c0) {
    prep_wt<<<(O * Cin + 255) / 256, 256, 0, stream>>>(W, Cin, O, At, W2t);
    dim3 gg(N / 64, O / 64, B);
    gemm_cn_no<<<gg, 256, 0, stream>>>(At, Cin, O, inp, in_bstride, N, u);
    gemm_cn_no<<<gg, 256, 0, stream>>>(W2t, Cin, O, inp, in_bstride, N, v);
    hipMemsetAsync(S1, 0, O * 8, stream);
    hipMemsetAsync(S2, 0, O * 8, stream);
    edge_pass<<<gg, 256, 0, stream>>>(u, v, idx, O, N, hmax, hmin, S1, S2);
    finalize_scale<<<(O + 255) / 256, 256, 0, stream>>>(S1, S2, g, beta,
                                                        1.0 / ((double)B * N * 9), O, scale, shift);
    edge_out<<<dim3(N / 64, B), 256, 0, stream>>>(hmax, hmin, scale, shift, O, N,
                                                  feat + (long)c0 * N, (long)512 * N);
  };

  // layer 1: C=3, K'=9 -> KC=1
  xx_kernel<3><<<gxx, 256, 0, stream>>>(x, (long)3 * N, N, xxg);
  pack3_kernel<3, 1><<<gpack, 256, 0, stream>>>(x, (long)3 * N, N, packR, packC);
  knn_v2<1><<<gknn, 256, 0, stream>>>(packR, packC, xxg, N, cand);
  rerank_kernel<3><<<grr, 256, 0, stream>>>(x, (long)3 * N, N, xxg, cand, idx);
  edge(x, (long)3 * N, 3, 64, w1, g1, b1, 0);

  // layer 2: C=64, K'=192 -> KC=12
  xx_kernel<64><<<gxx, 256, 0, stream>>>(feat, (long)512 * N, N, xxg);
  pack3_kernel<64, 12><<<gpack, 256, 0, stream>>>(feat, (long)512 * N, N, packR, packC);
  knn_v2<12><<<gknn, 256, 0, stream>>>(packR, packC, xxg, N, cand);
  rerank_kernel<64><<<grr, 256, 0, stream>>>(feat, (long)512 * N, N, xxg, cand, idx);
  edge(feat, (long)512 * N, 64, 64, w2, g2, b2, 64);

  // layer 3: C=64
  xx_kernel<64><<<gxx, 256, 0, stream>>>(feat + (long)64 * N, (long)512 * N, N, xxg);
  pack3_kernel<64, 12><<<gpack, 256, 0, stream>>>(feat + (long)64 * N, (long)512 * N, N, packR, packC);
  knn_v2<12><<<gknn, 256, 0, stream>>>(packR, packC, xxg, N, cand);
  rerank_kernel<64><<<grr, 256, 0, stream>>>(feat + (long)64 * N, (long)512 * N, N, xxg, cand, idx);
  edge(feat + (long)64 * N, (long)512 * N, 64, 128, w3, g3, b3, 128);

  // layer 4: C=128, K'=384 -> KC=24
  xx_kernel<128><<<gxx, 256, 0, stream>>>(feat + (long)128 * N, (long)512 * N, N, xxg);
  pack3_kernel<128, 24><<<gpack, 256, 0, stream>>>(feat + (long)128 * N, (long)512 * N, N, packR, packC);
  knn_v2<24><<<gknn, 256, 0, stream>>>(packR, packC, xxg, N, cand);
  rerank_kernel<128><<<grr, 256, 0, stream>>>(feat + (long)128 * N, (long)512 * N, N, xxg, cand, idx);
  edge(feat + (long)128 * N, (long)512 * N, 128, 256, w4, g4, b4, 256);

  // fusion conv 512->1024 (single GEMM, h stored over dead edge buffers)
  hipMemsetAsync(S1, 0, 1024 * 8, stream);
  hipMemsetAsync(S2, 0, 1024 * 8, stream);
  dim3 gfu(N / 64, 16, B);
  fusion_gemm<<<gfu, 256, 0, stream>>>(wfT, bfv, feat, N, hbuf, S1, S2);
  finalize_scale<<<4, 256, 0, stream>>>(S1, S2, gf, betaf, 1.0 / ((double)B * N), 1024, scale, shift);
  pool_kernel<<<2048, 256, 0, stream>>>(hbuf, scale, shift, x1x2);

  fc_kernel<<<16, 256, 0, stream>>>(x1x2, 2048, 512, wc1, bc1, gc1, betac1, h1, 1);
  fc_kernel<<<8, 256, 0, stream>>>(h1, 512, 256, wc2, bc2, gc2, betac2, h2, 1);
  fc_kernel<<<2, 256, 0, stream>>>(h2, 256, 40, wc3, bc3, nullptr, nullptr, (float*)d_out, 0);
}

// Round 7
// 3799.010 us; speedup vs baseline: 1.6732x; 1.1313x over previous
//
#include <hip/hip_runtime.h>
#include <math.h>
#include <float.h>

// DGCNN forward, MI355X. f32 except: kNN distance GEMM + fusion conv (3-term
// split-bf16 MFMA; x = hi + mid, products hi.hi + mid.hi + hi.mid).
// kNN two-phase: MFMA approx -> 32-cand pool -> exact f32 re-rank (r2 rounding).
// Fusion: two MFMA passes (stats, then BN+leaky+pool in-register) - h never stored.

#define LEAKY(y) ((y) >= 0.f ? (y) : 0.2f * (y))

using f32x16 = __attribute__((ext_vector_type(16))) float;
using bf16x8 = __attribute__((ext_vector_type(8))) __bf16;
using short8v = __attribute__((ext_vector_type(8))) short;

__device__ inline ushort f2bf(float x) {
  unsigned u = __float_as_uint(x);
  unsigned r = (u + 0x7fff + ((u >> 16) & 1)) >> 16;
  return (ushort)r;
}

// ------------------------------------------------------------- xx = sum x^2 --
template<int C>
__global__ void xx_kernel(const float* __restrict__ xin, long bstride, int N,
                          float* __restrict__ xxg) {
  int n = blockIdx.x * 256 + threadIdx.x;
  int b = blockIdx.y;
  if (n < N) {
    const float* xb = xin + (long)b * bstride;
    float s = 0.f;
    #pragma unroll
    for (int c = 0; c < C; ++c) { float t = xb[(long)c * N + n]; s += t * t; }
    xxg[(long)b * N + n] = s;
  }
}

// ---------------------------------------- pack points into MFMA frag order ---
// R slices (query/B-op): [hi, hi, mid]; C slices (cand/A-op): [hi, mid, hi].
// Also emits point-major f32 copy xpm[(b*N+n)*C + c] for the exact rerank.
template<int C, int KC>
__global__ __launch_bounds__(256) void pack3_kernel(const float* __restrict__ xin, long bstride,
                                                    int N, ushort* __restrict__ packR,
                                                    ushort* __restrict__ packC,
                                                    float* __restrict__ xpm) {
  __shared__ float xt[C][32];
  const int tid = threadIdx.x;
  const int pb = blockIdx.x, b = blockIdx.y;
  for (int i = tid; i < C * 32; i += 256) {
    int c = i >> 5, j = i & 31;
    xt[c][j] = xin[(long)b * bstride + (long)c * N + pb * 32 + j];
  }
  __syncthreads();
  for (int i = tid; i < 32 * C; i += 256) {
    int pt = i / C, c = i % C;
    xpm[((long)b * N + pb * 32 + pt) * C + c] = xt[c][pt];
  }
  const int PB = N >> 5;
  for (int it = tid; it < KC * 64; it += 256) {
    int kc = it >> 6, l = it & 63;
    int pt = l & 31;
    union { ushort u[8]; short8v v; } R, Cc;
    #pragma unroll
    for (int e = 0; e < 8; ++e) {
      int kp = kc * 16 + ((l >> 5) << 3) + e;
      ushort rv = 0, cv = 0;
      if (kp < 3 * C) {
        int s = kp / C, c = kp % C;
        float xv = xt[c][pt];
        ushort hi = f2bf(xv);
        float hif = __uint_as_float((unsigned)hi << 16);
        ushort mid = f2bf(xv - hif);
        rv = (s == 2) ? mid : hi;
        cv = (s == 1) ? mid : hi;
      }
      R.u[e] = rv; Cc.u[e] = cv;
    }
    long off = (((long)b * PB + pb) * KC + kc) * 512 + l * 8;
    *reinterpret_cast<short8v*>(&packR[off]) = R.v;
    *reinterpret_cast<short8v*>(&packC[off]) = Cc.v;
  }
}

// ----------------------------------------------------- kNN phase 1 (MFMA) ---
#define KNN_TOP9_UPDATE(d_, gi_)                                                 \
  if (d_ < td[8] || (d_ == td[8] && gi_ < ti[8])) {                              \
    td[8] = d_; ti[8] = gi_;                                                     \
    _Pragma("unroll")                                                            \
    for (int s_ = 8; s_ > 0; --s_) {                                             \
      bool sw_ = (td[s_] < td[s_ - 1]) || (td[s_] == td[s_ - 1] && ti[s_] < ti[s_ - 1]); \
      if (sw_) {                                                                 \
        float tf_ = td[s_]; td[s_] = td[s_ - 1]; td[s_ - 1] = tf_;               \
        int tn_ = ti[s_]; ti[s_] = ti[s_ - 1]; ti[s_ - 1] = tn_;                 \
      }                                                                          \
    }                                                                            \
  }

template<int KC>
__global__ __launch_bounds__(256, 2) void knn_v2(const ushort* __restrict__ packR,
                                                 const ushort* __restrict__ packC,
                                                 const float* __restrict__ xxg,
                                                 int N, int* __restrict__ cand) {
  constexpr int SA_ELEMS = KC * 512;
  __shared__ float sxx[4608];
  __shared__ ushort sA[2][SA_ELEMS];
  const int tid = threadIdx.x;
  const int b = blockIdx.y, rowblk = blockIdx.x, z = blockIdx.z;
  const int w = tid >> 6, l = tid & 63;
  const int lane31 = l & 31, hf = l >> 5;
  const int PB = N >> 5;
  const int HALF = PB >> 1;

  for (int i = tid; i < N; i += 256) sxx[i] = xxg[(long)b * N + i];

  const ushort* rp = packR + (((long)b * PB + rowblk * 4 + w) * (long)KC) * 512 + l * 8;
  bf16x8 bfr[KC];
  #pragma unroll
  for (int kc = 0; kc < KC; ++kc)
    bfr[kc] = *reinterpret_cast<const bf16x8*>(rp + kc * 512);

  const ushort* srcb = packC + ((long)b * PB) * (long)SA_ELEMS;
  const int mb0 = z * HALF;

  {
    const ushort* src = srcb + (long)mb0 * SA_ELEMS;
    for (int i = tid * 8; i < SA_ELEMS; i += 2048)
      __builtin_amdgcn_global_load_lds(
          (const __attribute__((address_space(1))) void*)(src + i),
          (__attribute__((address_space(3))) void*)(&sA[0][i]), 16, 0, 0);
  }
  __syncthreads();

  const int n_glob = rowblk * 128 + w * 32 + lane31;
  const float xr = sxx[n_glob];

  float td[9]; int ti[9];
  #pragma unroll
  for (int s = 0; s < 9; ++s) { td[s] = 3.0e38f; ti[s] = 0x7fffffff; }

  int cur = 0;
  for (int t = 0; t < HALF; ++t) {
    const int mb = mb0 + t;
    if (t + 1 < HALF) {
      const ushort* src = srcb + (long)(mb + 1) * SA_ELEMS;
      for (int i = tid * 8; i < SA_ELEMS; i += 2048)
        __builtin_amdgcn_global_load_lds(
            (const __attribute__((address_space(1))) void*)(src + i),
            (__attribute__((address_space(3))) void*)(&sA[cur ^ 1][i]), 16, 0, 0);
    }
    f32x16 acc = {};
    #pragma unroll
    for (int kc = 0; kc < KC; ++kc) {
      bf16x8 af = *reinterpret_cast<const bf16x8*>(&sA[cur][kc * 512 + l * 8]);
      acc = __builtin_amdgcn_mfma_f32_32x32x16_bf16(af, bfr[kc], acc, 0, 0, 0);
    }
    #pragma unroll
    for (int reg = 0; reg < 16; ++reg) {
      int m_loc = (reg & 3) + 8 * (reg >> 2) + 4 * hf;
      int m_glob = (mb << 5) + m_loc;
      float d = (xr - 2.0f * acc[reg]) + sxx[m_glob];
      if (m_glob == n_glob) d = 3.0e38f;
      KNN_TOP9_UPDATE(d, m_glob)
    }
    __syncthreads();
    cur ^= 1;
  }

  float (*mD)[18] = (float(*)[18])sxx;
  int   (*mI)[18] = (int(*)[18])(sxx + 2304);
  __syncthreads();
  const int row = w * 32 + lane31;
  #pragma unroll
  for (int s = 0; s < 9; ++s) {
    mD[row][hf * 9 + s] = td[s];
    mI[row][hf * 9 + s] = ti[s];
  }
  __syncthreads();
  if (tid < 128) {
    int p0 = 0, p1 = 0;
    const long ob = ((long)b * N + rowblk * 128 + tid) * 32 + z * 16;
    for (int s = 0; s < 16; ++s) {
      float d0 = (p0 < 9) ? mD[tid][p0] : 3.3e38f;
      int   i0 = (p0 < 9) ? mI[tid][p0] : 0x7fffffff;
      float d1 = (p1 < 9) ? mD[tid][9 + p1] : 3.3e38f;
      int   i1 = (p1 < 9) ? mI[tid][9 + p1] : 0x7fffffff;
      bool t0 = (d0 < d1) || (d0 == d1 && i0 < i1);
      cand[ob + s] = t0 ? i0 : i1;
      if (t0) ++p0; else ++p1;
    }
  }
}

// ---------------- exact f32 re-rank of 32 candidates (point-major input) ----
template<int C>
__global__ __launch_bounds__(256) void rerank_kernel(const float* __restrict__ xpm,
                                                     int N, const float* __restrict__ xxg,
                                                     const int* __restrict__ cand,
                                                     int* __restrict__ idx_out) {
  __shared__ float sq[8][C];
  __shared__ float sd[8][33];
  __shared__ int   si[8][33];
  const int tid = threadIdx.x;
  const int b = blockIdx.y, n0 = blockIdx.x * 8;
  const float* xb = xpm + (long)b * N * C;
  for (int i = tid; i < 8 * C; i += 256) {
    int r = i / C, c = i % C;
    sq[r][c] = xb[(long)(n0 + r) * C + c];
  }
  __syncthreads();
  const int r = tid >> 5, j = tid & 31;
  const int n = n0 + r;
  const int m = cand[(((long)b * N + n) << 5) + j];
  const float* cv = xb + (long)m * C;
  float dot = 0.f;
  if constexpr ((C & 3) == 0) {
    for (int c = 0; c < C; c += 4) {
      float4 v4 = *reinterpret_cast<const float4*>(cv + c);
      dot = fmaf(sq[r][c + 0], v4.x, dot);
      dot = fmaf(sq[r][c + 1], v4.y, dot);
      dot = fmaf(sq[r][c + 2], v4.z, dot);
      dot = fmaf(sq[r][c + 3], v4.w, dot);
    }
  } else {
    for (int c = 0; c < C; ++c) dot = fmaf(sq[r][c], cv[c], dot);
  }
  float d = (xxg[(long)b * N + n] - 2.0f * dot) + xxg[(long)b * N + m];
  if (m == n) d = 3.0e38f;
  sd[r][j] = d; si[r][j] = m;
  __syncthreads();
  int rank = 0;
  #pragma unroll
  for (int t = 0; t < 32; ++t) {
    float dd = sd[r][t]; int ii = si[r][t];
    if (dd < d || (dd == d && ii < m)) rank++;
  }
  if (rank < 9) idx_out[((long)b * N + n) * 9 + rank] = m;
}

// ------------------------------------------- W transposes (coalesced GEMMs) --
__global__ void prep_wt(const float* __restrict__ W, int Cin, int O,
                        float* __restrict__ At, float* __restrict__ W2t) {
  int i = blockIdx.x * 256 + threadIdx.x;
  if (i < O * Cin) {
    int o = i % O, c = i / O;
    float w1v = W[(long)o * 2 * Cin + c];
    float w2v = W[(long)o * 2 * Cin + Cin + c];
    At[(long)c * O + o]  = w1v - w2v;
    W2t[(long)c * O + o] = w2v;
  }
}

// ------------------------------ GEMM: out[b][n][o] = sum_c Wt[c][o] in[b][c][n]
__global__ __launch_bounds__(256) void gemm_cn_no(const float* __restrict__ Wt,
                                                  int C, int O,
                                                  const float* __restrict__ in,
                                                  long in_bstride, int N,
                                                  float* __restrict__ out) {
  const int tid = threadIdx.x;
  const int n0 = blockIdx.x * 64, o0 = blockIdx.y * 64, b = blockIdx.z;
  __shared__ float wT[128][64];
  __shared__ float inT[128][64];
  for (int i = tid; i < C * 64; i += 256) {
    int c = i >> 6, j = i & 63;
    wT[c][j]  = Wt[(long)c * O + o0 + j];
    inT[c][j] = in[(long)b * in_bstride + (long)c * N + n0 + j];
  }
  __syncthreads();
  const int tr = tid >> 4, tc = tid & 15;
  float acc[4][4];
  #pragma unroll
  for (int i = 0; i < 4; ++i)
    #pragma unroll
    for (int j = 0; j < 4; ++j) acc[i][j] = 0.f;
  for (int c = 0; c < C; ++c) {
    float4 a4 = *reinterpret_cast<const float4*>(&wT[c][4 * tr]);
    float4 b4 = *reinterpret_cast<const float4*>(&inT[c][4 * tc]);
    float av[4] = {a4.x, a4.y, a4.z, a4.w};
    float bv[4] = {b4.x, b4.y, b4.z, b4.w};
    #pragma unroll
    for (int i = 0; i < 4; ++i)
      #pragma unroll
      for (int j = 0; j < 4; ++j) acc[i][j] = fmaf(av[i], bv[j], acc[i][j]);
  }
  #pragma unroll
  for (int j = 0; j < 4; ++j) {
    float4 st = make_float4(acc[0][j], acc[1][j], acc[2][j], acc[3][j]);
    *reinterpret_cast<float4*>(&out[((long)b * N + n0 + 4 * tc + j) * O + o0 + 4 * tr]) = st;
  }
}

// ------------------- single gather pass: stats + hmax + hmin per (n,o) ------
__global__ __launch_bounds__(256) void edge_pass(const float* __restrict__ u,
                                                 const float* __restrict__ v,
                                                 const int* __restrict__ idx,
                                                 int O, int N,
                                                 float* __restrict__ hmax,
                                                 float* __restrict__ hmin,
                                                 double* __restrict__ S1,
                                                 double* __restrict__ S2) {
  const int tid = threadIdx.x;
  const int n0 = blockIdx.x * 64, o0 = blockIdx.y * 64, b = blockIdx.z;
  __shared__ int sidx[64][9];
  __shared__ float4 redA[4][16];
  __shared__ float4 redB[4][16];
  for (int i = tid; i < 576; i += 256)
    ((int*)sidx)[i] = idx[((long)b * N + n0) * 9 + i];
  __syncthreads();
  const int nl = tid >> 4, oq = tid & 15;
  const long base = (long)b * N;
  const int ocol = o0 + 4 * oq;
  float4 s1 = make_float4(0.f, 0.f, 0.f, 0.f);
  float4 s2 = make_float4(0.f, 0.f, 0.f, 0.f);
  for (int g = 0; g < 4; ++g) {
    const int n = g * 16 + nl;
    const float4 u4 = *reinterpret_cast<const float4*>(&u[(base + n0 + n) * O + ocol]);
    float4 mx = make_float4(-3.0e38f, -3.0e38f, -3.0e38f, -3.0e38f);
    float4 mn = make_float4(3.0e38f, 3.0e38f, 3.0e38f, 3.0e38f);
    #pragma unroll
    for (int k = 0; k < 9; ++k) {
      int m = sidx[n][k];
      const float4 v4 = *reinterpret_cast<const float4*>(&v[(base + m) * O + ocol]);
      float hx = u4.x + v4.x, hy = u4.y + v4.y, hz = u4.z + v4.z, hw = u4.w + v4.w;
      s1.x += hx; s1.y += hy; s1.z += hz; s1.w += hw;
      s2.x = fmaf(hx, hx, s2.x); s2.y = fmaf(hy, hy, s2.y);
      s2.z = fmaf(hz, hz, s2.z); s2.w = fmaf(hw, hw, s2.w);
      mx.x = fmaxf(mx.x, hx); mx.y = fmaxf(mx.y, hy); mx.z = fmaxf(mx.z, hz); mx.w = fmaxf(mx.w, hw);
      mn.x = fminf(mn.x, hx); mn.y = fminf(mn.y, hy); mn.z = fminf(mn.z, hz); mn.w = fminf(mn.w, hw);
    }
    *reinterpret_cast<float4*>(&hmax[(base + n0 + n) * O + ocol]) = mx;
    *reinterpret_cast<float4*>(&hmin[(base + n0 + n) * O + ocol]) = mn;
  }
  s1.x += __shfl_xor(s1.x, 16); s1.y += __shfl_xor(s1.y, 16);
  s1.z += __shfl_xor(s1.z, 16); s1.w += __shfl_xor(s1.w, 16);
  s2.x += __shfl_xor(s2.x, 16); s2.y += __shfl_xor(s2.y, 16);
  s2.z += __shfl_xor(s2.z, 16); s2.w += __shfl_xor(s2.w, 16);
  s1.x += __shfl_xor(s1.x, 32); s1.y += __shfl_xor(s1.y, 32);
  s1.z += __shfl_xor(s1.z, 32); s1.w += __shfl_xor(s1.w, 32);
  s2.x += __shfl_xor(s2.x, 32); s2.y += __shfl_xor(s2.y, 32);
  s2.z += __shfl_xor(s2.z, 32); s2.w += __shfl_xor(s2.w, 32);
  if ((tid & 48) == 0) { redA[tid >> 6][oq] = s1; redB[tid >> 6][oq] = s2; }
  __syncthreads();
  if (tid < 16) {
    float4 a = redA[0][tid], bb = redB[0][tid];
    #pragma unroll
    for (int ww = 1; ww < 4; ++ww) {
      float4 t1 = redA[ww][tid], t2 = redB[ww][tid];
      a.x += t1.x; a.y += t1.y; a.z += t1.z; a.w += t1.w;
      bb.x += t2.x; bb.y += t2.y; bb.z += t2.z; bb.w += t2.w;
    }
    int o = o0 + 4 * tid;
    atomicAdd(&S1[o + 0], (double)a.x);  atomicAdd(&S1[o + 1], (double)a.y);
    atomicAdd(&S1[o + 2], (double)a.z);  atomicAdd(&S1[o + 3], (double)a.w);
    atomicAdd(&S2[o + 0], (double)bb.x); atomicAdd(&S2[o + 1], (double)bb.y);
    atomicAdd(&S2[o + 2], (double)bb.z); atomicAdd(&S2[o + 3], (double)bb.w);
  }
}

__global__ void finalize_scale(const double* __restrict__ S1, const double* __restrict__ S2,
                               const float* __restrict__ g, const float* __restrict__ beta,
                               double invM, int O, float* __restrict__ scale,
                               float* __restrict__ shift) {
  int o = blockIdx.x * 256 + threadIdx.x;
  if (o < O) {
    double mean = S1[o] * invM;
    double var = S2[o] * invM - mean * mean;
    double sc = (double)g[o] / sqrt(var + 1e-5);
    scale[o] = (float)sc;
    shift[o] = (float)((double)beta[o] - mean * sc);
  }
}

// ------------------- elementwise finalize + transpose to (B,O,N) ------------
__global__ __launch_bounds__(256) void edge_out(const float* __restrict__ hmax,
                                                const float* __restrict__ hmin,
                                                const float* __restrict__ scale,
                                                const float* __restrict__ shift,
                                                int O, int N,
                                                float* __restrict__ outp, long out_bstride) {
  const int tid = threadIdx.x;
  const int b = blockIdx.y, n0 = blockIdx.x * 64;
  __shared__ float yt[64][65];
  const int ol = tid & 63, nl = tid >> 6;
  const long base = (long)b * N;
  for (int oc = 0; oc < O; oc += 64) {
    float sc = scale[oc + ol], sh = shift[oc + ol];
    __syncthreads();
    for (int ng = 0; ng < 16; ++ng) {
      int n = ng * 4 + nl;
      long off = (base + n0 + n) * O + oc + ol;
      float hv = (sc >= 0.f) ? hmax[off] : hmin[off];
      float y = sc * hv + sh;
      yt[ol][n] = LEAKY(y);
    }
    __syncthreads();
    for (int rr = 0; rr < 16; ++rr) {
      int r = rr * 4 + nl;
      outp[(long)b * out_bstride + (long)(oc + r) * N + n0 + ol] = yt[r][ol];
    }
  }
}

// ----------------- fusion packs: weights (A-pattern), feat (B-pattern) ------
__global__ __launch_bounds__(256) void pack3_wf(const float* __restrict__ wf,
                                                ushort* __restrict__ packW) {
  __shared__ float wt[32][129];
  const int po = blockIdx.x;
  const int tid = threadIdx.x;
  for (int c0 = 0; c0 < 512; c0 += 128) {
    __syncthreads();
    for (int i = tid; i < 32 * 128; i += 256) {
      int o = i >> 7, c = i & 127;
      wt[o][c] = wf[(long)(po * 32 + o) * 512 + c0 + c];
    }
    __syncthreads();
    #pragma unroll
    for (int s = 0; s < 3; ++s) {
      int kc0 = (s * 512 + c0) >> 4;
      for (int it = tid; it < 8 * 64; it += 256) {
        int kcl = it >> 6, l = it & 63;
        union { ushort u[8]; short8v v; } P;
        #pragma unroll
        for (int e = 0; e < 8; ++e) {
          int kp = (kc0 + kcl) * 16 + ((l >> 5) << 3) + e;
          int c = kp - s * 512 - c0;
          float xv = wt[l & 31][c];
          ushort hi = f2bf(xv);
          if (s == 1) {
            float hif = __uint_as_float((unsigned)hi << 16);
            P.u[e] = f2bf(xv - hif);
          } else P.u[e] = hi;
        }
        *reinterpret_cast<short8v*>(&packW[((long)po * 96 + kc0 + kcl) * 512 + l * 8]) = P.v;
      }
    }
  }
}

__global__ __launch_bounds__(256) void pack3_feat(const float* __restrict__ feat, int N,
                                                  ushort* __restrict__ packB) {
  __shared__ float xt[64][33];
  const int pb = blockIdx.x, b = blockIdx.y;
  const int tid = threadIdx.x;
  const int PB = N >> 5;
  for (int c0 = 0; c0 < 512; c0 += 64) {
    __syncthreads();
    for (int i = tid; i < 64 * 32; i += 256) {
      int c = i >> 5, j = i & 31;
      xt[c][j] = feat[((long)b * 512 + c0 + c) * N + pb * 32 + j];
    }
    __syncthreads();
    #pragma unroll
    for (int s = 0; s < 3; ++s) {
      int kc0 = (s * 512 + c0) >> 4;
      for (int it = tid; it < 4 * 64; it += 256) {
        int kcl = it >> 6, l = it & 63;
        union { ushort u[8]; short8v v; } P;
        #pragma unroll
        for (int e = 0; e < 8; ++e) {
          int kp = (kc0 + kcl) * 16 + ((l >> 5) << 3) + e;
          int c = kp - s * 512 - c0;
          float xv = xt[c][l & 31];
          ushort hi = f2bf(xv);
          if (s == 2) {
            float hif = __uint_as_float((unsigned)hi << 16);
            P.u[e] = f2bf(xv - hif);
          } else P.u[e] = hi;
        }
        *reinterpret_cast<short8v*>(
            &packB[(((long)b * PB + pb) * 96 + kc0 + kcl) * 512 + l * 8]) = P.v;
      }
    }
  }
}

// ---------------- fusion MFMA: PHASE 0 = stats partials, 1 = pool partials --
#define FUS_EPI(ACC, Q)                                                          \
  _Pragma("unroll")                                                              \
  for (int reg = 0; reg < 16; ++reg) {                                           \
    int o = ((z * 16 + (Q) * 4 + w) << 5) + (reg & 3) + 8 * (reg >> 2) + 4 * hf; \
    float h = ACC[reg] + bfb[o];                                                 \
    if (PHASE == 0) {                                                            \
      float s1 = h, s2 = h * h;                                                  \
      _Pragma("unroll")                                                          \
      for (int off = 1; off < 32; off <<= 1) {                                   \
        s1 += __shfl_xor(s1, off);                                               \
        s2 += __shfl_xor(s2, off);                                               \
      }                                                                          \
      if (lane31 == 0) {                                                         \
        p1[(long)o * 1024 + b * 128 + nt] = s1;                                  \
        p2[(long)o * 1024 + b * 128 + nt] = s2;                                  \
      }                                                                          \
    } else {                                                                     \
      float y = scale[o] * h + shift[o];                                         \
      y = LEAKY(y);                                                              \
      float mx = y, sm = y;                                                      \
      _Pragma("unroll")                                                          \
      for (int off = 1; off < 32; off <<= 1) {                                   \
        mx = fmaxf(mx, __shfl_xor(mx, off));                                     \
        sm += __shfl_xor(sm, off);                                               \
      }                                                                          \
      if (lane31 == 0) {                                                         \
        p1[((long)b * 1024 + o) * 128 + nt] = mx;                                \
        p2[((long)b * 1024 + o) * 128 + nt] = sm;                                \
      }                                                                          \
    }                                                                            \
  }

template<int PHASE>
__global__ __launch_bounds__(256) void fusion_mfma(const ushort* __restrict__ packW,
                                                   const ushort* __restrict__ packB,
                                                   const float* __restrict__ bfb,
                                                   const float* __restrict__ scale,
                                                   const float* __restrict__ shift,
                                                   int N,
                                                   float* __restrict__ p1,
                                                   float* __restrict__ p2) {
  __shared__ ushort sB[2][12 * 512];
  const int tid = threadIdx.x;
  const int nt = blockIdx.x, z = blockIdx.y, b = blockIdx.z;
  const int w = tid >> 6, l = tid & 63;
  const int lane31 = l & 31, hf = l >> 5;
  const int PB = N >> 5;
  const ushort* srcB = packB + (((long)b * PB + nt) * 96) * 512;

  for (int i = tid * 8; i < 12 * 512; i += 2048)
    __builtin_amdgcn_global_load_lds(
        (const __attribute__((address_space(1))) void*)(srcB + i),
        (__attribute__((address_space(3))) void*)(&sB[0][i]), 16, 0, 0);
  __syncthreads();

  f32x16 acc0 = {}, acc1 = {}, acc2 = {}, acc3 = {};
  const ushort* aw0 = packW + ((long)(z * 16 + 0 + w) * 96) * 512 + l * 8;
  const ushort* aw1 = packW + ((long)(z * 16 + 4 + w) * 96) * 512 + l * 8;
  const ushort* aw2 = packW + ((long)(z * 16 + 8 + w) * 96) * 512 + l * 8;
  const ushort* aw3 = packW + ((long)(z * 16 + 12 + w) * 96) * 512 + l * 8;

  int cur = 0;
  for (int ch = 0; ch < 8; ++ch) {
    if (ch + 1 < 8) {
      const ushort* src = srcB + (ch + 1) * 12 * 512;
      for (int i = tid * 8; i < 12 * 512; i += 2048)
        __builtin_amdgcn_global_load_lds(
            (const __attribute__((address_space(1))) void*)(src + i),
            (__attribute__((address_space(3))) void*)(&sB[cur ^ 1][i]), 16, 0, 0);
    }
    #pragma unroll
    for (int kcl = 0; kcl < 12; ++kcl) {
      const int kc = ch * 12 + kcl;
      bf16x8 bf = *reinterpret_cast<const bf16x8*>(&sB[cur][kcl * 512 + l * 8]);
      bf16x8 a0 = *reinterpret_cast<const bf16x8*>(aw0 + (long)kc * 512);
      acc0 = __builtin_amdgcn_mfma_f32_32x32x16_bf16(a0, bf, acc0, 0, 0, 0);
      bf16x8 a1 = *reinterpret_cast<const bf16x8*>(aw1 + (long)kc * 512);
      acc1 = __builtin_amdgcn_mfma_f32_32x32x16_bf16(a1, bf, acc1, 0, 0, 0);
      bf16x8 a2 = *reinterpret_cast<const bf16x8*>(aw2 + (long)kc * 512);
      acc2 = __builtin_amdgcn_mfma_f32_32x32x16_bf16(a2, bf, acc2, 0, 0, 0);
      bf16x8 a3 = *reinterpret_cast<const bf16x8*>(aw3 + (long)kc * 512);
      acc3 = __builtin_amdgcn_mfma_f32_32x32x16_bf16(a3, bf, acc3, 0, 0, 0);
    }
    __syncthreads();
    cur ^= 1;
  }

  FUS_EPI(acc0, 0)
  FUS_EPI(acc1, 1)
  FUS_EPI(acc2, 2)
  FUS_EPI(acc3, 3)
}

__global__ void finalize_fusion(const float* __restrict__ ps1, const float* __restrict__ ps2,
                                const float* __restrict__ g, const float* __restrict__ beta,
                                float* __restrict__ scale, float* __restrict__ shift) {
  int o = blockIdx.x * 256 + threadIdx.x;
  if (o < 1024) {
    double s1 = 0.0, s2 = 0.0;
    for (int k = 0; k < 1024; ++k) {
      s1 += (double)ps1[(long)o * 1024 + k];
      s2 += (double)ps2[(long)o * 1024 + k];
    }
    double invM = 1.0 / 32768.0;
    double mean = s1 * invM;
    double var = s2 * invM - mean * mean;
    double sc = (double)g[o] / sqrt(var + 1e-5);
    scale[o] = (float)sc;
    shift[o] = (float)((double)beta[o] - mean * sc);
  }
}

__global__ void pool_reduce2(const float* __restrict__ pmax, const float* __restrict__ psum,
                             float* __restrict__ x1x2) {
  int id = blockIdx.x * 256 + threadIdx.x;
  if (id < 8 * 1024) {
    int b = id >> 10, o = id & 1023;
    float mx = -3.0e38f, sm = 0.f;
    for (int t = 0; t < 128; ++t) {
      mx = fmaxf(mx, pmax[(long)id * 128 + t]);
      sm += psum[(long)id * 128 + t];
    }
    x1x2[(long)b * 2048 + o] = mx;
    x1x2[(long)b * 2048 + 1024 + o] = sm * (1.f / 4096.f);
  }
}

// ----------------------------------------------------------- classifier -----
__global__ __launch_bounds__(256) void fc_kernel(const float* __restrict__ in, int Cin, int O,
                                                 const float* __restrict__ W,
                                                 const float* __restrict__ bias,
                                                 const float* __restrict__ g,
                                                 const float* __restrict__ beta,
                                                 float* __restrict__ outp, int do_bn) {
  const int tid = threadIdx.x;
  const int o = blockIdx.x * 32 + (tid >> 3);
  const int bb = tid & 7;
  const int oc = (o < O) ? o : (O - 1);
  const float* ir = in + (long)bb * Cin;
  const float* wr = W + (long)oc * Cin;
  float dot = 0.f;
  for (int c = 0; c < Cin; c += 4) {
    float4 a = *reinterpret_cast<const float4*>(&ir[c]);
    float4 w = *reinterpret_cast<const float4*>(&wr[c]);
    dot += a.x * w.x + a.y * w.y + a.z * w.z + a.w * w.w;
  }
  float h = dot + bias[oc];
  if (do_bn) {
    float s = h;
    s += __shfl_xor(s, 1, 8); s += __shfl_xor(s, 2, 8); s += __shfl_xor(s, 4, 8);
    float mean = s * 0.125f;
    float dv = (h - mean) * (h - mean);
    dv += __shfl_xor(dv, 1, 8); dv += __shfl_xor(dv, 2, 8); dv += __shfl_xor(dv, 4, 8);
    float var = dv * 0.125f;
    float y = (h - mean) * (float)(1.0 / sqrt((double)var + 1e-5)) * g[oc] + beta[oc];
    h = LEAKY(y);
  }
  if (o < O) outp[(long)bb * O + o] = h;
}

// ---------------------------------------------------------------- driver ----
extern "C" void kernel_launch(void* const* d_in, const int* in_sizes, int n_in,
                              void* d_out, int out_size, void* d_ws, size_t ws_size,
                              hipStream_t stream) {
  const int B = 8, N = 4096;
  const float* x   = (const float*)d_in[0];
  const float* w1 = (const float*)d_in[2];  const float* g1 = (const float*)d_in[3];  const float* b1 = (const float*)d_in[4];
  const float* w2 = (const float*)d_in[5];  const float* g2 = (const float*)d_in[6];  const float* b2 = (const float*)d_in[7];
  const float* w3 = (const float*)d_in[8];  const float* g3 = (const float*)d_in[9];  const float* b3 = (const float*)d_in[10];
  const float* w4 = (const float*)d_in[11]; const float* g4 = (const float*)d_in[12]; const float* b4 = (const float*)d_in[13];
  const float* wf = (const float*)d_in[14]; const float* bfv = (const float*)d_in[15];
  const float* gf = (const float*)d_in[16]; const float* betaf = (const float*)d_in[17];
  const float* wc1 = (const float*)d_in[18]; const float* bc1 = (const float*)d_in[19];
  const float* gc1 = (const float*)d_in[20]; const float* betac1 = (const float*)d_in[21];
  const float* wc2 = (const float*)d_in[22]; const float* bc2 = (const float*)d_in[23];
  const float* gc2 = (const float*)d_in[24]; const float* betac2 = (const float*)d_in[25];
  const float* wc3 = (const float*)d_in[26]; const float* bc3 = (const float*)d_in[27];

  char* p = (char*)d_ws;
  auto alloc = [&](size_t bytes) -> char* {
    char* r = p;
    p += (bytes + 255) & ~(size_t)255;
    return r;
  };
  float* feat  = (float*)alloc((size_t)B * 512 * N * 4);   // 67.1MB
  int*   idx   = (int*)  alloc((size_t)B * N * 9 * 4);
  int*   cand  = (int*)  alloc((size_t)B * N * 32 * 4);    // 4.2MB
  float* xxg   = (float*)alloc((size_t)B * N * 4);
  // R region (4 x 33.55MB = u|v|hmax|hmin). Overlays:
  //   kNN phase:   packR->u, packC->hmax, xpm->hmin
  //   edge phase:  u|v|hmax|hmin proper
  //   fusion:      packB spans u+v+hmax exactly (100.66MB); partials in hmin
  float* u     = (float*)alloc((size_t)B * N * 256 * 4);
  float* v     = (float*)alloc((size_t)B * N * 256 * 4);
  float* hmax  = (float*)alloc((size_t)B * N * 256 * 4);
  float* hmin  = (float*)alloc((size_t)B * N * 256 * 4);
  ushort* packR = (ushort*)u;
  ushort* packC = (ushort*)hmax;
  float*  xpm   = hmin;
  ushort* packB = (ushort*)u;
  float*  ps1   = hmin;
  float*  ps2   = hmin + 1048576;
  float*  pmaxp = hmin + 2 * 1048576;
  float*  psump = hmin + 3 * 1048576;
  float* At    = (float*)alloc(128 * 256 * 4);
  float* W2t   = (float*)alloc(128 * 256 * 4);
  ushort* packW = (ushort*)alloc((size_t)32 * 96 * 512 * 2);  // 3.1MB
  double* S1   = (double*)alloc(1024 * 8);
  double* S2   = (double*)alloc(1024 * 8);
  float* scale = (float*)alloc(1024 * 4);
  float* shift = (float*)alloc(1024 * 4);
  float* x1x2  = (float*)alloc((size_t)B * 2048 * 4);
  float* h1    = (float*)alloc((size_t)B * 512 * 4);
  float* h2    = (float*)alloc((size_t)B * 256 * 4);

  dim3 gpack(N / 32, B);
  dim3 gknn(N / 128, B, 2);
  dim3 grr(N / 8, B);
  dim3 gxx(N / 256, B);

  pack3_wf<<<32, 256, 0, stream>>>(wf, packW);

  auto edge = [&](const float* inp, long in_bstride, int Cin, int O, const float* W,
                  const float* g, const float* beta, int c0) {
    prep_wt<<<(O * Cin + 255) / 256, 256, 0, stream>>>(W, Cin, O, At, W2t);
    dim3 gg(N / 64, O / 64, B);
    gemm_cn_no<<<gg, 256, 0, stream>>>(At, Cin, O, inp, in_bstride, N, u);
    gemm_cn_no<<<gg, 256, 0, stream>>>(W2t, Cin, O, inp, in_bstride, N, v);
    hipMemsetAsync(S1, 0, O * 8, stream);
    hipMemsetAsync(S2, 0, O * 8, stream);
    edge_pass<<<gg, 256, 0, stream>>>(u, v, idx, O, N, hmax, hmin, S1, S2);
    finalize_scale<<<(O + 255) / 256, 256, 0, stream>>>(S1, S2, g, beta,
                                                        1.0 / ((double)B * N * 9), O, scale, shift);
    edge_out<<<dim3(N / 64, B), 256, 0, stream>>>(hmax, hmin, scale, shift, O, N,
                                                  feat + (long)c0 * N, (long)512 * N);
  };

  // layer 1: C=3, K'=9 -> KC=1
  xx_kernel<3><<<gxx, 256, 0, stream>>>(x, (long)3 * N, N, xxg);
  pack3_kernel<3, 1><<<gpack, 256, 0, stream>>>(x, (long)3 * N, N, packR, packC, xpm);
  knn_v2<1><<<gknn, 256, 0, stream>>>(packR, packC, xxg, N, cand);
  rerank_kernel<3><<<grr, 256, 0, stream>>>(xpm, N, xxg, cand, idx);
  edge(x, (long)3 * N, 3, 64, w1, g1, b1, 0);

  // layer 2: C=64, K'=192 -> KC=12
  xx_kernel<64><<<gxx, 256, 0, stream>>>(feat, (long)512 * N, N, xxg);
  pack3_kernel<64, 12><<<gpack, 256, 0, stream>>>(feat, (long)512 * N, N, packR, packC, xpm);
  knn_v2<12><<<gknn, 256, 0, stream>>>(packR, packC, xxg, N, cand);
  rerank_kernel<64><<<grr, 256, 0, stream>>>(xpm, N, xxg, cand, idx);
  edge(feat, (long)512 * N, 64, 64, w2, g2, b2, 64);

  // layer 3: C=64
  xx_kernel<64><<<gxx, 256, 0, stream>>>(feat + (long)64 * N, (long)512 * N, N, xxg);
  pack3_kernel<64, 12><<<gpack, 256, 0, stream>>>(feat + (long)64 * N, (long)512 * N, N,
                                                  packR, packC, xpm);
  knn_v2<12><<<gknn, 256, 0, stream>>>(packR, packC, xxg, N, cand);
  rerank_kernel<64><<<grr, 256, 0, stream>>>(xpm, N, xxg, cand, idx);
  edge(feat + (long)64 * N, (long)512 * N, 64, 128, w3, g3, b3, 128);

  // layer 4: C=128, K'=384 -> KC=24
  xx_kernel<128><<<gxx, 256, 0, stream>>>(feat + (long)128 * N, (long)512 * N, N, xxg);
  pack3_kernel<128, 24><<<gpack, 256, 0, stream>>>(feat + (long)128 * N, (long)512 * N, N,
                                                   packR, packC, xpm);
  knn_v2<24><<<gknn, 256, 0, stream>>>(packR, packC, xxg, N, cand);
  rerank_kernel<128><<<grr, 256, 0, stream>>>(xpm, N, xxg, cand, idx);
  edge(feat + (long)128 * N, (long)512 * N, 128, 256, w4, g4, b4, 256);

  // fusion conv 512->1024 via split-bf16 MFMA, two passes, h never stored
  pack3_feat<<<dim3(N / 32, B), 256, 0, stream>>>(feat, N, packB);
  dim3 gfu(N / 32, 2, B);
  fusion_mfma<0><<<gfu, 256, 0, stream>>>(packW, packB, bfv, nullptr, nullptr, N, ps1, ps2);
  finalize_fusion<<<4, 256, 0, stream>>>(ps1, ps2, gf, betaf, scale, shift);
  fusion_mfma<1><<<gfu, 256, 0, stream>>>(packW, packB, bfv, scale, shift, N, pmaxp, psump);
  pool_reduce2<<<32, 256, 0, stream>>>(pmaxp, psump, x1x2);

  fc_kernel<<<16, 256, 0, stream>>>(x1x2, 2048, 512, wc1, bc1, gc1, betac1, h1, 1);
  fc_kernel<<<8, 256, 0, stream>>>(h1, 512, 256, wc2, bc2, gc2, betac2, h2, 1);
  fc_kernel<<<2, 256, 0, stream>>>(h2, 256, 40, wc3, bc3, nullptr, nullptr, (float*)d_out, 0);
}

// Round 8
// 3740.945 us; speedup vs baseline: 1.6992x; 1.0155x over previous
//
#include <hip/hip_runtime.h>
#include <math.h>
#include <float.h>

// DGCNN forward, MI355X. f32 except: kNN distance GEMM + fusion conv (3-term
// split-bf16 MFMA; x = hi + mid, products hi.hi + mid.hi + hi.mid).
// kNN two-phase: MFMA approx -> 32-cand pool -> exact f32 re-rank (r2 rounding).
// kNN v3: xx_m folded into GEMM as 2 extra k'-slots (cand:(xx_hi,xx_mid),
//         query:(-0.5,-0.5)) -> no sxx LDS; merge pool aliases A-tile dbuf.
// Fusion: two MFMA passes (stats, then BN+leaky+pool in-register) - h never stored.

#define LEAKY(y) ((y) >= 0.f ? (y) : 0.2f * (y))

using f32x16 = __attribute__((ext_vector_type(16))) float;
using bf16x8 = __attribute__((ext_vector_type(8))) __bf16;
using short8v = __attribute__((ext_vector_type(8))) short;

__device__ inline ushort f2bf(float x) {
  unsigned u = __float_as_uint(x);
  unsigned r = (u + 0x7fff + ((u >> 16) & 1)) >> 16;
  return (ushort)r;
}

// ------------------------------------------------------------- xx = sum x^2 --
template<int C>
__global__ void xx_kernel(const float* __restrict__ xin, long bstride, int N,
                          float* __restrict__ xxg) {
  int n = blockIdx.x * 256 + threadIdx.x;
  int b = blockIdx.y;
  if (n < N) {
    const float* xb = xin + (long)b * bstride;
    float s = 0.f;
    #pragma unroll
    for (int c = 0; c < C; ++c) { float t = xb[(long)c * N + n]; s += t * t; }
    xxg[(long)b * N + n] = s;
  }
}

// ---------------------------------------- pack points into MFMA frag order ---
// R slices (query/B-op): [hi, hi, mid | -0.5, -0.5]
// C slices (cand /A-op): [hi, mid, hi | xx_hi, xx_mid]
// => acc = inner - 0.5*xx_m ; d = fmaf(-2, acc, xx_n).
// Also emits point-major f32 copy xpm[(b*N+n)*C + c] for the exact rerank.
template<int C, int KCc>
__global__ __launch_bounds__(256) void pack3_kernel(const float* __restrict__ xin, long bstride,
                                                    int N, const float* __restrict__ xxg,
                                                    ushort* __restrict__ packR,
                                                    ushort* __restrict__ packC,
                                                    float* __restrict__ xpm) {
  __shared__ float xt[C][32];
  const int tid = threadIdx.x;
  const int pb = blockIdx.x, b = blockIdx.y;
  for (int i = tid; i < C * 32; i += 256) {
    int c = i >> 5, j = i & 31;
    xt[c][j] = xin[(long)b * bstride + (long)c * N + pb * 32 + j];
  }
  __syncthreads();
  for (int i = tid; i < 32 * C; i += 256) {
    int pt = i / C, c = i % C;
    xpm[((long)b * N + pb * 32 + pt) * C + c] = xt[c][pt];
  }
  const int PB = N >> 5;
  for (int it = tid; it < KCc * 64; it += 256) {
    int kc = it >> 6, l = it & 63;
    int pt = l & 31;
    union { ushort u[8]; short8v v; } R, Cc;
    #pragma unroll
    for (int e = 0; e < 8; ++e) {
      int kp = kc * 16 + ((l >> 5) << 3) + e;
      ushort rv = 0, cv = 0;
      if (kp < 3 * C) {
        int s = kp / C, c = kp % C;
        float xv = xt[c][pt];
        ushort hi = f2bf(xv);
        float hif = __uint_as_float((unsigned)hi << 16);
        ushort mid = f2bf(xv - hif);
        rv = (s == 2) ? mid : hi;
        cv = (s == 1) ? mid : hi;
      } else if (kp == 3 * C) {
        float xxv = xxg[(long)b * N + pb * 32 + pt];
        cv = f2bf(xxv);
        rv = 0xBF00;                       // bf16(-0.5), exact
      } else if (kp == 3 * C + 1) {
        float xxv = xxg[(long)b * N + pb * 32 + pt];
        ushort hi = f2bf(xxv);
        float hif = __uint_as_float((unsigned)hi << 16);
        cv = f2bf(xxv - hif);
        rv = 0xBF00;
      }
      R.u[e] = rv; Cc.u[e] = cv;
    }
    long off = (((long)b * PB + pb) * KCc + kc) * 512 + l * 8;
    *reinterpret_cast<short8v*>(&packR[off]) = R.v;
    *reinterpret_cast<short8v*>(&packC[off]) = Cc.v;
  }
}

// ----------------------------------------------------- kNN phase 1 (MFMA) ---
#define KNN_TOP9_UPDATE(d_, gi_)                                                 \
  if (d_ < td[8] || (d_ == td[8] && gi_ < ti[8])) {                              \
    td[8] = d_; ti[8] = gi_;                                                     \
    _Pragma("unroll")                                                            \
    for (int s_ = 8; s_ > 0; --s_) {                                             \
      bool sw_ = (td[s_] < td[s_ - 1]) || (td[s_] == td[s_ - 1] && ti[s_] < ti[s_ - 1]); \
      if (sw_) {                                                                 \
        float tf_ = td[s_]; td[s_] = td[s_ - 1]; td[s_ - 1] = tf_;               \
        int tn_ = ti[s_]; ti[s_] = ti[s_ - 1]; ti[s_ - 1] = tn_;                 \
      }                                                                          \
    }                                                                            \
  }

// grid (N/128, B, 2): 4 waves x 128 query rows; z = m-half. B-frags in regs;
// A-tile (32 cands) dbuf in LDS via global_load_lds; merge pool aliases A-tile.
template<int KCc, int MINW>
__global__ __launch_bounds__(256, MINW) void knn_v3(const ushort* __restrict__ packR,
                                                    const ushort* __restrict__ packC,
                                                    const float* __restrict__ xxg,
                                                    int N, int* __restrict__ cand) {
  constexpr int SA_ELEMS = KCc * 512;
  constexpr int SA_BYTES = SA_ELEMS * 2;
  constexpr int POOL = (2 * SA_BYTES > 18432) ? 2 * SA_BYTES : 18432;
  __shared__ __align__(16) char smem[POOL];
  ushort* const sA0 = (ushort*)smem;
  ushort* const sA1 = (ushort*)(smem + SA_BYTES);

  const int tid = threadIdx.x;
  const int b = blockIdx.y, rowblk = blockIdx.x, z = blockIdx.z;
  const int w = tid >> 6, l = tid & 63;
  const int lane31 = l & 31, hf = l >> 5;
  const int PB = N >> 5;
  const int HALF = PB >> 1;

  // B-fragments: wave w owns rows (rowblk*4 + w)*32 .. +31
  const ushort* rp = packR + (((long)b * PB + rowblk * 4 + w) * (long)KCc) * 512 + l * 8;
  bf16x8 bfr[KCc];
  #pragma unroll
  for (int kc = 0; kc < KCc; ++kc)
    bfr[kc] = *reinterpret_cast<const bf16x8*>(rp + kc * 512);

  const ushort* srcb = packC + ((long)b * PB) * (long)SA_ELEMS;
  const int mb0 = z * HALF;

  {
    const ushort* src = srcb + (long)mb0 * SA_ELEMS;
    for (int i = tid * 8; i < SA_ELEMS; i += 2048)
      __builtin_amdgcn_global_load_lds(
          (const __attribute__((address_space(1))) void*)(src + i),
          (__attribute__((address_space(3))) void*)(sA0 + i), 16, 0, 0);
  }

  const int n_glob = rowblk * 128 + w * 32 + lane31;
  const float xr = xxg[(long)b * N + n_glob];

  float td[9]; int ti[9];
  #pragma unroll
  for (int s = 0; s < 9; ++s) { td[s] = 3.0e38f; ti[s] = 0x7fffffff; }

  __syncthreads();

  for (int t = 0; t < HALF; ++t) {
    const int mb = mb0 + t;
    const ushort* curA = (t & 1) ? sA1 : sA0;
    ushort* nxtA = (t & 1) ? sA0 : sA1;
    if (t + 1 < HALF) {
      const ushort* src = srcb + (long)(mb + 1) * SA_ELEMS;
      for (int i = tid * 8; i < SA_ELEMS; i += 2048)
        __builtin_amdgcn_global_load_lds(
            (const __attribute__((address_space(1))) void*)(src + i),
            (__attribute__((address_space(3))) void*)(nxtA + i), 16, 0, 0);
    }
    f32x16 acc = {};
    #pragma unroll
    for (int kc = 0; kc < KCc; ++kc) {
      bf16x8 af = *reinterpret_cast<const bf16x8*>(curA + kc * 512 + l * 8);
      acc = __builtin_amdgcn_mfma_f32_32x32x16_bf16(af, bfr[kc], acc, 0, 0, 0);
    }
    #pragma unroll
    for (int reg = 0; reg < 16; ++reg) {
      int m_loc = (reg & 3) + 8 * (reg >> 2) + 4 * hf;
      int m_glob = (mb << 5) + m_loc;
      float d = fmaf(-2.0f, acc[reg], xr);   // = xx_n - 2*inner + xx_m
      if (m_glob == n_glob) d = 3.0e38f;
      KNN_TOP9_UPDATE(d, m_glob)
    }
    __syncthreads();                          // next tile staged; curA free
  }

  // merge: per row 2 lists (hf 0/1) x 9 -> top-16. Pool aliases sA (dead).
  float* mD = (float*)smem;                   // [128][18]
  int*   mI = (int*)(smem + 9216);            // [128][18]
  const int row = w * 32 + lane31;
  #pragma unroll
  for (int s = 0; s < 9; ++s) {
    mD[row * 18 + hf * 9 + s] = td[s];
    mI[row * 18 + hf * 9 + s] = ti[s];
  }
  __syncthreads();
  if (tid < 128) {
    int p0 = 0, p1 = 0;
    const long ob = ((long)b * N + rowblk * 128 + tid) * 32 + z * 16;
    for (int s = 0; s < 16; ++s) {
      float d0 = (p0 < 9) ? mD[tid * 18 + p0] : 3.3e38f;
      int   i0 = (p0 < 9) ? mI[tid * 18 + p0] : 0x7fffffff;
      float d1 = (p1 < 9) ? mD[tid * 18 + 9 + p1] : 3.3e38f;
      int   i1 = (p1 < 9) ? mI[tid * 18 + 9 + p1] : 0x7fffffff;
      bool t0 = (d0 < d1) || (d0 == d1 && i0 < i1);
      cand[ob + s] = t0 ? i0 : i1;
      if (t0) ++p0; else ++p1;
    }
  }
}

// ---------------- exact f32 re-rank of 32 candidates (point-major input) ----
template<int C>
__global__ __launch_bounds__(256) void rerank_kernel(const float* __restrict__ xpm,
                                                     int N, const float* __restrict__ xxg,
                                                     const int* __restrict__ cand,
                                                     int* __restrict__ idx_out) {
  __shared__ float sq[8][C];
  __shared__ float sd[8][33];
  __shared__ int   si[8][33];
  const int tid = threadIdx.x;
  const int b = blockIdx.y, n0 = blockIdx.x * 8;
  const float* xb = xpm + (long)b * N * C;
  for (int i = tid; i < 8 * C; i += 256) {
    int r = i / C, c = i % C;
    sq[r][c] = xb[(long)(n0 + r) * C + c];
  }
  __syncthreads();
  const int r = tid >> 5, j = tid & 31;
  const int n = n0 + r;
  const int m = cand[(((long)b * N + n) << 5) + j];
  const float* cv = xb + (long)m * C;
  float dot = 0.f;
  if constexpr ((C & 3) == 0) {
    for (int c = 0; c < C; c += 4) {
      float4 v4 = *reinterpret_cast<const float4*>(cv + c);
      dot = fmaf(sq[r][c + 0], v4.x, dot);
      dot = fmaf(sq[r][c + 1], v4.y, dot);
      dot = fmaf(sq[r][c + 2], v4.z, dot);
      dot = fmaf(sq[r][c + 3], v4.w, dot);
    }
  } else {
    for (int c = 0; c < C; ++c) dot = fmaf(sq[r][c], cv[c], dot);
  }
  float d = (xxg[(long)b * N + n] - 2.0f * dot) + xxg[(long)b * N + m];
  if (m == n) d = 3.0e38f;
  sd[r][j] = d; si[r][j] = m;
  __syncthreads();
  int rank = 0;
  #pragma unroll
  for (int t = 0; t < 32; ++t) {
    float dd = sd[r][t]; int ii = si[r][t];
    if (dd < d || (dd == d && ii < m)) rank++;
  }
  if (rank < 9) idx_out[((long)b * N + n) * 9 + rank] = m;
}

// ------------------------------------------- W transposes (coalesced GEMMs) --
__global__ void prep_wt(const float* __restrict__ W, int Cin, int O,
                        float* __restrict__ At, float* __restrict__ W2t) {
  int i = blockIdx.x * 256 + threadIdx.x;
  if (i < O * Cin) {
    int o = i % O, c = i / O;
    float w1v = W[(long)o * 2 * Cin + c];
    float w2v = W[(long)o * 2 * Cin + Cin + c];
    At[(long)c * O + o]  = w1v - w2v;
    W2t[(long)c * O + o] = w2v;
  }
}

// ------------------------------ GEMM: out[b][n][o] = sum_c Wt[c][o] in[b][c][n]
__global__ __launch_bounds__(256) void gemm_cn_no(const float* __restrict__ Wt,
                                                  int C, int O,
                                                  const float* __restrict__ in,
                                                  long in_bstride, int N,
                                                  float* __restrict__ out) {
  const int tid = threadIdx.x;
  const int n0 = blockIdx.x * 64, o0 = blockIdx.y * 64, b = blockIdx.z;
  __shared__ float wT[128][64];
  __shared__ float inT[128][64];
  for (int i = tid; i < C * 64; i += 256) {
    int c = i >> 6, j = i & 63;
    wT[c][j]  = Wt[(long)c * O + o0 + j];
    inT[c][j] = in[(long)b * in_bstride + (long)c * N + n0 + j];
  }
  __syncthreads();
  const int tr = tid >> 4, tc = tid & 15;
  float acc[4][4];
  #pragma unroll
  for (int i = 0; i < 4; ++i)
    #pragma unroll
    for (int j = 0; j < 4; ++j) acc[i][j] = 0.f;
  for (int c = 0; c < C; ++c) {
    float4 a4 = *reinterpret_cast<const float4*>(&wT[c][4 * tr]);
    float4 b4 = *reinterpret_cast<const float4*>(&inT[c][4 * tc]);
    float av[4] = {a4.x, a4.y, a4.z, a4.w};
    float bv[4] = {b4.x, b4.y, b4.z, b4.w};
    #pragma unroll
    for (int i = 0; i < 4; ++i)
      #pragma unroll
      for (int j = 0; j < 4; ++j) acc[i][j] = fmaf(av[i], bv[j], acc[i][j]);
  }
  #pragma unroll
  for (int j = 0; j < 4; ++j) {
    float4 st = make_float4(acc[0][j], acc[1][j], acc[2][j], acc[3][j]);
    *reinterpret_cast<float4*>(&out[((long)b * N + n0 + 4 * tc + j) * O + o0 + 4 * tr]) = st;
  }
}

// ------------------- single gather pass: stats + hmax + hmin per (n,o) ------
__global__ __launch_bounds__(256) void edge_pass(const float* __restrict__ u,
                                                 const float* __restrict__ v,
                                                 const int* __restrict__ idx,
                                                 int O, int N,
                                                 float* __restrict__ hmax,
                                                 float* __restrict__ hmin,
                                                 double* __restrict__ S1,
                                                 double* __restrict__ S2) {
  const int tid = threadIdx.x;
  const int n0 = blockIdx.x * 64, o0 = blockIdx.y * 64, b = blockIdx.z;
  __shared__ int sidx[64][9];
  __shared__ float4 redA[4][16];
  __shared__ float4 redB[4][16];
  for (int i = tid; i < 576; i += 256)
    ((int*)sidx)[i] = idx[((long)b * N + n0) * 9 + i];
  __syncthreads();
  const int nl = tid >> 4, oq = tid & 15;
  const long base = (long)b * N;
  const int ocol = o0 + 4 * oq;
  float4 s1 = make_float4(0.f, 0.f, 0.f, 0.f);
  float4 s2 = make_float4(0.f, 0.f, 0.f, 0.f);
  for (int g = 0; g < 4; ++g) {
    const int n = g * 16 + nl;
    const float4 u4 = *reinterpret_cast<const float4*>(&u[(base + n0 + n) * O + ocol]);
    float4 mx = make_float4(-3.0e38f, -3.0e38f, -3.0e38f, -3.0e38f);
    float4 mn = make_float4(3.0e38f, 3.0e38f, 3.0e38f, 3.0e38f);
    #pragma unroll
    for (int k = 0; k < 9; ++k) {
      int m = sidx[n][k];
      const float4 v4 = *reinterpret_cast<const float4*>(&v[(base + m) * O + ocol]);
      float hx = u4.x + v4.x, hy = u4.y + v4.y, hz = u4.z + v4.z, hw = u4.w + v4.w;
      s1.x += hx; s1.y += hy; s1.z += hz; s1.w += hw;
      s2.x = fmaf(hx, hx, s2.x); s2.y = fmaf(hy, hy, s2.y);
      s2.z = fmaf(hz, hz, s2.z); s2.w = fmaf(hw, hw, s2.w);
      mx.x = fmaxf(mx.x, hx); mx.y = fmaxf(mx.y, hy); mx.z = fmaxf(mx.z, hz); mx.w = fmaxf(mx.w, hw);
      mn.x = fminf(mn.x, hx); mn.y = fminf(mn.y, hy); mn.z = fminf(mn.z, hz); mn.w = fminf(mn.w, hw);
    }
    *reinterpret_cast<float4*>(&hmax[(base + n0 + n) * O + ocol]) = mx;
    *reinterpret_cast<float4*>(&hmin[(base + n0 + n) * O + ocol]) = mn;
  }
  s1.x += __shfl_xor(s1.x, 16); s1.y += __shfl_xor(s1.y, 16);
  s1.z += __shfl_xor(s1.z, 16); s1.w += __shfl_xor(s1.w, 16);
  s2.x += __shfl_xor(s2.x, 16); s2.y += __shfl_xor(s2.y, 16);
  s2.z += __shfl_xor(s2.z, 16); s2.w += __shfl_xor(s2.w, 16);
  s1.x += __shfl_xor(s1.x, 32); s1.y += __shfl_xor(s1.y, 32);
  s1.z += __shfl_xor(s1.z, 32); s1.w += __shfl_xor(s1.w, 32);
  s2.x += __shfl_xor(s2.x, 32); s2.y += __shfl_xor(s2.y, 32);
  s2.z += __shfl_xor(s2.z, 32); s2.w += __shfl_xor(s2.w, 32);
  if ((tid & 48) == 0) { redA[tid >> 6][oq] = s1; redB[tid >> 6][oq] = s2; }
  __syncthreads();
  if (tid < 16) {
    float4 a = redA[0][tid], bb = redB[0][tid];
    #pragma unroll
    for (int ww = 1; ww < 4; ++ww) {
      float4 t1 = redA[ww][tid], t2 = redB[ww][tid];
      a.x += t1.x; a.y += t1.y; a.z += t1.z; a.w += t1.w;
      bb.x += t2.x; bb.y += t2.y; bb.z += t2.z; bb.w += t2.w;
    }
    int o = o0 + 4 * tid;
    atomicAdd(&S1[o + 0], (double)a.x);  atomicAdd(&S1[o + 1], (double)a.y);
    atomicAdd(&S1[o + 2], (double)a.z);  atomicAdd(&S1[o + 3], (double)a.w);
    atomicAdd(&S2[o + 0], (double)bb.x); atomicAdd(&S2[o + 1], (double)bb.y);
    atomicAdd(&S2[o + 2], (double)bb.z); atomicAdd(&S2[o + 3], (double)bb.w);
  }
}

__global__ void finalize_scale(const double* __restrict__ S1, const double* __restrict__ S2,
                               const float* __restrict__ g, const float* __restrict__ beta,
                               double invM, int O, float* __restrict__ scale,
                               float* __restrict__ shift) {
  int o = blockIdx.x * 256 + threadIdx.x;
  if (o < O) {
    double mean = S1[o] * invM;
    double var = S2[o] * invM - mean * mean;
    double sc = (double)g[o] / sqrt(var + 1e-5);
    scale[o] = (float)sc;
    shift[o] = (float)((double)beta[o] - mean * sc);
  }
}

// ------------------- elementwise finalize + transpose to (B,O,N) ------------
__global__ __launch_bounds__(256) void edge_out(const float* __restrict__ hmax,
                                                const float* __restrict__ hmin,
                                                const float* __restrict__ scale,
                                                const float* __restrict__ shift,
                                                int O, int N,
                                                float* __restrict__ outp, long out_bstride) {
  const int tid = threadIdx.x;
  const int b = blockIdx.y, n0 = blockIdx.x * 64;
  __shared__ float yt[64][65];
  const int ol = tid & 63, nl = tid >> 6;
  const long base = (long)b * N;
  for (int oc = 0; oc < O; oc += 64) {
    float sc = scale[oc + ol], sh = shift[oc + ol];
    __syncthreads();
    for (int ng = 0; ng < 16; ++ng) {
      int n = ng * 4 + nl;
      long off = (base + n0 + n) * O + oc + ol;
      float hv = (sc >= 0.f) ? hmax[off] : hmin[off];
      float y = sc * hv + sh;
      yt[ol][n] = LEAKY(y);
    }
    __syncthreads();
    for (int rr = 0; rr < 16; ++rr) {
      int r = rr * 4 + nl;
      outp[(long)b * out_bstride + (long)(oc + r) * N + n0 + ol] = yt[r][ol];
    }
  }
}

// ----------------- fusion packs: weights (A-pattern), feat (B-pattern) ------
__global__ __launch_bounds__(256) void pack3_wf(const float* __restrict__ wf,
                                                ushort* __restrict__ packW) {
  __shared__ float wt[32][129];
  const int po = blockIdx.x;
  const int tid = threadIdx.x;
  for (int c0 = 0; c0 < 512; c0 += 128) {
    __syncthreads();
    for (int i = tid; i < 32 * 128; i += 256) {
      int o = i >> 7, c = i & 127;
      wt[o][c] = wf[(long)(po * 32 + o) * 512 + c0 + c];
    }
    __syncthreads();
    #pragma unroll
    for (int s = 0; s < 3; ++s) {
      int kc0 = (s * 512 + c0) >> 4;
      for (int it = tid; it < 8 * 64; it += 256) {
        int kcl = it >> 6, l = it & 63;
        union { ushort u[8]; short8v v; } P;
        #pragma unroll
        for (int e = 0; e < 8; ++e) {
          int kp = (kc0 + kcl) * 16 + ((l >> 5) << 3) + e;
          int c = kp - s * 512 - c0;
          float xv = wt[l & 31][c];
          ushort hi = f2bf(xv);
          if (s == 1) {
            float hif = __uint_as_float((unsigned)hi << 16);
            P.u[e] = f2bf(xv - hif);
          } else P.u[e] = hi;
        }
        *reinterpret_cast<short8v*>(&packW[((long)po * 96 + kc0 + kcl) * 512 + l * 8]) = P.v;
      }
    }
  }
}

__global__ __launch_bounds__(256) void pack3_feat(const float* __restrict__ feat, int N,
                                                  ushort* __restrict__ packB) {
  __shared__ float xt[64][33];
  const int pb = blockIdx.x, b = blockIdx.y;
  const int tid = threadIdx.x;
  const int PB = N >> 5;
  for (int c0 = 0; c0 < 512; c0 += 64) {
    __syncthreads();
    for (int i = tid; i < 64 * 32; i += 256) {
      int c = i >> 5, j = i & 31;
      xt[c][j] = feat[((long)b * 512 + c0 + c) * N + pb * 32 + j];
    }
    __syncthreads();
    #pragma unroll
    for (int s = 0; s < 3; ++s) {
      int kc0 = (s * 512 + c0) >> 4;
      for (int it = tid; it < 4 * 64; it += 256) {
        int kcl = it >> 6, l = it & 63;
        union { ushort u[8]; short8v v; } P;
        #pragma unroll
        for (int e = 0; e < 8; ++e) {
          int kp = (kc0 + kcl) * 16 + ((l >> 5) << 3) + e;
          int c = kp - s * 512 - c0;
          float xv = xt[c][l & 31];
          ushort hi = f2bf(xv);
          if (s == 2) {
            float hif = __uint_as_float((unsigned)hi << 16);
            P.u[e] = f2bf(xv - hif);
          } else P.u[e] = hi;
        }
        *reinterpret_cast<short8v*>(
            &packB[(((long)b * PB + pb) * 96 + kc0 + kcl) * 512 + l * 8]) = P.v;
      }
    }
  }
}

// ---------------- fusion MFMA: PHASE 0 = stats partials, 1 = pool partials --
#define FUS_EPI(ACC, Q)                                                          \
  _Pragma("unroll")                                                              \
  for (int reg = 0; reg < 16; ++reg) {                                           \
    int o = ((z * 16 + (Q) * 4 + w) << 5) + (reg & 3) + 8 * (reg >> 2) + 4 * hf; \
    float h = ACC[reg] + bfb[o];                                                 \
    if (PHASE == 0) {                                                            \
      float s1 = h, s2 = h * h;                                                  \
      _Pragma("unroll")                                                          \
      for (int off = 1; off < 32; off <<= 1) {                                   \
        s1 += __shfl_xor(s1, off);                                               \
        s2 += __shfl_xor(s2, off);                                               \
      }                                                                          \
      if (lane31 == 0) {                                                         \
        p1[(long)o * 1024 + b * 128 + nt] = s1;                                  \
        p2[(long)o * 1024 + b * 128 + nt] = s2;                                  \
      }                                                                          \
    } else {                                                                     \
      float y = scale[o] * h + shift[o];                                         \
      y = LEAKY(y);                                                              \
      float mx = y, sm = y;                                                      \
      _Pragma("unroll")                                                          \
      for (int off = 1; off < 32; off <<= 1) {                                   \
        mx = fmaxf(mx, __shfl_xor(mx, off));                                     \
        sm += __shfl_xor(sm, off);                                               \
      }                                                                          \
      if (lane31 == 0) {                                                         \
        p1[((long)b * 1024 + o) * 128 + nt] = mx;                                \
        p2[((long)b * 1024 + o) * 128 + nt] = sm;                                \
      }                                                                          \
    }                                                                            \
  }

template<int PHASE>
__global__ __launch_bounds__(256) void fusion_mfma(const ushort* __restrict__ packW,
                                                   const ushort* __restrict__ packB,
                                                   const float* __restrict__ bfb,
                                                   const float* __restrict__ scale,
                                                   const float* __restrict__ shift,
                                                   int N,
                                                   float* __restrict__ p1,
                                                   float* __restrict__ p2) {
  __shared__ ushort sB[2][12 * 512];
  const int tid = threadIdx.x;
  const int nt = blockIdx.x, z = blockIdx.y, b = blockIdx.z;
  const int w = tid >> 6, l = tid & 63;
  const int lane31 = l & 31, hf = l >> 5;
  const int PB = N >> 5;
  const ushort* srcB = packB + (((long)b * PB + nt) * 96) * 512;

  for (int i = tid * 8; i < 12 * 512; i += 2048)
    __builtin_amdgcn_global_load_lds(
        (const __attribute__((address_space(1))) void*)(srcB + i),
        (__attribute__((address_space(3))) void*)(&sB[0][i]), 16, 0, 0);
  __syncthreads();

  f32x16 acc0 = {}, acc1 = {}, acc2 = {}, acc3 = {};
  const ushort* aw0 = packW + ((long)(z * 16 + 0 + w) * 96) * 512 + l * 8;
  const ushort* aw1 = packW + ((long)(z * 16 + 4 + w) * 96) * 512 + l * 8;
  const ushort* aw2 = packW + ((long)(z * 16 + 8 + w) * 96) * 512 + l * 8;
  const ushort* aw3 = packW + ((long)(z * 16 + 12 + w) * 96) * 512 + l * 8;

  int cur = 0;
  for (int ch = 0; ch < 8; ++ch) {
    if (ch + 1 < 8) {
      const ushort* src = srcB + (ch + 1) * 12 * 512;
      for (int i = tid * 8; i < 12 * 512; i += 2048)
        __builtin_amdgcn_global_load_lds(
            (const __attribute__((address_space(1))) void*)(src + i),
            (__attribute__((address_space(3))) void*)(&sB[cur ^ 1][i]), 16, 0, 0);
    }
    #pragma unroll
    for (int kcl = 0; kcl < 12; ++kcl) {
      const int kc = ch * 12 + kcl;
      bf16x8 bf = *reinterpret_cast<const bf16x8*>(&sB[cur][kcl * 512 + l * 8]);
      bf16x8 a0 = *reinterpret_cast<const bf16x8*>(aw0 + (long)kc * 512);
      acc0 = __builtin_amdgcn_mfma_f32_32x32x16_bf16(a0, bf, acc0, 0, 0, 0);
      bf16x8 a1 = *reinterpret_cast<const bf16x8*>(aw1 + (long)kc * 512);
      acc1 = __builtin_amdgcn_mfma_f32_32x32x16_bf16(a1, bf, acc1, 0, 0, 0);
      bf16x8 a2 = *reinterpret_cast<const bf16x8*>(aw2 + (long)kc * 512);
      acc2 = __builtin_amdgcn_mfma_f32_32x32x16_bf16(a2, bf, acc2, 0, 0, 0);
      bf16x8 a3 = *reinterpret_cast<const bf16x8*>(aw3 + (long)kc * 512);
      acc3 = __builtin_amdgcn_mfma_f32_32x32x16_bf16(a3, bf, acc3, 0, 0, 0);
    }
    __syncthreads();
    cur ^= 1;
  }

  FUS_EPI(acc0, 0)
  FUS_EPI(acc1, 1)
  FUS_EPI(acc2, 2)
  FUS_EPI(acc3, 3)
}

__global__ void finalize_fusion(const float* __restrict__ ps1, const float* __restrict__ ps2,
                                const float* __restrict__ g, const float* __restrict__ beta,
                                float* __restrict__ scale, float* __restrict__ shift) {
  int o = blockIdx.x * 256 + threadIdx.x;
  if (o < 1024) {
    double s1 = 0.0, s2 = 0.0;
    for (int k = 0; k < 1024; ++k) {
      s1 += (double)ps1[(long)o * 1024 + k];
      s2 += (double)ps2[(long)o * 1024 + k];
    }
    double invM = 1.0 / 32768.0;
    double mean = s1 * invM;
    double var = s2 * invM - mean * mean;
    double sc = (double)g[o] / sqrt(var + 1e-5);
    scale[o] = (float)sc;
    shift[o] = (float)((double)beta[o] - mean * sc);
  }
}

__global__ void pool_reduce2(const float* __restrict__ pmax, const float* __restrict__ psum,
                             float* __restrict__ x1x2) {
  int id = blockIdx.x * 256 + threadIdx.x;
  if (id < 8 * 1024) {
    int b = id >> 10, o = id & 1023;
    float mx = -3.0e38f, sm = 0.f;
    for (int t = 0; t < 128; ++t) {
      mx = fmaxf(mx, pmax[(long)id * 128 + t]);
      sm += psum[(long)id * 128 + t];
    }
    x1x2[(long)b * 2048 + o] = mx;
    x1x2[(long)b * 2048 + 1024 + o] = sm * (1.f / 4096.f);
  }
}

// ----------------------------------------------------------- classifier -----
__global__ __launch_bounds__(256) void fc_kernel(const float* __restrict__ in, int Cin, int O,
                                                 const float* __restrict__ W,
                                                 const float* __restrict__ bias,
                                                 const float* __restrict__ g,
                                                 const float* __restrict__ beta,
                                                 float* __restrict__ outp, int do_bn) {
  const int tid = threadIdx.x;
  const int o = blockIdx.x * 32 + (tid >> 3);
  const int bb = tid & 7;
  const int oc = (o < O) ? o : (O - 1);
  const float* ir = in + (long)bb * Cin;
  const float* wr = W + (long)oc * Cin;
  float dot = 0.f;
  for (int c = 0; c < Cin; c += 4) {
    float4 a = *reinterpret_cast<const float4*>(&ir[c]);
    float4 w = *reinterpret_cast<const float4*>(&wr[c]);
    dot += a.x * w.x + a.y * w.y + a.z * w.z + a.w * w.w;
  }
  float h = dot + bias[oc];
  if (do_bn) {
    float s = h;
    s += __shfl_xor(s, 1, 8); s += __shfl_xor(s, 2, 8); s += __shfl_xor(s, 4, 8);
    float mean = s * 0.125f;
    float dv = (h - mean) * (h - mean);
    dv += __shfl_xor(dv, 1, 8); dv += __shfl_xor(dv, 2, 8); dv += __shfl_xor(dv, 4, 8);
    float var = dv * 0.125f;
    float y = (h - mean) * (float)(1.0 / sqrt((double)var + 1e-5)) * g[oc] + beta[oc];
    h = LEAKY(y);
  }
  if (o < O) outp[(long)bb * O + o] = h;
}

// ---------------------------------------------------------------- driver ----
extern "C" void kernel_launch(void* const* d_in, const int* in_sizes, int n_in,
                              void* d_out, int out_size, void* d_ws, size_t ws_size,
                              hipStream_t stream) {
  const int B = 8, N = 4096;
  const float* x   = (const float*)d_in[0];
  const float* w1 = (const float*)d_in[2];  const float* g1 = (const float*)d_in[3];  const float* b1 = (const float*)d_in[4];
  const float* w2 = (const float*)d_in[5];  const float* g2 = (const float*)d_in[6];  const float* b2 = (const float*)d_in[7];
  const float* w3 = (const float*)d_in[8];  const float* g3 = (const float*)d_in[9];  const float* b3 = (const float*)d_in[10];
  const float* w4 = (const float*)d_in[11]; const float* g4 = (const float*)d_in[12]; const float* b4 = (const float*)d_in[13];
  const float* wf = (const float*)d_in[14]; const float* bfv = (const float*)d_in[15];
  const float* gf = (const float*)d_in[16]; const float* betaf = (const float*)d_in[17];
  const float* wc1 = (const float*)d_in[18]; const float* bc1 = (const float*)d_in[19];
  const float* gc1 = (const float*)d_in[20]; const float* betac1 = (const float*)d_in[21];
  const float* wc2 = (const float*)d_in[22]; const float* bc2 = (const float*)d_in[23];
  const float* gc2 = (const float*)d_in[24]; const float* betac2 = (const float*)d_in[25];
  const float* wc3 = (const float*)d_in[26]; const float* bc3 = (const float*)d_in[27];

  char* p = (char*)d_ws;
  auto alloc = [&](size_t bytes) -> char* {
    char* r = p;
    p += (bytes + 255) & ~(size_t)255;
    return r;
  };
  float* feat  = (float*)alloc((size_t)B * 512 * N * 4);   // 67.1MB
  int*   idx   = (int*)  alloc((size_t)B * N * 9 * 4);
  int*   cand  = (int*)  alloc((size_t)B * N * 32 * 4);    // 4.2MB
  float* xxg   = (float*)alloc((size_t)B * N * 4);
  // R region (4 x 33.55MB = u|v|hmax|hmin). Overlays:
  //   kNN phase:   packR->u (KC<=25: 26.2MB), packC->hmax, xpm->hmin
  //   edge phase:  u|v|hmax|hmin proper
  //   fusion:      packB spans u+v+hmax exactly (100.66MB); partials in hmin
  float* u     = (float*)alloc((size_t)B * N * 256 * 4);
  float* v     = (float*)alloc((size_t)B * N * 256 * 4);
  float* hmax  = (float*)alloc((size_t)B * N * 256 * 4);
  float* hmin  = (float*)alloc((size_t)B * N * 256 * 4);
  ushort* packR = (ushort*)u;
  ushort* packC = (ushort*)hmax;
  float*  xpm   = hmin;
  ushort* packB = (ushort*)u;
  float*  ps1   = hmin;
  float*  ps2   = hmin + 1048576;
  float*  pmaxp = hmin + 2 * 1048576;
  float*  psump = hmin + 3 * 1048576;
  float* At    = (float*)alloc(128 * 256 * 4);
  float* W2t   = (float*)alloc(128 * 256 * 4);
  ushort* packW = (ushort*)alloc((size_t)32 * 96 * 512 * 2);  // 3.1MB
  double* S1   = (double*)alloc(1024 * 8);
  double* S2   = (double*)alloc(1024 * 8);
  float* scale = (float*)alloc(1024 * 4);
  float* shift = (float*)alloc(1024 * 4);
  float* x1x2  = (float*)alloc((size_t)B * 2048 * 4);
  float* h1    = (float*)alloc((size_t)B * 512 * 4);
  float* h2    = (float*)alloc((size_t)B * 256 * 4);

  dim3 gpack(N / 32, B);
  dim3 gknn(N / 128, B, 2);
  dim3 grr(N / 8, B);
  dim3 gxx(N / 256, B);

  pack3_wf<<<32, 256, 0, stream>>>(wf, packW);

  auto edge = [&](const float* inp, long in_bstride, int Cin, int O, const float* W,
                  const float* g, const float* beta, int c0) {
    prep_wt<<<(O * Cin + 255) / 256, 256, 0, stream>>>(W, Cin, O, At, W2t);
    dim3 gg(N / 64, O / 64, B);
    gemm_cn_no<<<gg, 256, 0, stream>>>(At, Cin, O, inp, in_bstride, N, u);
    gemm_cn_no<<<gg, 256, 0, stream>>>(W2t, Cin, O, inp, in_bstride, N, v);
    hipMemsetAsync(S1, 0, O * 8, stream);
    hipMemsetAsync(S2, 0, O * 8, stream);
    edge_pass<<<gg, 256, 0, stream>>>(u, v, idx, O, N, hmax, hmin, S1, S2);
    finalize_scale<<<(O + 255) / 256, 256, 0, stream>>>(S1, S2, g, beta,
                                                        1.0 / ((double)B * N * 9), O, scale, shift);
    edge_out<<<dim3(N / 64, B), 256, 0, stream>>>(hmax, hmin, scale, shift, O, N,
                                                  feat + (long)c0 * N, (long)512 * N);
  };

  // layer 1: C=3, K'=9+2=11 -> KC=1
  xx_kernel<3><<<gxx, 256, 0, stream>>>(x, (long)3 * N, N, xxg);
  pack3_kernel<3, 1><<<gpack, 256, 0, stream>>>(x, (long)3 * N, N, xxg, packR, packC, xpm);
  knn_v3<1, 4><<<gknn, 256, 0, stream>>>(packR, packC, xxg, N, cand);
  rerank_kernel<3><<<grr, 256, 0, stream>>>(xpm, N, xxg, cand, idx);
  edge(x, (long)3 * N, 3, 64, w1, g1, b1, 0);

  // layer 2: C=64, K'=192+2 -> KC=13
  xx_kernel<64><<<gxx, 256, 0, stream>>>(feat, (long)512 * N, N, xxg);
  pack3_kernel<64, 13><<<gpack, 256, 0, stream>>>(feat, (long)512 * N, N, xxg, packR, packC, xpm);
  knn_v3<13, 4><<<gknn, 256, 0, stream>>>(packR, packC, xxg, N, cand);
  rerank_kernel<64><<<grr, 256, 0, stream>>>(xpm, N, xxg, cand, idx);
  edge(feat, (long)512 * N, 64, 64, w2, g2, b2, 64);

  // layer 3: C=64
  xx_kernel<64><<<gxx, 256, 0, stream>>>(feat + (long)64 * N, (long)512 * N, N, xxg);
  pack3_kernel<64, 13><<<gpack, 256, 0, stream>>>(feat + (long)64 * N, (long)512 * N, N, xxg,
                                                  packR, packC, xpm);
  knn_v3<13, 4><<<gknn, 256, 0, stream>>>(packR, packC, xxg, N, cand);
  rerank_kernel<64><<<grr, 256, 0, stream>>>(xpm, N, xxg, cand, idx);
  edge(feat + (long)64 * N, (long)512 * N, 64, 128, w3, g3, b3, 128);

  // layer 4: C=128, K'=384+2 -> KC=25
  xx_kernel<128><<<gxx, 256, 0, stream>>>(feat + (long)128 * N, (long)512 * N, N, xxg);
  pack3_kernel<128, 25><<<gpack, 256, 0, stream>>>(feat + (long)128 * N, (long)512 * N, N, xxg,
                                                   packR, packC, xpm);
  knn_v3<25, 3><<<gknn, 256, 0, stream>>>(packR, packC, xxg, N, cand);
  rerank_kernel<128><<<grr, 256, 0, stream>>>(xpm, N, xxg, cand, idx);
  edge(feat + (long)128 * N, (long)512 * N, 128, 256, w4, g4, b4, 256);

  // fusion conv 512->1024 via split-bf16 MFMA, two passes, h never stored
  pack3_feat<<<dim3(N / 32, B), 256, 0, stream>>>(feat, N, packB);
  dim3 gfu(N / 32, 2, B);
  fusion_mfma<0><<<gfu, 256, 0, stream>>>(packW, packB, bfv, nullptr, nullptr, N, ps1, ps2);
  finalize_fusion<<<4, 256, 0, stream>>>(ps1, ps2, gf, betaf, scale, shift);
  fusion_mfma<1><<<gfu, 256, 0, stream>>>(packW, packB, bfv, scale, shift, N, pmaxp, psump);
  pool_reduce2<<<32, 256, 0, stream>>>(pmaxp, psump, x1x2);

  fc_kernel<<<16, 256, 0, stream>>>(x1x2, 2048, 512, wc1, bc1, gc1, betac1, h1, 1);
  fc_kernel<<<8, 256, 0, stream>>>(h1, 512, 256, wc2, bc2, gc2, betac2, h2, 1);
  fc_kernel<<<2, 256, 0, stream>>>(h2, 256, 40, wc3, bc3, nullptr, nullptr, (float*)d_out, 0);
}

// Round 9
// 2244.096 us; speedup vs baseline: 2.8326x; 1.6670x over previous
//
#include <hip/hip_runtime.h>
#include <math.h>
#include <float.h>

// DGCNN forward, MI355X. f32 except: kNN distance GEMM + fusion conv (3-term
// split-bf16 MFMA; x = hi + mid, products hi.hi + mid.hi + hi.mid).
// kNN two-phase: MFMA approx -> per-partition top-9 pool -> exact f32 re-rank.
// kNN v4: xx_m folded into GEMM; strict-< stable insertion (no per-lane
//         tie-break: membership-only, exact rerank re-orders); self-mask
//         hoisted to wave-uniform branch; z-split=4 for L1-L3 (occupancy).
// Fusion: two MFMA passes (stats, then BN+leaky+pool in-register) - h never stored.

#define LEAKY(y) ((y) >= 0.f ? (y) : 0.2f * (y))

using f32x16 = __attribute__((ext_vector_type(16))) float;
using bf16x8 = __attribute__((ext_vector_type(8))) __bf16;
using short8v = __attribute__((ext_vector_type(8))) short;

__device__ inline ushort f2bf(float x) {
  unsigned u = __float_as_uint(x);
  unsigned r = (u + 0x7fff + ((u >> 16) & 1)) >> 16;
  return (ushort)r;
}

// ------------------------------------------------------------- xx = sum x^2 --
template<int C>
__global__ void xx_kernel(const float* __restrict__ xin, long bstride, int N,
                          float* __restrict__ xxg) {
  int n = blockIdx.x * 256 + threadIdx.x;
  int b = blockIdx.y;
  if (n < N) {
    const float* xb = xin + (long)b * bstride;
    float s = 0.f;
    #pragma unroll
    for (int c = 0; c < C; ++c) { float t = xb[(long)c * N + n]; s += t * t; }
    xxg[(long)b * N + n] = s;
  }
}

// ---------------------------------------- pack points into MFMA frag order ---
// R slices (query/B-op): [hi, hi, mid | -0.5, -0.5]
// C slices (cand /A-op): [hi, mid, hi | xx_hi, xx_mid]
// => acc = inner - 0.5*xx_m ; d = fmaf(-2, acc, xx_n).
// Also emits point-major f32 copy xpm[(b*N+n)*C + c] for the exact rerank.
template<int C, int KCc>
__global__ __launch_bounds__(256) void pack3_kernel(const float* __restrict__ xin, long bstride,
                                                    int N, const float* __restrict__ xxg,
                                                    ushort* __restrict__ packR,
                                                    ushort* __restrict__ packC,
                                                    float* __restrict__ xpm) {
  __shared__ float xt[C][32];
  const int tid = threadIdx.x;
  const int pb = blockIdx.x, b = blockIdx.y;
  for (int i = tid; i < C * 32; i += 256) {
    int c = i >> 5, j = i & 31;
    xt[c][j] = xin[(long)b * bstride + (long)c * N + pb * 32 + j];
  }
  __syncthreads();
  for (int i = tid; i < 32 * C; i += 256) {
    int pt = i / C, c = i % C;
    xpm[((long)b * N + pb * 32 + pt) * C + c] = xt[c][pt];
  }
  const int PB = N >> 5;
  for (int it = tid; it < KCc * 64; it += 256) {
    int kc = it >> 6, l = it & 63;
    int pt = l & 31;
    union { ushort u[8]; short8v v; } R, Cc;
    #pragma unroll
    for (int e = 0; e < 8; ++e) {
      int kp = kc * 16 + ((l >> 5) << 3) + e;
      ushort rv = 0, cv = 0;
      if (kp < 3 * C) {
        int s = kp / C, c = kp % C;
        float xv = xt[c][pt];
        ushort hi = f2bf(xv);
        float hif = __uint_as_float((unsigned)hi << 16);
        ushort mid = f2bf(xv - hif);
        rv = (s == 2) ? mid : hi;
        cv = (s == 1) ? mid : hi;
      } else if (kp == 3 * C) {
        float xxv = xxg[(long)b * N + pb * 32 + pt];
        cv = f2bf(xxv);
        rv = 0xBF00;                       // bf16(-0.5), exact
      } else if (kp == 3 * C + 1) {
        float xxv = xxg[(long)b * N + pb * 32 + pt];
        ushort hi = f2bf(xxv);
        float hif = __uint_as_float((unsigned)hi << 16);
        cv = f2bf(xxv - hif);
        rv = 0xBF00;
      }
      R.u[e] = rv; Cc.u[e] = cv;
    }
    long off = (((long)b * PB + pb) * KCc + kc) * 512 + l * 8;
    *reinterpret_cast<short8v*>(&packR[off]) = R.v;
    *reinterpret_cast<short8v*>(&packC[off]) = Cc.v;
  }
}

// ----------------------------------------------------- kNN phase 1 (MFMA) ---
// Strict-< stable insertion (no tie-break): within a lane candidates arrive in
// ascending index, so equal distances keep the lowest index automatically.
#define KNN_INSERT(d_, gi_)                                       \
  if (d_ < td[8]) {                                               \
    float dc_ = d_; int ic_ = gi_;                                \
    _Pragma("unroll")                                             \
    for (int s_ = 0; s_ < 9; ++s_) {                              \
      bool lt_ = dc_ < td[s_];                                    \
      float tn_ = lt_ ? dc_ : td[s_];                             \
      float dn_ = lt_ ? td[s_] : dc_;                             \
      int iin_ = lt_ ? ic_ : ti[s_];                              \
      int inx_ = lt_ ? ti[s_] : ic_;                              \
      td[s_] = tn_; dc_ = dn_; ti[s_] = iin_; ic_ = inx_;         \
    }                                                             \
  }

#define KNN_SCAN(SELF)                                            \
  _Pragma("unroll")                                               \
  for (int reg = 0; reg < 16; ++reg) {                            \
    int m_loc = (reg & 3) + 8 * (reg >> 2) + 4 * hf;              \
    int m_glob = (mb << 5) + m_loc;                               \
    float d = fmaf(-2.0f, acc[reg], xr);                          \
    if (SELF && m_glob == n_glob) d = 3.0e38f;                    \
    KNN_INSERT(d, m_glob)                                         \
  }

// grid (N/128, B, Z): 4 waves x 128 query rows; z = m-partition. B-frags in
// regs; A-tile (32 cands) dbuf in LDS via global_load_lds (shared by 4 waves);
// merge pool aliases A-tile. Emits per row: top-16 of 2x9 into cand[.. z*16].
template<int KCc, int MINW, int Z>
__global__ __launch_bounds__(256, MINW) void knn_v4(const ushort* __restrict__ packR,
                                                    const ushort* __restrict__ packC,
                                                    const float* __restrict__ xxg,
                                                    int N, int* __restrict__ cand) {
  constexpr int SA_ELEMS = KCc * 512;
  constexpr int SA_BYTES = SA_ELEMS * 2;
  constexpr int POOL = (2 * SA_BYTES > 18432) ? 2 * SA_BYTES : 18432;
  __shared__ __align__(16) char smem[POOL];
  ushort* const sA0 = (ushort*)smem;
  ushort* const sA1 = (ushort*)(smem + SA_BYTES);

  const int tid = threadIdx.x;
  const int b = blockIdx.y, rowblk = blockIdx.x, z = blockIdx.z;
  const int w = tid >> 6, l = tid & 63;
  const int lane31 = l & 31, hf = l >> 5;
  const int PB = N >> 5;
  const int HALF = PB / Z;
  const int myblk = rowblk * 4 + w;        // m-block containing this wave's rows

  const ushort* rp = packR + (((long)b * PB + myblk) * (long)KCc) * 512 + l * 8;
  bf16x8 bfr[KCc];
  #pragma unroll
  for (int kc = 0; kc < KCc; ++kc)
    bfr[kc] = *reinterpret_cast<const bf16x8*>(rp + kc * 512);

  const ushort* srcb = packC + ((long)b * PB) * (long)SA_ELEMS;
  const int mb0 = z * HALF;

  {
    const ushort* src = srcb + (long)mb0 * SA_ELEMS;
    for (int i = tid * 8; i < SA_ELEMS; i += 2048)
      __builtin_amdgcn_global_load_lds(
          (const __attribute__((address_space(1))) void*)(src + i),
          (__attribute__((address_space(3))) void*)(sA0 + i), 16, 0, 0);
  }

  const int n_glob = rowblk * 128 + w * 32 + lane31;
  const float xr = xxg[(long)b * N + n_glob];

  float td[9]; int ti[9];
  #pragma unroll
  for (int s = 0; s < 9; ++s) { td[s] = 3.0e38f; ti[s] = 0x7fffffff; }

  __syncthreads();

  for (int t = 0; t < HALF; ++t) {
    const int mb = mb0 + t;
    const ushort* curA = (t & 1) ? sA1 : sA0;
    ushort* nxtA = (t & 1) ? sA0 : sA1;
    if (t + 1 < HALF) {
      const ushort* src = srcb + (long)(mb + 1) * SA_ELEMS;
      for (int i = tid * 8; i < SA_ELEMS; i += 2048)
        __builtin_amdgcn_global_load_lds(
            (const __attribute__((address_space(1))) void*)(src + i),
            (__attribute__((address_space(3))) void*)(nxtA + i), 16, 0, 0);
    }
    f32x16 acc = {};
    #pragma unroll
    for (int kc = 0; kc < KCc; ++kc) {
      bf16x8 af = *reinterpret_cast<const bf16x8*>(curA + kc * 512 + l * 8);
      acc = __builtin_amdgcn_mfma_f32_32x32x16_bf16(af, bfr[kc], acc, 0, 0, 0);
    }
    if (mb == myblk) {
      KNN_SCAN(true)
    } else {
      KNN_SCAN(false)
    }
    __syncthreads();                          // next tile staged; curA free
  }

  // merge: per row 2 lists (hf 0/1) x 9 -> top-16 (with index tie-break).
  float* mD = (float*)smem;                   // [128][18]
  int*   mI = (int*)(smem + 9216);            // [128][18]
  const int row = w * 32 + lane31;
  #pragma unroll
  for (int s = 0; s < 9; ++s) {
    mD[row * 18 + hf * 9 + s] = td[s];
    mI[row * 18 + hf * 9 + s] = ti[s];
  }
  __syncthreads();
  if (tid < 128) {
    int p0 = 0, p1 = 0;
    const long ob = ((long)b * N + rowblk * 128 + tid) * (Z * 16) + z * 16;
    for (int s = 0; s < 16; ++s) {
      float d0 = (p0 < 9) ? mD[tid * 18 + p0] : 3.3e38f;
      int   i0 = (p0 < 9) ? mI[tid * 18 + p0] : 0x7fffffff;
      float d1 = (p1 < 9) ? mD[tid * 18 + 9 + p1] : 3.3e38f;
      int   i1 = (p1 < 9) ? mI[tid * 18 + 9 + p1] : 0x7fffffff;
      bool t0 = (d0 < d1) || (d0 == d1 && i0 < i1);
      cand[ob + s] = t0 ? i0 : i1;
      if (t0) ++p0; else ++p1;
    }
  }
}

// ---------------- exact f32 re-rank of P candidates (point-major input) -----
template<int C, int P>
__global__ __launch_bounds__(256) void rerank_kernel(const float* __restrict__ xpm,
                                                     int N, const float* __restrict__ xxg,
                                                     const int* __restrict__ cand,
                                                     int* __restrict__ idx_out) {
  constexpr int ROWS = 256 / P;
  __shared__ float sq[ROWS][C];
  __shared__ float sd[ROWS][P + 1];
  __shared__ int   si[ROWS][P + 1];
  const int tid = threadIdx.x;
  const int b = blockIdx.y, n0 = blockIdx.x * ROWS;
  const float* xb = xpm + (long)b * N * C;
  for (int i = tid; i < ROWS * C; i += 256) {
    int r = i / C, c = i % C;
    sq[r][c] = xb[(long)(n0 + r) * C + c];
  }
  __syncthreads();
  const int r = tid / P, j = tid % P;
  const int n = n0 + r;
  const int m = cand[((long)b * N + n) * P + j];
  const float* cv = xb + (long)m * C;
  float dot = 0.f;
  if constexpr ((C & 3) == 0) {
    for (int c = 0; c < C; c += 4) {
      float4 v4 = *reinterpret_cast<const float4*>(cv + c);
      dot = fmaf(sq[r][c + 0], v4.x, dot);
      dot = fmaf(sq[r][c + 1], v4.y, dot);
      dot = fmaf(sq[r][c + 2], v4.z, dot);
      dot = fmaf(sq[r][c + 3], v4.w, dot);
    }
  } else {
    for (int c = 0; c < C; ++c) dot = fmaf(sq[r][c], cv[c], dot);
  }
  float d = (xxg[(long)b * N + n] - 2.0f * dot) + xxg[(long)b * N + m];
  if (m == n) d = 3.0e38f;
  sd[r][j] = d; si[r][j] = m;
  __syncthreads();
  int rank = 0;
  #pragma unroll
  for (int t = 0; t < P; ++t) {
    float dd = sd[r][t]; int ii = si[r][t];
    if (dd < d || (dd == d && ii < m)) rank++;
  }
  if (rank < 9) idx_out[((long)b * N + n) * 9 + rank] = m;
}

// ------------------------------------------- W transposes (coalesced GEMMs) --
__global__ void prep_wt(const float* __restrict__ W, int Cin, int O,
                        float* __restrict__ At, float* __restrict__ W2t) {
  int i = blockIdx.x * 256 + threadIdx.x;
  if (i < O * Cin) {
    int o = i % O, c = i / O;
    float w1v = W[(long)o * 2 * Cin + c];
    float w2v = W[(long)o * 2 * Cin + Cin + c];
    At[(long)c * O + o]  = w1v - w2v;
    W2t[(long)c * O + o] = w2v;
  }
}

// ------------------------------ GEMM: out[b][n][o] = sum_c Wt[c][o] in[b][c][n]
__global__ __launch_bounds__(256) void gemm_cn_no(const float* __restrict__ Wt,
                                                  int C, int O,
                                                  const float* __restrict__ in,
                                                  long in_bstride, int N,
                                                  float* __restrict__ out) {
  const int tid = threadIdx.x;
  const int n0 = blockIdx.x * 64, o0 = blockIdx.y * 64, b = blockIdx.z;
  __shared__ float wT[128][64];
  __shared__ float inT[128][64];
  for (int i = tid; i < C * 64; i += 256) {
    int c = i >> 6, j = i & 63;
    wT[c][j]  = Wt[(long)c * O + o0 + j];
    inT[c][j] = in[(long)b * in_bstride + (long)c * N + n0 + j];
  }
  __syncthreads();
  const int tr = tid >> 4, tc = tid & 15;
  float acc[4][4];
  #pragma unroll
  for (int i = 0; i < 4; ++i)
    #pragma unroll
    for (int j = 0; j < 4; ++j) acc[i][j] = 0.f;
  for (int c = 0; c < C; ++c) {
    float4 a4 = *reinterpret_cast<const float4*>(&wT[c][4 * tr]);
    float4 b4 = *reinterpret_cast<const float4*>(&inT[c][4 * tc]);
    float av[4] = {a4.x, a4.y, a4.z, a4.w};
    float bv[4] = {b4.x, b4.y, b4.z, b4.w};
    #pragma unroll
    for (int i = 0; i < 4; ++i)
      #pragma unroll
      for (int j = 0; j < 4; ++j) acc[i][j] = fmaf(av[i], bv[j], acc[i][j]);
  }
  #pragma unroll
  for (int j = 0; j < 4; ++j) {
    float4 st = make_float4(acc[0][j], acc[1][j], acc[2][j], acc[3][j]);
    *reinterpret_cast<float4*>(&out[((long)b * N + n0 + 4 * tc + j) * O + o0 + 4 * tr]) = st;
  }
}

// ------------------- single gather pass: stats + hmax + hmin per (n,o) ------
__global__ __launch_bounds__(256) void edge_pass(const float* __restrict__ u,
                                                 const float* __restrict__ v,
                                                 const int* __restrict__ idx,
                                                 int O, int N,
                                                 float* __restrict__ hmax,
                                                 float* __restrict__ hmin,
                                                 double* __restrict__ S1,
                                                 double* __restrict__ S2) {
  const int tid = threadIdx.x;
  const int n0 = blockIdx.x * 64, o0 = blockIdx.y * 64, b = blockIdx.z;
  __shared__ int sidx[64][9];
  __shared__ float4 redA[4][16];
  __shared__ float4 redB[4][16];
  for (int i = tid; i < 576; i += 256)
    ((int*)sidx)[i] = idx[((long)b * N + n0) * 9 + i];
  __syncthreads();
  const int nl = tid >> 4, oq = tid & 15;
  const long base = (long)b * N;
  const int ocol = o0 + 4 * oq;
  float4 s1 = make_float4(0.f, 0.f, 0.f, 0.f);
  float4 s2 = make_float4(0.f, 0.f, 0.f, 0.f);
  for (int g = 0; g < 4; ++g) {
    const int n = g * 16 + nl;
    const float4 u4 = *reinterpret_cast<const float4*>(&u[(base + n0 + n) * O + ocol]);
    float4 mx = make_float4(-3.0e38f, -3.0e38f, -3.0e38f, -3.0e38f);
    float4 mn = make_float4(3.0e38f, 3.0e38f, 3.0e38f, 3.0e38f);
    #pragma unroll
    for (int k = 0; k < 9; ++k) {
      int m = sidx[n][k];
      const float4 v4 = *reinterpret_cast<const float4*>(&v[(base + m) * O + ocol]);
      float hx = u4.x + v4.x, hy = u4.y + v4.y, hz = u4.z + v4.z, hw = u4.w + v4.w;
      s1.x += hx; s1.y += hy; s1.z += hz; s1.w += hw;
      s2.x = fmaf(hx, hx, s2.x); s2.y = fmaf(hy, hy, s2.y);
      s2.z = fmaf(hz, hz, s2.z); s2.w = fmaf(hw, hw, s2.w);
      mx.x = fmaxf(mx.x, hx); mx.y = fmaxf(mx.y, hy); mx.z = fmaxf(mx.z, hz); mx.w = fmaxf(mx.w, hw);
      mn.x = fminf(mn.x, hx); mn.y = fminf(mn.y, hy); mn.z = fminf(mn.z, hz); mn.w = fminf(mn.w, hw);
    }
    *reinterpret_cast<float4*>(&hmax[(base + n0 + n) * O + ocol]) = mx;
    *reinterpret_cast<float4*>(&hmin[(base + n0 + n) * O + ocol]) = mn;
  }
  s1.x += __shfl_xor(s1.x, 16); s1.y += __shfl_xor(s1.y, 16);
  s1.z += __shfl_xor(s1.z, 16); s1.w += __shfl_xor(s1.w, 16);
  s2.x += __shfl_xor(s2.x, 16); s2.y += __shfl_xor(s2.y, 16);
  s2.z += __shfl_xor(s2.z, 16); s2.w += __shfl_xor(s2.w, 16);
  s1.x += __shfl_xor(s1.x, 32); s1.y += __shfl_xor(s1.y, 32);
  s1.z += __shfl_xor(s1.z, 32); s1.w += __shfl_xor(s1.w, 32);
  s2.x += __shfl_xor(s2.x, 32); s2.y += __shfl_xor(s2.y, 32);
  s2.z += __shfl_xor(s2.z, 32); s2.w += __shfl_xor(s2.w, 32);
  if ((tid & 48) == 0) { redA[tid >> 6][oq] = s1; redB[tid >> 6][oq] = s2; }
  __syncthreads();
  if (tid < 16) {
    float4 a = redA[0][tid], bb = redB[0][tid];
    #pragma unroll
    for (int ww = 1; ww < 4; ++ww) {
      float4 t1 = redA[ww][tid], t2 = redB[ww][tid];
      a.x += t1.x; a.y += t1.y; a.z += t1.z; a.w += t1.w;
      bb.x += t2.x; bb.y += t2.y; bb.z += t2.z; bb.w += t2.w;
    }
    int o = o0 + 4 * tid;
    atomicAdd(&S1[o + 0], (double)a.x);  atomicAdd(&S1[o + 1], (double)a.y);
    atomicAdd(&S1[o + 2], (double)a.z);  atomicAdd(&S1[o + 3], (double)a.w);
    atomicAdd(&S2[o + 0], (double)bb.x); atomicAdd(&S2[o + 1], (double)bb.y);
    atomicAdd(&S2[o + 2], (double)bb.z); atomicAdd(&S2[o + 3], (double)bb.w);
  }
}

__global__ void finalize_scale(const double* __restrict__ S1, const double* __restrict__ S2,
                               const float* __restrict__ g, const float* __restrict__ beta,
                               double invM, int O, float* __restrict__ scale,
                               float* __restrict__ shift) {
  int o = blockIdx.x * 256 + threadIdx.x;
  if (o < O) {
    double mean = S1[o] * invM;
    double var = S2[o] * invM - mean * mean;
    double sc = (double)g[o] / sqrt(var + 1e-5);
    scale[o] = (float)sc;
    shift[o] = (float)((double)beta[o] - mean * sc);
  }
}

// ------------------- elementwise finalize + transpose to (B,O,N) ------------
__global__ __launch_bounds__(256) void edge_out(const float* __restrict__ hmax,
                                                const float* __restrict__ hmin,
                                                const float* __restrict__ scale,
                                                const float* __restrict__ shift,
                                                int O, int N,
                                                float* __restrict__ outp, long out_bstride) {
  const int tid = threadIdx.x;
  const int b = blockIdx.y, n0 = blockIdx.x * 64;
  __shared__ float yt[64][65];
  const int ol = tid & 63, nl = tid >> 6;
  const long base = (long)b * N;
  for (int oc = 0; oc < O; oc += 64) {
    float sc = scale[oc + ol], sh = shift[oc + ol];
    __syncthreads();
    for (int ng = 0; ng < 16; ++ng) {
      int n = ng * 4 + nl;
      long off = (base + n0 + n) * O + oc + ol;
      float hv = (sc >= 0.f) ? hmax[off] : hmin[off];
      float y = sc * hv + sh;
      yt[ol][n] = LEAKY(y);
    }
    __syncthreads();
    for (int rr = 0; rr < 16; ++rr) {
      int r = rr * 4 + nl;
      outp[(long)b * out_bstride + (long)(oc + r) * N + n0 + ol] = yt[r][ol];
    }
  }
}

// ----------------- fusion packs: weights (A-pattern), feat (B-pattern) ------
__global__ __launch_bounds__(256) void pack3_wf(const float* __restrict__ wf,
                                                ushort* __restrict__ packW) {
  __shared__ float wt[32][129];
  const int po = blockIdx.x;
  const int tid = threadIdx.x;
  for (int c0 = 0; c0 < 512; c0 += 128) {
    __syncthreads();
    for (int i = tid; i < 32 * 128; i += 256) {
      int o = i >> 7, c = i & 127;
      wt[o][c] = wf[(long)(po * 32 + o) * 512 + c0 + c];
    }
    __syncthreads();
    #pragma unroll
    for (int s = 0; s < 3; ++s) {
      int kc0 = (s * 512 + c0) >> 4;
      for (int it = tid; it < 8 * 64; it += 256) {
        int kcl = it >> 6, l = it & 63;
        union { ushort u[8]; short8v v; } P;
        #pragma unroll
        for (int e = 0; e < 8; ++e) {
          int kp = (kc0 + kcl) * 16 + ((l >> 5) << 3) + e;
          int c = kp - s * 512 - c0;
          float xv = wt[l & 31][c];
          ushort hi = f2bf(xv);
          if (s == 1) {
            float hif = __uint_as_float((unsigned)hi << 16);
            P.u[e] = f2bf(xv - hif);
          } else P.u[e] = hi;
        }
        *reinterpret_cast<short8v*>(&packW[((long)po * 96 + kc0 + kcl) * 512 + l * 8]) = P.v;
      }
    }
  }
}

__global__ __launch_bounds__(256) void pack3_feat(const float* __restrict__ feat, int N,
                                                  ushort* __restrict__ packB) {
  __shared__ float xt[64][33];
  const int pb = blockIdx.x, b = blockIdx.y;
  const int tid = threadIdx.x;
  const int PB = N >> 5;
  for (int c0 = 0; c0 < 512; c0 += 64) {
    __syncthreads();
    for (int i = tid; i < 64 * 32; i += 256) {
      int c = i >> 5, j = i & 31;
      xt[c][j] = feat[((long)b * 512 + c0 + c) * N + pb * 32 + j];
    }
    __syncthreads();
    #pragma unroll
    for (int s = 0; s < 3; ++s) {
      int kc0 = (s * 512 + c0) >> 4;
      for (int it = tid; it < 4 * 64; it += 256) {
        int kcl = it >> 6, l = it & 63;
        union { ushort u[8]; short8v v; } P;
        #pragma unroll
        for (int e = 0; e < 8; ++e) {
          int kp = (kc0 + kcl) * 16 + ((l >> 5) << 3) + e;
          int c = kp - s * 512 - c0;
          float xv = xt[c][l & 31];
          ushort hi = f2bf(xv);
          if (s == 2) {
            float hif = __uint_as_float((unsigned)hi << 16);
            P.u[e] = f2bf(xv - hif);
          } else P.u[e] = hi;
        }
        *reinterpret_cast<short8v*>(
            &packB[(((long)b * PB + pb) * 96 + kc0 + kcl) * 512 + l * 8]) = P.v;
      }
    }
  }
}

// ---------------- fusion MFMA: PHASE 0 = stats partials, 1 = pool partials --
#define FUS_EPI(ACC, Q)                                                          \
  _Pragma("unroll")                                                              \
  for (int reg = 0; reg < 16; ++reg) {                                           \
    int o = ((z * 16 + (Q) * 4 + w) << 5) + (reg & 3) + 8 * (reg >> 2) + 4 * hf; \
    float h = ACC[reg] + bfb[o];                                                 \
    if (PHASE == 0) {                                                            \
      float s1 = h, s2 = h * h;                                                  \
      _Pragma("unroll")                                                          \
      for (int off = 1; off < 32; off <<= 1) {                                   \
        s1 += __shfl_xor(s1, off);                                               \
        s2 += __shfl_xor(s2, off);                                               \
      }                                                                          \
      if (lane31 == 0) {                                                         \
        p1[(long)o * 1024 + b * 128 + nt] = s1;                                  \
        p2[(long)o * 1024 + b * 128 + nt] = s2;                                  \
      }                                                                          \
    } else {                                                                     \
      float y = scale[o] * h + shift[o];                                         \
      y = LEAKY(y);                                                              \
      float mx = y, sm = y;                                                      \
      _Pragma("unroll")                                                          \
      for (int off = 1; off < 32; off <<= 1) {                                   \
        mx = fmaxf(mx, __shfl_xor(mx, off));                                     \
        sm += __shfl_xor(sm, off);                                               \
      }                                                                          \
      if (lane31 == 0) {                                                         \
        p1[((long)b * 1024 + o) * 128 + nt] = mx;                                \
        p2[((long)b * 1024 + o) * 128 + nt] = sm;                                \
      }                                                                          \
    }                                                                            \
  }

template<int PHASE>
__global__ __launch_bounds__(256) void fusion_mfma(const ushort* __restrict__ packW,
                                                   const ushort* __restrict__ packB,
                                                   const float* __restrict__ bfb,
                                                   const float* __restrict__ scale,
                                                   const float* __restrict__ shift,
                                                   int N,
                                                   float* __restrict__ p1,
                                                   float* __restrict__ p2) {
  __shared__ ushort sB[2][12 * 512];
  const int tid = threadIdx.x;
  const int nt = blockIdx.x, z = blockIdx.y, b = blockIdx.z;
  const int w = tid >> 6, l = tid & 63;
  const int lane31 = l & 31, hf = l >> 5;
  const int PB = N >> 5;
  const ushort* srcB = packB + (((long)b * PB + nt) * 96) * 512;

  for (int i = tid * 8; i < 12 * 512; i += 2048)
    __builtin_amdgcn_global_load_lds(
        (const __attribute__((address_space(1))) void*)(srcB + i),
        (__attribute__((address_space(3))) void*)(&sB[0][i]), 16, 0, 0);
  __syncthreads();

  f32x16 acc0 = {}, acc1 = {}, acc2 = {}, acc3 = {};
  const ushort* aw0 = packW + ((long)(z * 16 + 0 + w) * 96) * 512 + l * 8;
  const ushort* aw1 = packW + ((long)(z * 16 + 4 + w) * 96) * 512 + l * 8;
  const ushort* aw2 = packW + ((long)(z * 16 + 8 + w) * 96) * 512 + l * 8;
  const ushort* aw3 = packW + ((long)(z * 16 + 12 + w) * 96) * 512 + l * 8;

  int cur = 0;
  for (int ch = 0; ch < 8; ++ch) {
    if (ch + 1 < 8) {
      const ushort* src = srcB + (ch + 1) * 12 * 512;
      for (int i = tid * 8; i < 12 * 512; i += 2048)
        __builtin_amdgcn_global_load_lds(
            (const __attribute__((address_space(1))) void*)(src + i),
            (__attribute__((address_space(3))) void*)(&sB[cur ^ 1][i]), 16, 0, 0);
    }
    #pragma unroll
    for (int kcl = 0; kcl < 12; ++kcl) {
      const int kc = ch * 12 + kcl;
      bf16x8 bf = *reinterpret_cast<const bf16x8*>(&sB[cur][kcl * 512 + l * 8]);
      bf16x8 a0 = *reinterpret_cast<const bf16x8*>(aw0 + (long)kc * 512);
      acc0 = __builtin_amdgcn_mfma_f32_32x32x16_bf16(a0, bf, acc0, 0, 0, 0);
      bf16x8 a1 = *reinterpret_cast<const bf16x8*>(aw1 + (long)kc * 512);
      acc1 = __builtin_amdgcn_mfma_f32_32x32x16_bf16(a1, bf, acc1, 0, 0, 0);
      bf16x8 a2 = *reinterpret_cast<const bf16x8*>(aw2 + (long)kc * 512);
      acc2 = __builtin_amdgcn_mfma_f32_32x32x16_bf16(a2, bf, acc2, 0, 0, 0);
      bf16x8 a3 = *reinterpret_cast<const bf16x8*>(aw3 + (long)kc * 512);
      acc3 = __builtin_amdgcn_mfma_f32_32x32x16_bf16(a3, bf, acc3, 0, 0, 0);
    }
    __syncthreads();
    cur ^= 1;
  }

  FUS_EPI(acc0, 0)
  FUS_EPI(acc1, 1)
  FUS_EPI(acc2, 2)
  FUS_EPI(acc3, 3)
}

__global__ void finalize_fusion(const float* __restrict__ ps1, const float* __restrict__ ps2,
                                const float* __restrict__ g, const float* __restrict__ beta,
                                float* __restrict__ scale, float* __restrict__ shift) {
  int o = blockIdx.x * 256 + threadIdx.x;
  if (o < 1024) {
    double s1 = 0.0, s2 = 0.0;
    for (int k = 0; k < 1024; ++k) {
      s1 += (double)ps1[(long)o * 1024 + k];
      s2 += (double)ps2[(long)o * 1024 + k];
    }
    double invM = 1.0 / 32768.0;
    double mean = s1 * invM;
    double var = s2 * invM - mean * mean;
    double sc = (double)g[o] / sqrt(var + 1e-5);
    scale[o] = (float)sc;
    shift[o] = (float)((double)beta[o] - mean * sc);
  }
}

__global__ void pool_reduce2(const float* __restrict__ pmax, const float* __restrict__ psum,
                             float* __restrict__ x1x2) {
  int id = blockIdx.x * 256 + threadIdx.x;
  if (id < 8 * 1024) {
    int b = id >> 10, o = id & 1023;
    float mx = -3.0e38f, sm = 0.f;
    for (int t = 0; t < 128; ++t) {
      mx = fmaxf(mx, pmax[(long)id * 128 + t]);
      sm += psum[(long)id * 128 + t];
    }
    x1x2[(long)b * 2048 + o] = mx;
    x1x2[(long)b * 2048 + 1024 + o] = sm * (1.f / 4096.f);
  }
}

// ----------------------------------------------------------- classifier -----
__global__ __launch_bounds__(256) void fc_kernel(const float* __restrict__ in, int Cin, int O,
                                                 const float* __restrict__ W,
                                                 const float* __restrict__ bias,
                                                 const float* __restrict__ g,
                                                 const float* __restrict__ beta,
                                                 float* __restrict__ outp, int do_bn) {
  const int tid = threadIdx.x;
  const int o = blockIdx.x * 32 + (tid >> 3);
  const int bb = tid & 7;
  const int oc = (o < O) ? o : (O - 1);
  const float* ir = in + (long)bb * Cin;
  const float* wr = W + (long)oc * Cin;
  float dot = 0.f;
  for (int c = 0; c < Cin; c += 4) {
    float4 a = *reinterpret_cast<const float4*>(&ir[c]);
    float4 w = *reinterpret_cast<const float4*>(&wr[c]);
    dot += a.x * w.x + a.y * w.y + a.z * w.z + a.w * w.w;
  }
  float h = dot + bias[oc];
  if (do_bn) {
    float s = h;
    s += __shfl_xor(s, 1, 8); s += __shfl_xor(s, 2, 8); s += __shfl_xor(s, 4, 8);
    float mean = s * 0.125f;
    float dv = (h - mean) * (h - mean);
    dv += __shfl_xor(dv, 1, 8); dv += __shfl_xor(dv, 2, 8); dv += __shfl_xor(dv, 4, 8);
    float var = dv * 0.125f;
    float y = (h - mean) * (float)(1.0 / sqrt((double)var + 1e-5)) * g[oc] + beta[oc];
    h = LEAKY(y);
  }
  if (o < O) outp[(long)bb * O + o] = h;
}

// ---------------------------------------------------------------- driver ----
extern "C" void kernel_launch(void* const* d_in, const int* in_sizes, int n_in,
                              void* d_out, int out_size, void* d_ws, size_t ws_size,
                              hipStream_t stream) {
  const int B = 8, N = 4096;
  const float* x   = (const float*)d_in[0];
  const float* w1 = (const float*)d_in[2];  const float* g1 = (const float*)d_in[3];  const float* b1 = (const float*)d_in[4];
  const float* w2 = (const float*)d_in[5];  const float* g2 = (const float*)d_in[6];  const float* b2 = (const float*)d_in[7];
  const float* w3 = (const float*)d_in[8];  const float* g3 = (const float*)d_in[9];  const float* b3 = (const float*)d_in[10];
  const float* w4 = (const float*)d_in[11]; const float* g4 = (const float*)d_in[12]; const float* b4 = (const float*)d_in[13];
  const float* wf = (const float*)d_in[14]; const float* bfv = (const float*)d_in[15];
  const float* gf = (const float*)d_in[16]; const float* betaf = (const float*)d_in[17];
  const float* wc1 = (const float*)d_in[18]; const float* bc1 = (const float*)d_in[19];
  const float* gc1 = (const float*)d_in[20]; const float* betac1 = (const float*)d_in[21];
  const float* wc2 = (const float*)d_in[22]; const float* bc2 = (const float*)d_in[23];
  const float* gc2 = (const float*)d_in[24]; const float* betac2 = (const float*)d_in[25];
  const float* wc3 = (const float*)d_in[26]; const float* bc3 = (const float*)d_in[27];

  char* p = (char*)d_ws;
  auto alloc = [&](size_t bytes) -> char* {
    char* r = p;
    p += (bytes + 255) & ~(size_t)255;
    return r;
  };
  float* feat  = (float*)alloc((size_t)B * 512 * N * 4);   // 67.1MB
  int*   idx   = (int*)  alloc((size_t)B * N * 9 * 4);
  int*   cand  = (int*)  alloc((size_t)B * N * 64 * 4);    // 8.4MB (pool<=64)
  float* xxg   = (float*)alloc((size_t)B * N * 4);
  // R region (4 x 33.55MB = u|v|hmax|hmin). Overlays:
  //   kNN phase:   packR->u (KC<=25: 26.2MB), packC->hmax, xpm->hmin
  //   edge phase:  u|v|hmax|hmin proper
  //   fusion:      packB spans u+v+hmax exactly (100.66MB); partials in hmin
  float* u     = (float*)alloc((size_t)B * N * 256 * 4);
  float* v     = (float*)alloc((size_t)B * N * 256 * 4);
  float* hmax  = (float*)alloc((size_t)B * N * 256 * 4);
  float* hmin  = (float*)alloc((size_t)B * N * 256 * 4);
  ushort* packR = (ushort*)u;
  ushort* packC = (ushort*)hmax;
  float*  xpm   = hmin;
  ushort* packB = (ushort*)u;
  float*  ps1   = hmin;
  float*  ps2   = hmin + 1048576;
  float*  pmaxp = hmin + 2 * 1048576;
  float*  psump = hmin + 3 * 1048576;
  float* At    = (float*)alloc(128 * 256 * 4);
  float* W2t   = (float*)alloc(128 * 256 * 4);
  ushort* packW = (ushort*)alloc((size_t)32 * 96 * 512 * 2);  // 3.1MB
  double* S1   = (double*)alloc(1024 * 8);
  double* S2   = (double*)alloc(1024 * 8);
  float* scale = (float*)alloc(1024 * 4);
  float* shift = (float*)alloc(1024 * 4);
  float* x1x2  = (float*)alloc((size_t)B * 2048 * 4);
  float* h1    = (float*)alloc((size_t)B * 512 * 4);
  float* h2    = (float*)alloc((size_t)B * 256 * 4);

  dim3 gpack(N / 32, B);
  dim3 gknn4(N / 128, B, 4);   // z-split 4: pool 64 (L1-L3)
  dim3 gknn2(N / 128, B, 2);   // z-split 2: pool 32 (L4, reg-bound anyway)
  dim3 grr64(N / 4, B);
  dim3 grr32(N / 8, B);
  dim3 gxx(N / 256, B);

  pack3_wf<<<32, 256, 0, stream>>>(wf, packW);

  auto edge = [&](const float* inp, long in_bstride, int Cin, int O, const float* W,
                  const float* g, const float* beta, int c0) {
    prep_wt<<<(O * Cin + 255) / 256, 256, 0, stream>>>(W, Cin, O, At, W2t);
    dim3 gg(N / 64, O / 64, B);
    gemm_cn_no<<<gg, 256, 0, stream>>>(At, Cin, O, inp, in_bstride, N, u);
    gemm_cn_no<<<gg, 256, 0, stream>>>(W2t, Cin, O, inp, in_bstride, N, v);
    hipMemsetAsync(S1, 0, O * 8, stream);
    hipMemsetAsync(S2, 0, O * 8, stream);
    edge_pass<<<gg, 256, 0, stream>>>(u, v, idx, O, N, hmax, hmin, S1, S2);
    finalize_scale<<<(O + 255) / 256, 256, 0, stream>>>(S1, S2, g, beta,
                                                        1.0 / ((double)B * N * 9), O, scale, shift);
    edge_out<<<dim3(N / 64, B), 256, 0, stream>>>(hmax, hmin, scale, shift, O, N,
                                                  feat + (long)c0 * N, (long)512 * N);
  };

  // layer 1: C=3, K'=9+2=11 -> KC=1
  xx_kernel<3><<<gxx, 256, 0, stream>>>(x, (long)3 * N, N, xxg);
  pack3_kernel<3, 1><<<gpack, 256, 0, stream>>>(x, (long)3 * N, N, xxg, packR, packC, xpm);
  knn_v4<1, 4, 4><<<gknn4, 256, 0, stream>>>(packR, packC, xxg, N, cand);
  rerank_kernel<3, 64><<<grr64, 256, 0, stream>>>(xpm, N, xxg, cand, idx);
  edge(x, (long)3 * N, 3, 64, w1, g1, b1, 0);

  // layer 2: C=64, K'=192+2 -> KC=13
  xx_kernel<64><<<gxx, 256, 0, stream>>>(feat, (long)512 * N, N, xxg);
  pack3_kernel<64, 13><<<gpack, 256, 0, stream>>>(feat, (long)512 * N, N, xxg, packR, packC, xpm);
  knn_v4<13, 3, 4><<<gknn4, 256, 0, stream>>>(packR, packC, xxg, N, cand);
  rerank_kernel<64, 64><<<grr64, 256, 0, stream>>>(xpm, N, xxg, cand, idx);
  edge(feat, (long)512 * N, 64, 64, w2, g2, b2, 64);

  // layer 3: C=64
  xx_kernel<64><<<gxx, 256, 0, stream>>>(feat + (long)64 * N, (long)512 * N, N, xxg);
  pack3_kernel<64, 13><<<gpack, 256, 0, stream>>>(feat + (long)64 * N, (long)512 * N, N, xxg,
                                                  packR, packC, xpm);
  knn_v4<13, 3, 4><<<gknn4, 256, 0, stream>>>(packR, packC, xxg, N, cand);
  rerank_kernel<64, 64><<<grr64, 256, 0, stream>>>(xpm, N, xxg, cand, idx);
  edge(feat + (long)64 * N, (long)512 * N, 64, 128, w3, g3, b3, 128);

  // layer 4: C=128, K'=384+2 -> KC=25 (z=2: reg-bound at 2 waves/SIMD)
  xx_kernel<128><<<gxx, 256, 0, stream>>>(feat + (long)128 * N, (long)512 * N, N, xxg);
  pack3_kernel<128, 25><<<gpack, 256, 0, stream>>>(feat + (long)128 * N, (long)512 * N, N, xxg,
                                                   packR, packC, xpm);
  knn_v4<25, 3, 2><<<gknn2, 256, 0, stream>>>(packR, packC, xxg, N, cand);
  rerank_kernel<128, 32><<<grr32, 256, 0, stream>>>(xpm, N, xxg, cand, idx);
  edge(feat + (long)128 * N, (long)512 * N, 128, 256, w4, g4, b4, 256);

  // fusion conv 512->1024 via split-bf16 MFMA, two passes, h never stored
  pack3_feat<<<dim3(N / 32, B), 256, 0, stream>>>(feat, N, packB);
  dim3 gfu(N / 32, 2, B);
  fusion_mfma<0><<<gfu, 256, 0, stream>>>(packW, packB, bfv, nullptr, nullptr, N, ps1, ps2);
  finalize_fusion<<<4, 256, 0, stream>>>(ps1, ps2, gf, betaf, scale, shift);
  fusion_mfma<1><<<gfu, 256, 0, stream>>>(packW, packB, bfv, scale, shift, N, pmaxp, psump);
  pool_reduce2<<<32, 256, 0, stream>>>(pmaxp, psump, x1x2);

  fc_kernel<<<16, 256, 0, stream>>>(x1x2, 2048, 512, wc1, bc1, gc1, betac1, h1, 1);
  fc_kernel<<<8, 256, 0, stream>>>(h1, 512, 256, wc2, bc2, gc2, betac2, h2, 1);
  fc_kernel<<<2, 256, 0, stream>>>(h2, 256, 40, wc3, bc3, nullptr, nullptr, (float*)d_out, 0);
}

// Round 10
// 1914.770 us; speedup vs baseline: 3.3198x; 1.1720x over previous
//
#include <hip/hip_runtime.h>
#include <math.h>
#include <float.h>

// DGCNN forward, MI355X. f32 except: kNN distance GEMM + fusion conv (3-term
// split-bf16 MFMA; x = hi + mid, products hi.hi + mid.hi + hi.mid).
// kNN two-phase: MFMA approx -> per-partition top-10 pool -> exact f32 re-rank.
// kNN v5: candidate index packed into low mantissa bits of the distance ->
//         top-10 kept as sorted uints via umin/umax (2 ops/level, no index
//         regs). Perturbation (2^-12 rel) affects membership only; 10-deep
//         lists + exact rerank absorb it. xx_m folded into GEMM.
// Fusion: two MFMA passes (stats, then BN+leaky+pool in-register) - h never stored.

#define LEAKY(y) ((y) >= 0.f ? (y) : 0.2f * (y))

using f32x16 = __attribute__((ext_vector_type(16))) float;
using bf16x8 = __attribute__((ext_vector_type(8))) __bf16;
using short8v = __attribute__((ext_vector_type(8))) short;

__device__ inline ushort f2bf(float x) {
  unsigned u = __float_as_uint(x);
  unsigned r = (u + 0x7fff + ((u >> 16) & 1)) >> 16;
  return (ushort)r;
}

// ------------------------------------------------------------- xx = sum x^2 --
template<int C>
__global__ void xx_kernel(const float* __restrict__ xin, long bstride, int N,
                          float* __restrict__ xxg) {
  int n = blockIdx.x * 256 + threadIdx.x;
  int b = blockIdx.y;
  if (n < N) {
    const float* xb = xin + (long)b * bstride;
    float s = 0.f;
    #pragma unroll
    for (int c = 0; c < C; ++c) { float t = xb[(long)c * N + n]; s += t * t; }
    xxg[(long)b * N + n] = s;
  }
}

// ---------------------------------------- pack points into MFMA frag order ---
// R slices (query/B-op): [hi, hi, mid | -0.5, -0.5]
// C slices (cand /A-op): [hi, mid, hi | xx_hi, xx_mid]
// => acc = inner - 0.5*xx_m ; d = fmaf(-2, acc, xx_n).
// Also emits point-major f32 copy xpm[(b*N+n)*C + c] for the exact rerank.
template<int C, int KCc>
__global__ __launch_bounds__(256) void pack3_kernel(const float* __restrict__ xin, long bstride,
                                                    int N, const float* __restrict__ xxg,
                                                    ushort* __restrict__ packR,
                                                    ushort* __restrict__ packC,
                                                    float* __restrict__ xpm) {
  __shared__ float xt[C][32];
  const int tid = threadIdx.x;
  const int pb = blockIdx.x, b = blockIdx.y;
  for (int i = tid; i < C * 32; i += 256) {
    int c = i >> 5, j = i & 31;
    xt[c][j] = xin[(long)b * bstride + (long)c * N + pb * 32 + j];
  }
  __syncthreads();
  for (int i = tid; i < 32 * C; i += 256) {
    int pt = i / C, c = i % C;
    xpm[((long)b * N + pb * 32 + pt) * C + c] = xt[c][pt];
  }
  const int PB = N >> 5;
  for (int it = tid; it < KCc * 64; it += 256) {
    int kc = it >> 6, l = it & 63;
    int pt = l & 31;
    union { ushort u[8]; short8v v; } R, Cc;
    #pragma unroll
    for (int e = 0; e < 8; ++e) {
      int kp = kc * 16 + ((l >> 5) << 3) + e;
      ushort rv = 0, cv = 0;
      if (kp < 3 * C) {
        int s = kp / C, c = kp % C;
        float xv = xt[c][pt];
        ushort hi = f2bf(xv);
        float hif = __uint_as_float((unsigned)hi << 16);
        ushort mid = f2bf(xv - hif);
        rv = (s == 2) ? mid : hi;
        cv = (s == 1) ? mid : hi;
      } else if (kp == 3 * C) {
        float xxv = xxg[(long)b * N + pb * 32 + pt];
        cv = f2bf(xxv);
        rv = 0xBF00;                       // bf16(-0.5), exact
      } else if (kp == 3 * C + 1) {
        float xxv = xxg[(long)b * N + pb * 32 + pt];
        ushort hi = f2bf(xxv);
        float hif = __uint_as_float((unsigned)hi << 16);
        cv = f2bf(xxv - hif);
        rv = 0xBF00;
      }
      R.u[e] = rv; Cc.u[e] = cv;
    }
    long off = (((long)b * PB + pb) * KCc + kc) * 512 + l * 8;
    *reinterpret_cast<short8v*>(&packR[off]) = R.v;
    *reinterpret_cast<short8v*>(&packC[off]) = Cc.v;
  }
}

// ----------------------------------------------------- kNN phase 1 (MFMA) ---
// Packed-key top-10: key = (bits(d) & KEYMASK) | local_idx. Sorted ascending;
// insert via umin/umax ladder (2 ops/level). Keys unique (idx embedded;
// hf-halves own disjoint m_loc sets), ties order by index = ref tie-break.
#define KNN_SCAN(SELF)                                            \
  _Pragma("unroll")                                               \
  for (int reg = 0; reg < 16; ++reg) {                            \
    int m_loc = (reg & 3) + 8 * (reg >> 2) + 4 * hf;              \
    float d = fmaf(-2.0f, acc[reg], xr);                          \
    d = fmaxf(d, 0.f);                                            \
    unsigned key = (__float_as_uint(d) & KEYMASK) |               \
                   (unsigned)((t << 5) | m_loc);                  \
    if (SELF && ((mb << 5) | m_loc) == n_glob) key = 0xFFFFFFFFu; \
    if (key < tk[9]) {                                            \
      unsigned kc = key;                                          \
      _Pragma("unroll")                                           \
      for (int s_ = 0; s_ < 10; ++s_) {                           \
        unsigned mn_ = min(kc, tk[s_]);                           \
        kc = max(kc, tk[s_]);                                     \
        tk[s_] = mn_;                                             \
      }                                                           \
    }                                                             \
  }

// grid (N/128, B, Z): 4 waves x 128 query rows; z = m-partition. B-frags in
// regs; A-tile (32 cands) dbuf in LDS via global_load_lds (shared by 4 waves);
// merge pool aliases A-tile. Emits per row: merged top-10 into cand[.. z*10].
template<int KCc, int MINW, int Z>
__global__ __launch_bounds__(256, MINW) void knn_v5(const ushort* __restrict__ packR,
                                                    const ushort* __restrict__ packC,
                                                    const float* __restrict__ xxg,
                                                    int N, int* __restrict__ cand) {
  constexpr int SA_ELEMS = KCc * 512;
  constexpr int SA_BYTES = SA_ELEMS * 2;
  constexpr int POOL = (2 * SA_BYTES > 10240) ? 2 * SA_BYTES : 10240;
  __shared__ __align__(16) char smem[POOL];
  ushort* const sA0 = (ushort*)smem;
  ushort* const sA1 = (ushort*)(smem + SA_BYTES);

  const int tid = threadIdx.x;
  const int b = blockIdx.y, rowblk = blockIdx.x, z = blockIdx.z;
  const int w = tid >> 6, l = tid & 63;
  const int lane31 = l & 31, hf = l >> 5;
  const int PB = N >> 5;
  const int HALF = PB / Z;
  const unsigned IDXMASK = (unsigned)(HALF * 32 - 1);   // 10-11 bits
  const unsigned KEYMASK = ~IDXMASK;
  const int myblk = rowblk * 4 + w;        // m-block containing this wave's rows

  const ushort* rp = packR + (((long)b * PB + myblk) * (long)KCc) * 512 + l * 8;
  bf16x8 bfr[KCc];
  #pragma unroll
  for (int kc = 0; kc < KCc; ++kc)
    bfr[kc] = *reinterpret_cast<const bf16x8*>(rp + kc * 512);

  const ushort* srcb = packC + ((long)b * PB) * (long)SA_ELEMS;
  const int mb0 = z * HALF;

  {
    const ushort* src = srcb + (long)mb0 * SA_ELEMS;
    for (int i = tid * 8; i < SA_ELEMS; i += 2048)
      __builtin_amdgcn_global_load_lds(
          (const __attribute__((address_space(1))) void*)(src + i),
          (__attribute__((address_space(3))) void*)(sA0 + i), 16, 0, 0);
  }

  const int n_glob = rowblk * 128 + w * 32 + lane31;
  const float xr = xxg[(long)b * N + n_glob];

  unsigned tk[10];
  #pragma unroll
  for (int s = 0; s < 10; ++s) tk[s] = 0xFFFFFFFFu;

  __syncthreads();

  for (int t = 0; t < HALF; ++t) {
    const int mb = mb0 + t;
    const ushort* curA = (t & 1) ? sA1 : sA0;
    ushort* nxtA = (t & 1) ? sA0 : sA1;
    if (t + 1 < HALF) {
      const ushort* src = srcb + (long)(mb + 1) * SA_ELEMS;
      for (int i = tid * 8; i < SA_ELEMS; i += 2048)
        __builtin_amdgcn_global_load_lds(
            (const __attribute__((address_space(1))) void*)(src + i),
            (__attribute__((address_space(3))) void*)(nxtA + i), 16, 0, 0);
    }
    f32x16 acc = {};
    #pragma unroll
    for (int kc = 0; kc < KCc; ++kc) {
      bf16x8 af = *reinterpret_cast<const bf16x8*>(curA + kc * 512 + l * 8);
      acc = __builtin_amdgcn_mfma_f32_32x32x16_bf16(af, bfr[kc], acc, 0, 0, 0);
    }
    if (mb == myblk) {
      KNN_SCAN(true)
    } else {
      KNN_SCAN(false)
    }
    __syncthreads();                          // next tile staged; curA free
  }

  // merge: per row 2 sorted-10 key lists (hf 0/1) -> top-10 -> global indices.
  unsigned* mK = (unsigned*)smem;             // [128][20]
  const int row = w * 32 + lane31;
  #pragma unroll
  for (int s = 0; s < 10; ++s)
    mK[row * 20 + hf * 10 + s] = tk[s];
  __syncthreads();
  if (tid < 128) {
    int p0 = 0, p1 = 0;
    const long ob = ((long)b * N + rowblk * 128 + tid) * (Z * 10) + z * 10;
    const int base_m = z * HALF * 32;
    for (int s = 0; s < 10; ++s) {
      unsigned k0 = mK[tid * 20 + p0];
      unsigned k1 = mK[tid * 20 + 10 + p1];
      bool t0 = k0 < k1;
      unsigned kk = t0 ? k0 : k1;
      cand[ob + s] = base_m + (int)(kk & IDXMASK);
      if (t0) ++p0; else ++p1;
    }
  }
}

// ---------------- exact f32 re-rank of P candidates (point-major input) -----
// block = 320 threads = ROWS x P, ROWS = 320/P (P in {40,20}).
template<int C, int P>
__global__ __launch_bounds__(320) void rerank_kernel(const float* __restrict__ xpm,
                                                     int N, const float* __restrict__ xxg,
                                                     const int* __restrict__ cand,
                                                     int* __restrict__ idx_out) {
  constexpr int ROWS = 320 / P;
  __shared__ float sq[ROWS][C];
  __shared__ float sd[ROWS][P + 1];
  __shared__ int   si[ROWS][P + 1];
  const int tid = threadIdx.x;
  const int b = blockIdx.y, n0 = blockIdx.x * ROWS;
  const float* xb = xpm + (long)b * N * C;
  for (int i = tid; i < ROWS * C; i += 320) {
    int r = i / C, c = i % C;
    sq[r][c] = xb[(long)(n0 + r) * C + c];
  }
  __syncthreads();
  const int r = tid / P, j = tid % P;
  const int n = n0 + r;
  const int m = cand[((long)b * N + n) * P + j];
  const float* cv = xb + (long)m * C;
  float dot = 0.f;
  if constexpr ((C & 3) == 0) {
    for (int c = 0; c < C; c += 4) {
      float4 v4 = *reinterpret_cast<const float4*>(cv + c);
      dot = fmaf(sq[r][c + 0], v4.x, dot);
      dot = fmaf(sq[r][c + 1], v4.y, dot);
      dot = fmaf(sq[r][c + 2], v4.z, dot);
      dot = fmaf(sq[r][c + 3], v4.w, dot);
    }
  } else {
    for (int c = 0; c < C; ++c) dot = fmaf(sq[r][c], cv[c], dot);
  }
  float d = (xxg[(long)b * N + n] - 2.0f * dot) + xxg[(long)b * N + m];
  if (m == n) d = 3.0e38f;
  sd[r][j] = d; si[r][j] = m;
  __syncthreads();
  int rank = 0;
  #pragma unroll
  for (int t = 0; t < P; ++t) {
    float dd = sd[r][t]; int ii = si[r][t];
    if (dd < d || (dd == d && ii < m)) rank++;
  }
  if (rank < 9) idx_out[((long)b * N + n) * 9 + rank] = m;
}

// ------------------------------------------- W transposes (coalesced GEMMs) --
__global__ void prep_wt(const float* __restrict__ W, int Cin, int O,
                        float* __restrict__ At, float* __restrict__ W2t) {
  int i = blockIdx.x * 256 + threadIdx.x;
  if (i < O * Cin) {
    int o = i % O, c = i / O;
    float w1v = W[(long)o * 2 * Cin + c];
    float w2v = W[(long)o * 2 * Cin + Cin + c];
    At[(long)c * O + o]  = w1v - w2v;
    W2t[(long)c * O + o] = w2v;
  }
}

// ------------------------------ GEMM: out[b][n][o] = sum_c Wt[c][o] in[b][c][n]
__global__ __launch_bounds__(256) void gemm_cn_no(const float* __restrict__ Wt,
                                                  int C, int O,
                                                  const float* __restrict__ in,
                                                  long in_bstride, int N,
                                                  float* __restrict__ out) {
  const int tid = threadIdx.x;
  const int n0 = blockIdx.x * 64, o0 = blockIdx.y * 64, b = blockIdx.z;
  __shared__ float wT[128][64];
  __shared__ float inT[128][64];
  for (int i = tid; i < C * 64; i += 256) {
    int c = i >> 6, j = i & 63;
    wT[c][j]  = Wt[(long)c * O + o0 + j];
    inT[c][j] = in[(long)b * in_bstride + (long)c * N + n0 + j];
  }
  __syncthreads();
  const int tr = tid >> 4, tc = tid & 15;
  float acc[4][4];
  #pragma unroll
  for (int i = 0; i < 4; ++i)
    #pragma unroll
    for (int j = 0; j < 4; ++j) acc[i][j] = 0.f;
  for (int c = 0; c < C; ++c) {
    float4 a4 = *reinterpret_cast<const float4*>(&wT[c][4 * tr]);
    float4 b4 = *reinterpret_cast<const float4*>(&inT[c][4 * tc]);
    float av[4] = {a4.x, a4.y, a4.z, a4.w};
    float bv[4] = {b4.x, b4.y, b4.z, b4.w};
    #pragma unroll
    for (int i = 0; i < 4; ++i)
      #pragma unroll
      for (int j = 0; j < 4; ++j) acc[i][j] = fmaf(av[i], bv[j], acc[i][j]);
  }
  #pragma unroll
  for (int j = 0; j < 4; ++j) {
    float4 st = make_float4(acc[0][j], acc[1][j], acc[2][j], acc[3][j]);
    *reinterpret_cast<float4*>(&out[((long)b * N + n0 + 4 * tc + j) * O + o0 + 4 * tr]) = st;
  }
}

// ------------------- single gather pass: stats + hmax + hmin per (n,o) ------
__global__ __launch_bounds__(256) void edge_pass(const float* __restrict__ u,
                                                 const float* __restrict__ v,
                                                 const int* __restrict__ idx,
                                                 int O, int N,
                                                 float* __restrict__ hmax,
                                                 float* __restrict__ hmin,
                                                 double* __restrict__ S1,
                                                 double* __restrict__ S2) {
  const int tid = threadIdx.x;
  const int n0 = blockIdx.x * 64, o0 = blockIdx.y * 64, b = blockIdx.z;
  __shared__ int sidx[64][9];
  __shared__ float4 redA[4][16];
  __shared__ float4 redB[4][16];
  for (int i = tid; i < 576; i += 256)
    ((int*)sidx)[i] = idx[((long)b * N + n0) * 9 + i];
  __syncthreads();
  const int nl = tid >> 4, oq = tid & 15;
  const long base = (long)b * N;
  const int ocol = o0 + 4 * oq;
  float4 s1 = make_float4(0.f, 0.f, 0.f, 0.f);
  float4 s2 = make_float4(0.f, 0.f, 0.f, 0.f);
  for (int g = 0; g < 4; ++g) {
    const int n = g * 16 + nl;
    const float4 u4 = *reinterpret_cast<const float4*>(&u[(base + n0 + n) * O + ocol]);
    float4 mx = make_float4(-3.0e38f, -3.0e38f, -3.0e38f, -3.0e38f);
    float4 mn = make_float4(3.0e38f, 3.0e38f, 3.0e38f, 3.0e38f);
    #pragma unroll
    for (int k = 0; k < 9; ++k) {
      int m = sidx[n][k];
      const float4 v4 = *reinterpret_cast<const float4*>(&v[(base + m) * O + ocol]);
      float hx = u4.x + v4.x, hy = u4.y + v4.y, hz = u4.z + v4.z, hw = u4.w + v4.w;
      s1.x += hx; s1.y += hy; s1.z += hz; s1.w += hw;
      s2.x = fmaf(hx, hx, s2.x); s2.y = fmaf(hy, hy, s2.y);
      s2.z = fmaf(hz, hz, s2.z); s2.w = fmaf(hw, hw, s2.w);
      mx.x = fmaxf(mx.x, hx); mx.y = fmaxf(mx.y, hy); mx.z = fmaxf(mx.z, hz); mx.w = fmaxf(mx.w, hw);
      mn.x = fminf(mn.x, hx); mn.y = fminf(mn.y, hy); mn.z = fminf(mn.z, hz); mn.w = fminf(mn.w, hw);
    }
    *reinterpret_cast<float4*>(&hmax[(base + n0 + n) * O + ocol]) = mx;
    *reinterpret_cast<float4*>(&hmin[(base + n0 + n) * O + ocol]) = mn;
  }
  s1.x += __shfl_xor(s1.x, 16); s1.y += __shfl_xor(s1.y, 16);
  s1.z += __shfl_xor(s1.z, 16); s1.w += __shfl_xor(s1.w, 16);
  s2.x += __shfl_xor(s2.x, 16); s2.y += __shfl_xor(s2.y, 16);
  s2.z += __shfl_xor(s2.z, 16); s2.w += __shfl_xor(s2.w, 16);
  s1.x += __shfl_xor(s1.x, 32); s1.y += __shfl_xor(s1.y, 32);
  s1.z += __shfl_xor(s1.z, 32); s1.w += __shfl_xor(s1.w, 32);
  s2.x += __shfl_xor(s2.x, 32); s2.y += __shfl_xor(s2.y, 32);
  s2.z += __shfl_xor(s2.z, 32); s2.w += __shfl_xor(s2.w, 32);
  if ((tid & 48) == 0) { redA[tid >> 6][oq] = s1; redB[tid >> 6][oq] = s2; }
  __syncthreads();
  if (tid < 16) {
    float4 a = redA[0][tid], bb = redB[0][tid];
    #pragma unroll
    for (int ww = 1; ww < 4; ++ww) {
      float4 t1 = redA[ww][tid], t2 = redB[ww][tid];
      a.x += t1.x; a.y += t1.y; a.z += t1.z; a.w += t1.w;
      bb.x += t2.x; bb.y += t2.y; bb.z += t2.z; bb.w += t2.w;
    }
    int o = o0 + 4 * tid;
    atomicAdd(&S1[o + 0], (double)a.x);  atomicAdd(&S1[o + 1], (double)a.y);
    atomicAdd(&S1[o + 2], (double)a.z);  atomicAdd(&S1[o + 3], (double)a.w);
    atomicAdd(&S2[o + 0], (double)bb.x); atomicAdd(&S2[o + 1], (double)bb.y);
    atomicAdd(&S2[o + 2], (double)bb.z); atomicAdd(&S2[o + 3], (double)bb.w);
  }
}

__global__ void finalize_scale(const double* __restrict__ S1, const double* __restrict__ S2,
                               const float* __restrict__ g, const float* __restrict__ beta,
                               double invM, int O, float* __restrict__ scale,
                               float* __restrict__ shift) {
  int o = blockIdx.x * 256 + threadIdx.x;
  if (o < O) {
    double mean = S1[o] * invM;
    double var = S2[o] * invM - mean * mean;
    double sc = (double)g[o] / sqrt(var + 1e-5);
    scale[o] = (float)sc;
    shift[o] = (float)((double)beta[o] - mean * sc);
  }
}

// ------------------- elementwise finalize + transpose to (B,O,N) ------------
__global__ __launch_bounds__(256) void edge_out(const float* __restrict__ hmax,
                                                const float* __restrict__ hmin,
                                                const float* __restrict__ scale,
                                                const float* __restrict__ shift,
                                                int O, int N,
                                                float* __restrict__ outp, long out_bstride) {
  const int tid = threadIdx.x;
  const int b = blockIdx.y, n0 = blockIdx.x * 64;
  __shared__ float yt[64][65];
  const int ol = tid & 63, nl = tid >> 6;
  const long base = (long)b * N;
  for (int oc = 0; oc < O; oc += 64) {
    float sc = scale[oc + ol], sh = shift[oc + ol];
    __syncthreads();
    for (int ng = 0; ng < 16; ++ng) {
      int n = ng * 4 + nl;
      long off = (base + n0 + n) * O + oc + ol;
      float hv = (sc >= 0.f) ? hmax[off] : hmin[off];
      float y = sc * hv + sh;
      yt[ol][n] = LEAKY(y);
    }
    __syncthreads();
    for (int rr = 0; rr < 16; ++rr) {
      int r = rr * 4 + nl;
      outp[(long)b * out_bstride + (long)(oc + r) * N + n0 + ol] = yt[r][ol];
    }
  }
}

// ----------------- fusion packs: weights (A-pattern), feat (B-pattern) ------
__global__ __launch_bounds__(256) void pack3_wf(const float* __restrict__ wf,
                                                ushort* __restrict__ packW) {
  __shared__ float wt[32][129];
  const int po = blockIdx.x;
  const int tid = threadIdx.x;
  for (int c0 = 0; c0 < 512; c0 += 128) {
    __syncthreads();
    for (int i = tid; i < 32 * 128; i += 256) {
      int o = i >> 7, c = i & 127;
      wt[o][c] = wf[(long)(po * 32 + o) * 512 + c0 + c];
    }
    __syncthreads();
    #pragma unroll
    for (int s = 0; s < 3; ++s) {
      int kc0 = (s * 512 + c0) >> 4;
      for (int it = tid; it < 8 * 64; it += 256) {
        int kcl = it >> 6, l = it & 63;
        union { ushort u[8]; short8v v; } P;
        #pragma unroll
        for (int e = 0; e < 8; ++e) {
          int kp = (kc0 + kcl) * 16 + ((l >> 5) << 3) + e;
          int c = kp - s * 512 - c0;
          float xv = wt[l & 31][c];
          ushort hi = f2bf(xv);
          if (s == 1) {
            float hif = __uint_as_float((unsigned)hi << 16);
            P.u[e] = f2bf(xv - hif);
          } else P.u[e] = hi;
        }
        *reinterpret_cast<short8v*>(&packW[((long)po * 96 + kc0 + kcl) * 512 + l * 8]) = P.v;
      }
    }
  }
}

__global__ __launch_bounds__(256) void pack3_feat(const float* __restrict__ feat, int N,
                                                  ushort* __restrict__ packB) {
  __shared__ float xt[64][33];
  const int pb = blockIdx.x, b = blockIdx.y;
  const int tid = threadIdx.x;
  const int PB = N >> 5;
  for (int c0 = 0; c0 < 512; c0 += 64) {
    __syncthreads();
    for (int i = tid; i < 64 * 32; i += 256) {
      int c = i >> 5, j = i & 31;
      xt[c][j] = feat[((long)b * 512 + c0 + c) * N + pb * 32 + j];
    }
    __syncthreads();
    #pragma unroll
    for (int s = 0; s < 3; ++s) {
      int kc0 = (s * 512 + c0) >> 4;
      for (int it = tid; it < 4 * 64; it += 256) {
        int kcl = it >> 6, l = it & 63;
        union { ushort u[8]; short8v v; } P;
        #pragma unroll
        for (int e = 0; e < 8; ++e) {
          int kp = (kc0 + kcl) * 16 + ((l >> 5) << 3) + e;
          int c = kp - s * 512 - c0;
          float xv = xt[c][l & 31];
          ushort hi = f2bf(xv);
          if (s == 2) {
            float hif = __uint_as_float((unsigned)hi << 16);
            P.u[e] = f2bf(xv - hif);
          } else P.u[e] = hi;
        }
        *reinterpret_cast<short8v*>(
            &packB[(((long)b * PB + pb) * 96 + kc0 + kcl) * 512 + l * 8]) = P.v;
      }
    }
  }
}

// ---------------- fusion MFMA: PHASE 0 = stats partials, 1 = pool partials --
#define FUS_EPI(ACC, Q)                                                          \
  _Pragma("unroll")                                                              \
  for (int reg = 0; reg < 16; ++reg) {                                           \
    int o = ((z * 16 + (Q) * 4 + w) << 5) + (reg & 3) + 8 * (reg >> 2) + 4 * hf; \
    float h = ACC[reg] + bfb[o];                                                 \
    if (PHASE == 0) {                                                            \
      float s1 = h, s2 = h * h;                                                  \
      _Pragma("unroll")                                                          \
      for (int off = 1; off < 32; off <<= 1) {                                   \
        s1 += __shfl_xor(s1, off);                                               \
        s2 += __shfl_xor(s2, off);                                               \
      }                                                                          \
      if (lane31 == 0) {                                                         \
        p1[(long)o * 1024 + b * 128 + nt] = s1;                                  \
        p2[(long)o * 1024 + b * 128 + nt] = s2;                                  \
      }                                                                          \
    } else {                                                                     \
      float y = scale[o] * h + shift[o];                                         \
      y = LEAKY(y);                                                              \
      float mx = y, sm = y;                                                      \
      _Pragma("unroll")                                                          \
      for (int off = 1; off < 32; off <<= 1) {                                   \
        mx = fmaxf(mx, __shfl_xor(mx, off));                                     \
        sm += __shfl_xor(sm, off);                                               \
      }                                                                          \
      if (lane31 == 0) {                                                         \
        p1[((long)b * 1024 + o) * 128 + nt] = mx;                                \
        p2[((long)b * 1024 + o) * 128 + nt] = sm;                                \
      }                                                                          \
    }                                                                            \
  }

template<int PHASE>
__global__ __launch_bounds__(256) void fusion_mfma(const ushort* __restrict__ packW,
                                                   const ushort* __restrict__ packB,
                                                   const float* __restrict__ bfb,
                                                   const float* __restrict__ scale,
                                                   const float* __restrict__ shift,
                                                   int N,
                                                   float* __restrict__ p1,
                                                   float* __restrict__ p2) {
  __shared__ ushort sB[2][12 * 512];
  const int tid = threadIdx.x;
  const int nt = blockIdx.x, z = blockIdx.y, b = blockIdx.z;
  const int w = tid >> 6, l = tid & 63;
  const int lane31 = l & 31, hf = l >> 5;
  const int PB = N >> 5;
  const ushort* srcB = packB + (((long)b * PB + nt) * 96) * 512;

  for (int i = tid * 8; i < 12 * 512; i += 2048)
    __builtin_amdgcn_global_load_lds(
        (const __attribute__((address_space(1))) void*)(srcB + i),
        (__attribute__((address_space(3))) void*)(&sB[0][i]), 16, 0, 0);
  __syncthreads();

  f32x16 acc0 = {}, acc1 = {}, acc2 = {}, acc3 = {};
  const ushort* aw0 = packW + ((long)(z * 16 + 0 + w) * 96) * 512 + l * 8;
  const ushort* aw1 = packW + ((long)(z * 16 + 4 + w) * 96) * 512 + l * 8;
  const ushort* aw2 = packW + ((long)(z * 16 + 8 + w) * 96) * 512 + l * 8;
  const ushort* aw3 = packW + ((long)(z * 16 + 12 + w) * 96) * 512 + l * 8;

  int cur = 0;
  for (int ch = 0; ch < 8; ++ch) {
    if (ch + 1 < 8) {
      const ushort* src = srcB + (ch + 1) * 12 * 512;
      for (int i = tid * 8; i < 12 * 512; i += 2048)
        __builtin_amdgcn_global_load_lds(
            (const __attribute__((address_space(1))) void*)(src + i),
            (__attribute__((address_space(3))) void*)(&sB[cur ^ 1][i]), 16, 0, 0);
    }
    #pragma unroll
    for (int kcl = 0; kcl < 12; ++kcl) {
      const int kc = ch * 12 + kcl;
      bf16x8 bf = *reinterpret_cast<const bf16x8*>(&sB[cur][kcl * 512 + l * 8]);
      bf16x8 a0 = *reinterpret_cast<const bf16x8*>(aw0 + (long)kc * 512);
      acc0 = __builtin_amdgcn_mfma_f32_32x32x16_bf16(a0, bf, acc0, 0, 0, 0);
      bf16x8 a1 = *reinterpret_cast<const bf16x8*>(aw1 + (long)kc * 512);
      acc1 = __builtin_amdgcn_mfma_f32_32x32x16_bf16(a1, bf, acc1, 0, 0, 0);
      bf16x8 a2 = *reinterpret_cast<const bf16x8*>(aw2 + (long)kc * 512);
      acc2 = __builtin_amdgcn_mfma_f32_32x32x16_bf16(a2, bf, acc2, 0, 0, 0);
      bf16x8 a3 = *reinterpret_cast<const bf16x8*>(aw3 + (long)kc * 512);
      acc3 = __builtin_amdgcn_mfma_f32_32x32x16_bf16(a3, bf, acc3, 0, 0, 0);
    }
    __syncthreads();
    cur ^= 1;
  }

  FUS_EPI(acc0, 0)
  FUS_EPI(acc1, 1)
  FUS_EPI(acc2, 2)
  FUS_EPI(acc3, 3)
}

__global__ void finalize_fusion(const float* __restrict__ ps1, const float* __restrict__ ps2,
                                const float* __restrict__ g, const float* __restrict__ beta,
                                float* __restrict__ scale, float* __restrict__ shift) {
  int o = blockIdx.x * 256 + threadIdx.x;
  if (o < 1024) {
    double s1 = 0.0, s2 = 0.0;
    for (int k = 0; k < 1024; ++k) {
      s1 += (double)ps1[(long)o * 1024 + k];
      s2 += (double)ps2[(long)o * 1024 + k];
    }
    double invM = 1.0 / 32768.0;
    double mean = s1 * invM;
    double var = s2 * invM - mean * mean;
    double sc = (double)g[o] / sqrt(var + 1e-5);
    scale[o] = (float)sc;
    shift[o] = (float)((double)beta[o] - mean * sc);
  }
}

__global__ void pool_reduce2(const float* __restrict__ pmax, const float* __restrict__ psum,
                             float* __restrict__ x1x2) {
  int id = blockIdx.x * 256 + threadIdx.x;
  if (id < 8 * 1024) {
    int b = id >> 10, o = id & 1023;
    float mx = -3.0e38f, sm = 0.f;
    for (int t = 0; t < 128; ++t) {
      mx = fmaxf(mx, pmax[(long)id * 128 + t]);
      sm += psum[(long)id * 128 + t];
    }
    x1x2[(long)b * 2048 + o] = mx;
    x1x2[(long)b * 2048 + 1024 + o] = sm * (1.f / 4096.f);
  }
}

// ----------------------------------------------------------- classifier -----
__global__ __launch_bounds__(256) void fc_kernel(const float* __restrict__ in, int Cin, int O,
                                                 const float* __restrict__ W,
                                                 const float* __restrict__ bias,
                                                 const float* __restrict__ g,
                                                 const float* __restrict__ beta,
                                                 float* __restrict__ outp, int do_bn) {
  const int tid = threadIdx.x;
  const int o = blockIdx.x * 32 + (tid >> 3);
  const int bb = tid & 7;
  const int oc = (o < O) ? o : (O - 1);
  const float* ir = in + (long)bb * Cin;
  const float* wr = W + (long)oc * Cin;
  float dot = 0.f;
  for (int c = 0; c < Cin; c += 4) {
    float4 a = *reinterpret_cast<const float4*>(&ir[c]);
    float4 w = *reinterpret_cast<const float4*>(&wr[c]);
    dot += a.x * w.x + a.y * w.y + a.z * w.z + a.w * w.w;
  }
  float h = dot + bias[oc];
  if (do_bn) {
    float s = h;
    s += __shfl_xor(s, 1, 8); s += __shfl_xor(s, 2, 8); s += __shfl_xor(s, 4, 8);
    float mean = s * 0.125f;
    float dv = (h - mean) * (h - mean);
    dv += __shfl_xor(dv, 1, 8); dv += __shfl_xor(dv, 2, 8); dv += __shfl_xor(dv, 4, 8);
    float var = dv * 0.125f;
    float y = (h - mean) * (float)(1.0 / sqrt((double)var + 1e-5)) * g[oc] + beta[oc];
    h = LEAKY(y);
  }
  if (o < O) outp[(long)bb * O + o] = h;
}

// ---------------------------------------------------------------- driver ----
extern "C" void kernel_launch(void* const* d_in, const int* in_sizes, int n_in,
                              void* d_out, int out_size, void* d_ws, size_t ws_size,
                              hipStream_t stream) {
  const int B = 8, N = 4096;
  const float* x   = (const float*)d_in[0];
  const float* w1 = (const float*)d_in[2];  const float* g1 = (const float*)d_in[3];  const float* b1 = (const float*)d_in[4];
  const float* w2 = (const float*)d_in[5];  const float* g2 = (const float*)d_in[6];  const float* b2 = (const float*)d_in[7];
  const float* w3 = (const float*)d_in[8];  const float* g3 = (const float*)d_in[9];  const float* b3 = (const float*)d_in[10];
  const float* w4 = (const float*)d_in[11]; const float* g4 = (const float*)d_in[12]; const float* b4 = (const float*)d_in[13];
  const float* wf = (const float*)d_in[14]; const float* bfv = (const float*)d_in[15];
  const float* gf = (const float*)d_in[16]; const float* betaf = (const float*)d_in[17];
  const float* wc1 = (const float*)d_in[18]; const float* bc1 = (const float*)d_in[19];
  const float* gc1 = (const float*)d_in[20]; const float* betac1 = (const float*)d_in[21];
  const float* wc2 = (const float*)d_in[22]; const float* bc2 = (const float*)d_in[23];
  const float* gc2 = (const float*)d_in[24]; const float* betac2 = (const float*)d_in[25];
  const float* wc3 = (const float*)d_in[26]; const float* bc3 = (const float*)d_in[27];

  char* p = (char*)d_ws;
  auto alloc = [&](size_t bytes) -> char* {
    char* r = p;
    p += (bytes + 255) & ~(size_t)255;
    return r;
  };
  float* feat  = (float*)alloc((size_t)B * 512 * N * 4);   // 67.1MB
  int*   idx   = (int*)  alloc((size_t)B * N * 9 * 4);
  int*   cand  = (int*)  alloc((size_t)B * N * 64 * 4);    // pool<=40
  float* xxg   = (float*)alloc((size_t)B * N * 4);
  // R region (4 x 33.55MB = u|v|hmax|hmin). Overlays:
  //   kNN phase:   packR->u (KC<=25: 26.2MB), packC->hmax, xpm->hmin
  //   edge phase:  u|v|hmax|hmin proper
  //   fusion:      packB spans u+v+hmax exactly (100.66MB); partials in hmin
  float* u     = (float*)alloc((size_t)B * N * 256 * 4);
  float* v     = (float*)alloc((size_t)B * N * 256 * 4);
  float* hmax  = (float*)alloc((size_t)B * N * 256 * 4);
  float* hmin  = (float*)alloc((size_t)B * N * 256 * 4);
  ushort* packR = (ushort*)u;
  ushort* packC = (ushort*)hmax;
  float*  xpm   = hmin;
  ushort* packB = (ushort*)u;
  float*  ps1   = hmin;
  float*  ps2   = hmin + 1048576;
  float*  pmaxp = hmin + 2 * 1048576;
  float*  psump = hmin + 3 * 1048576;
  float* At    = (float*)alloc(128 * 256 * 4);
  float* W2t   = (float*)alloc(128 * 256 * 4);
  ushort* packW = (ushort*)alloc((size_t)32 * 96 * 512 * 2);  // 3.1MB
  double* S1   = (double*)alloc(1024 * 8);
  double* S2   = (double*)alloc(1024 * 8);
  float* scale = (float*)alloc(1024 * 4);
  float* shift = (float*)alloc(1024 * 4);
  float* x1x2  = (float*)alloc((size_t)B * 2048 * 4);
  float* h1    = (float*)alloc((size_t)B * 512 * 4);
  float* h2    = (float*)alloc((size_t)B * 256 * 4);

  dim3 gpack(N / 32, B);
  dim3 gknn4(N / 128, B, 4);   // z-split 4: pool 40 (L1-L3), 10-bit idx
  dim3 gknn2(N / 128, B, 2);   // z-split 2: pool 20 (L4), 11-bit idx
  dim3 grr40(N / 8, B);        // rerank P=40: 8 rows x 40 = 320 threads
  dim3 grr20(N / 16, B);       // rerank P=20: 16 rows x 20 = 320 threads
  dim3 gxx(N / 256, B);

  pack3_wf<<<32, 256, 0, stream>>>(wf, packW);

  auto edge = [&](const float* inp, long in_bstride, int Cin, int O, const float* W,
                  const float* g, const float* beta, int c0) {
    prep_wt<<<(O * Cin + 255) / 256, 256, 0, stream>>>(W, Cin, O, At, W2t);
    dim3 gg(N / 64, O / 64, B);
    gemm_cn_no<<<gg, 256, 0, stream>>>(At, Cin, O, inp, in_bstride, N, u);
    gemm_cn_no<<<gg, 256, 0, stream>>>(W2t, Cin, O, inp, in_bstride, N, v);
    hipMemsetAsync(S1, 0, O * 8, stream);
    hipMemsetAsync(S2, 0, O * 8, stream);
    edge_pass<<<gg, 256, 0, stream>>>(u, v, idx, O, N, hmax, hmin, S1, S2);
    finalize_scale<<<(O + 255) / 256, 256, 0, stream>>>(S1, S2, g, beta,
                                                        1.0 / ((double)B * N * 9), O, scale, shift);
    edge_out<<<dim3(N / 64, B), 256, 0, stream>>>(hmax, hmin, scale, shift, O, N,
                                                  feat + (long)c0 * N, (long)512 * N);
  };

  // layer 1: C=3, K'=9+2=11 -> KC=1
  xx_kernel<3><<<gxx, 256, 0, stream>>>(x, (long)3 * N, N, xxg);
  pack3_kernel<3, 1><<<gpack, 256, 0, stream>>>(x, (long)3 * N, N, xxg, packR, packC, xpm);
  knn_v5<1, 4, 4><<<gknn4, 256, 0, stream>>>(packR, packC, xxg, N, cand);
  rerank_kernel<3, 40><<<grr40, 320, 0, stream>>>(xpm, N, xxg, cand, idx);
  edge(x, (long)3 * N, 3, 64, w1, g1, b1, 0);

  // layer 2: C=64, K'=192+2 -> KC=13
  xx_kernel<64><<<gxx, 256, 0, stream>>>(feat, (long)512 * N, N, xxg);
  pack3_kernel<64, 13><<<gpack, 256, 0, stream>>>(feat, (long)512 * N, N, xxg, packR, packC, xpm);
  knn_v5<13, 3, 4><<<gknn4, 256, 0, stream>>>(packR, packC, xxg, N, cand);
  rerank_kernel<64, 40><<<grr40, 320, 0, stream>>>(xpm, N, xxg, cand, idx);
  edge(feat, (long)512 * N, 64, 64, w2, g2, b2, 64);

  // layer 3: C=64
  xx_kernel<64><<<gxx, 256, 0, stream>>>(feat + (long)64 * N, (long)512 * N, N, xxg);
  pack3_kernel<64, 13><<<gpack, 256, 0, stream>>>(feat + (long)64 * N, (long)512 * N, N, xxg,
                                                  packR, packC, xpm);
  knn_v5<13, 3, 4><<<gknn4, 256, 0, stream>>>(packR, packC, xxg, N, cand);
  rerank_kernel<64, 40><<<grr40, 320, 0, stream>>>(xpm, N, xxg, cand, idx);
  edge(feat + (long)64 * N, (long)512 * N, 64, 128, w3, g3, b3, 128);

  // layer 4: C=128, K'=384+2 -> KC=25 (z=2: reg-bound at 2 waves/SIMD)
  xx_kernel<128><<<gxx, 256, 0, stream>>>(feat + (long)128 * N, (long)512 * N, N, xxg);
  pack3_kernel<128, 25><<<gpack, 256, 0, stream>>>(feat + (long)128 * N, (long)512 * N, N, xxg,
                                                   packR, packC, xpm);
  knn_v5<25, 3, 2><<<gknn2, 256, 0, stream>>>(packR, packC, xxg, N, cand);
  rerank_kernel<128, 20><<<grr20, 320, 0, stream>>>(xpm, N, xxg, cand, idx);
  edge(feat + (long)128 * N, (long)512 * N, 128, 256, w4, g4, b4, 256);

  // fusion conv 512->1024 via split-bf16 MFMA, two passes, h never stored
  pack3_feat<<<dim3(N / 32, B), 256, 0, stream>>>(feat, N, packB);
  dim3 gfu(N / 32, 2, B);
  fusion_mfma<0><<<gfu, 256, 0, stream>>>(packW, packB, bfv, nullptr, nullptr, N, ps1, ps2);
  finalize_fusion<<<4, 256, 0, stream>>>(ps1, ps2, gf, betaf, scale, shift);
  fusion_mfma<1><<<gfu, 256, 0, stream>>>(packW, packB, bfv, scale, shift, N, pmaxp, psump);
  pool_reduce2<<<32, 256, 0, stream>>>(pmaxp, psump, x1x2);

  fc_kernel<<<16, 256, 0, stream>>>(x1x2, 2048, 512, wc1, bc1, gc1, betac1, h1, 1);
  fc_kernel<<<8, 256, 0, stream>>>(h1, 512, 256, wc2, bc2, gc2, betac2, h2, 1);
  fc_kernel<<<2, 256, 0, stream>>>(h2, 256, 40, wc3, bc3, nullptr, nullptr, (float*)d_out, 0);
}

// Round 11
// 1663.146 us; speedup vs baseline: 3.8220x; 1.1513x over previous
//
#include <hip/hip_runtime.h>
#include <math.h>
#include <float.h>

// DGCNN forward, MI355X. f32 except: kNN distance GEMM + fusion conv (3-term
// split-bf16 MFMA; x = hi + mid, products hi.hi + mid.hi + hi.mid).
// kNN two-phase: MFMA approx -> per-partition top-10 pool -> exact f32 re-rank.
// kNN v5: candidate index packed into low mantissa bits of the distance ->
//         top-10 kept as sorted uints via umin/umax. xx_m folded into GEMM.
// Fusion v2: SINGLE MFMA pass (f32 stats + bf16 h stored over dead feat buf),
//            then memory-bound BN+leaky+max/mean pool sweep. No 2nd GEMM.

#define LEAKY(y) ((y) >= 0.f ? (y) : 0.2f * (y))

using f32x16 = __attribute__((ext_vector_type(16))) float;
using bf16x8 = __attribute__((ext_vector_type(8))) __bf16;
using short8v = __attribute__((ext_vector_type(8))) short;

__device__ inline ushort f2bf(float x) {
  unsigned u = __float_as_uint(x);
  unsigned r = (u + 0x7fff + ((u >> 16) & 1)) >> 16;
  return (ushort)r;
}

// ------------------------------------------------------------- xx = sum x^2 --
template<int C>
__global__ void xx_kernel(const float* __restrict__ xin, long bstride, int N,
                          float* __restrict__ xxg) {
  int n = blockIdx.x * 256 + threadIdx.x;
  int b = blockIdx.y;
  if (n < N) {
    const float* xb = xin + (long)b * bstride;
    float s = 0.f;
    #pragma unroll
    for (int c = 0; c < C; ++c) { float t = xb[(long)c * N + n]; s += t * t; }
    xxg[(long)b * N + n] = s;
  }
}

// ---------------------------------------- pack points into MFMA frag order ---
template<int C, int KCc>
__global__ __launch_bounds__(256) void pack3_kernel(const float* __restrict__ xin, long bstride,
                                                    int N, const float* __restrict__ xxg,
                                                    ushort* __restrict__ packR,
                                                    ushort* __restrict__ packC,
                                                    float* __restrict__ xpm) {
  __shared__ float xt[C][32];
  const int tid = threadIdx.x;
  const int pb = blockIdx.x, b = blockIdx.y;
  for (int i = tid; i < C * 32; i += 256) {
    int c = i >> 5, j = i & 31;
    xt[c][j] = xin[(long)b * bstride + (long)c * N + pb * 32 + j];
  }
  __syncthreads();
  for (int i = tid; i < 32 * C; i += 256) {
    int pt = i / C, c = i % C;
    xpm[((long)b * N + pb * 32 + pt) * C + c] = xt[c][pt];
  }
  const int PB = N >> 5;
  for (int it = tid; it < KCc * 64; it += 256) {
    int kc = it >> 6, l = it & 63;
    int pt = l & 31;
    union { ushort u[8]; short8v v; } R, Cc;
    #pragma unroll
    for (int e = 0; e < 8; ++e) {
      int kp = kc * 16 + ((l >> 5) << 3) + e;
      ushort rv = 0, cv = 0;
      if (kp < 3 * C) {
        int s = kp / C, c = kp % C;
        float xv = xt[c][pt];
        ushort hi = f2bf(xv);
        float hif = __uint_as_float((unsigned)hi << 16);
        ushort mid = f2bf(xv - hif);
        rv = (s == 2) ? mid : hi;
        cv = (s == 1) ? mid : hi;
      } else if (kp == 3 * C) {
        float xxv = xxg[(long)b * N + pb * 32 + pt];
        cv = f2bf(xxv);
        rv = 0xBF00;                       // bf16(-0.5), exact
      } else if (kp == 3 * C + 1) {
        float xxv = xxg[(long)b * N + pb * 32 + pt];
        ushort hi = f2bf(xxv);
        float hif = __uint_as_float((unsigned)hi << 16);
        cv = f2bf(xxv - hif);
        rv = 0xBF00;
      }
      R.u[e] = rv; Cc.u[e] = cv;
    }
    long off = (((long)b * PB + pb) * KCc + kc) * 512 + l * 8;
    *reinterpret_cast<short8v*>(&packR[off]) = R.v;
    *reinterpret_cast<short8v*>(&packC[off]) = Cc.v;
  }
}

// ----------------------------------------------------- kNN phase 1 (MFMA) ---
#define KNN_SCAN(SELF)                                            \
  _Pragma("unroll")                                               \
  for (int reg = 0; reg < 16; ++reg) {                            \
    int m_loc = (reg & 3) + 8 * (reg >> 2) + 4 * hf;              \
    float d = fmaf(-2.0f, acc[reg], xr);                          \
    d = fmaxf(d, 0.f);                                            \
    unsigned key = (__float_as_uint(d) & KEYMASK) |               \
                   (unsigned)((t << 5) | m_loc);                  \
    if (SELF && ((mb << 5) | m_loc) == n_glob) key = 0xFFFFFFFFu; \
    if (key < tk[9]) {                                            \
      unsigned kc = key;                                          \
      _Pragma("unroll")                                           \
      for (int s_ = 0; s_ < 10; ++s_) {                           \
        unsigned mn_ = min(kc, tk[s_]);                           \
        kc = max(kc, tk[s_]);                                     \
        tk[s_] = mn_;                                             \
      }                                                           \
    }                                                             \
  }

template<int KCc, int MINW, int Z>
__global__ __launch_bounds__(256, MINW) void knn_v5(const ushort* __restrict__ packR,
                                                    const ushort* __restrict__ packC,
                                                    const float* __restrict__ xxg,
                                                    int N, int* __restrict__ cand) {
  constexpr int SA_ELEMS = KCc * 512;
  constexpr int SA_BYTES = SA_ELEMS * 2;
  constexpr int POOL = (2 * SA_BYTES > 10240) ? 2 * SA_BYTES : 10240;
  __shared__ __align__(16) char smem[POOL];
  ushort* const sA0 = (ushort*)smem;
  ushort* const sA1 = (ushort*)(smem + SA_BYTES);

  const int tid = threadIdx.x;
  const int b = blockIdx.y, rowblk = blockIdx.x, z = blockIdx.z;
  const int w = tid >> 6, l = tid & 63;
  const int lane31 = l & 31, hf = l >> 5;
  const int PB = N >> 5;
  const int HALF = PB / Z;
  const unsigned IDXMASK = (unsigned)(HALF * 32 - 1);
  const unsigned KEYMASK = ~IDXMASK;
  const int myblk = rowblk * 4 + w;

  const ushort* rp = packR + (((long)b * PB + myblk) * (long)KCc) * 512 + l * 8;
  bf16x8 bfr[KCc];
  #pragma unroll
  for (int kc = 0; kc < KCc; ++kc)
    bfr[kc] = *reinterpret_cast<const bf16x8*>(rp + kc * 512);

  const ushort* srcb = packC + ((long)b * PB) * (long)SA_ELEMS;
  const int mb0 = z * HALF;

  {
    const ushort* src = srcb + (long)mb0 * SA_ELEMS;
    for (int i = tid * 8; i < SA_ELEMS; i += 2048)
      __builtin_amdgcn_global_load_lds(
          (const __attribute__((address_space(1))) void*)(src + i),
          (__attribute__((address_space(3))) void*)(sA0 + i), 16, 0, 0);
  }

  const int n_glob = rowblk * 128 + w * 32 + lane31;
  const float xr = xxg[(long)b * N + n_glob];

  unsigned tk[10];
  #pragma unroll
  for (int s = 0; s < 10; ++s) tk[s] = 0xFFFFFFFFu;

  __syncthreads();

  for (int t = 0; t < HALF; ++t) {
    const int mb = mb0 + t;
    const ushort* curA = (t & 1) ? sA1 : sA0;
    ushort* nxtA = (t & 1) ? sA0 : sA1;
    if (t + 1 < HALF) {
      const ushort* src = srcb + (long)(mb + 1) * SA_ELEMS;
      for (int i = tid * 8; i < SA_ELEMS; i += 2048)
        __builtin_amdgcn_global_load_lds(
            (const __attribute__((address_space(1))) void*)(src + i),
            (__attribute__((address_space(3))) void*)(nxtA + i), 16, 0, 0);
    }
    f32x16 acc = {};
    #pragma unroll
    for (int kc = 0; kc < KCc; ++kc) {
      bf16x8 af = *reinterpret_cast<const bf16x8*>(curA + kc * 512 + l * 8);
      acc = __builtin_amdgcn_mfma_f32_32x32x16_bf16(af, bfr[kc], acc, 0, 0, 0);
    }
    if (mb == myblk) {
      KNN_SCAN(true)
    } else {
      KNN_SCAN(false)
    }
    __syncthreads();
  }

  unsigned* mK = (unsigned*)smem;             // [128][20]
  const int row = w * 32 + lane31;
  #pragma unroll
  for (int s = 0; s < 10; ++s)
    mK[row * 20 + hf * 10 + s] = tk[s];
  __syncthreads();
  if (tid < 128) {
    int p0 = 0, p1 = 0;
    const long ob = ((long)b * N + rowblk * 128 + tid) * (Z * 10) + z * 10;
    const int base_m = z * HALF * 32;
    for (int s = 0; s < 10; ++s) {
      unsigned k0 = mK[tid * 20 + p0];
      unsigned k1 = mK[tid * 20 + 10 + p1];
      bool t0 = k0 < k1;
      unsigned kk = t0 ? k0 : k1;
      cand[ob + s] = base_m + (int)(kk & IDXMASK);
      if (t0) ++p0; else ++p1;
    }
  }
}

// ---------------- exact f32 re-rank of P candidates (point-major input) -----
template<int C, int P>
__global__ __launch_bounds__(320) void rerank_kernel(const float* __restrict__ xpm,
                                                     int N, const float* __restrict__ xxg,
                                                     const int* __restrict__ cand,
                                                     int* __restrict__ idx_out) {
  constexpr int ROWS = 320 / P;
  __shared__ float sq[ROWS][C];
  __shared__ float sd[ROWS][P + 1];
  __shared__ int   si[ROWS][P + 1];
  const int tid = threadIdx.x;
  const int b = blockIdx.y, n0 = blockIdx.x * ROWS;
  const float* xb = xpm + (long)b * N * C;
  for (int i = tid; i < ROWS * C; i += 320) {
    int r = i / C, c = i % C;
    sq[r][c] = xb[(long)(n0 + r) * C + c];
  }
  __syncthreads();
  const int r = tid / P, j = tid % P;
  const int n = n0 + r;
  const int m = cand[((long)b * N + n) * P + j];
  const float* cv = xb + (long)m * C;
  float dot = 0.f;
  if constexpr ((C & 3) == 0) {
    for (int c = 0; c < C; c += 4) {
      float4 v4 = *reinterpret_cast<const float4*>(cv + c);
      dot = fmaf(sq[r][c + 0], v4.x, dot);
      dot = fmaf(sq[r][c + 1], v4.y, dot);
      dot = fmaf(sq[r][c + 2], v4.z, dot);
      dot = fmaf(sq[r][c + 3], v4.w, dot);
    }
  } else {
    for (int c = 0; c < C; ++c) dot = fmaf(sq[r][c], cv[c], dot);
  }
  float d = (xxg[(long)b * N + n] - 2.0f * dot) + xxg[(long)b * N + m];
  if (m == n) d = 3.0e38f;
  sd[r][j] = d; si[r][j] = m;
  __syncthreads();
  int rank = 0;
  #pragma unroll
  for (int t = 0; t < P; ++t) {
    float dd = sd[r][t]; int ii = si[r][t];
    if (dd < d || (dd == d && ii < m)) rank++;
  }
  if (rank < 9) idx_out[((long)b * N + n) * 9 + rank] = m;
}

// ------------------------------------------- W transposes (coalesced GEMMs) --
__global__ void prep_wt(const float* __restrict__ W, int Cin, int O,
                        float* __restrict__ At, float* __restrict__ W2t) {
  int i = blockIdx.x * 256 + threadIdx.x;
  if (i < O * Cin) {
    int o = i % O, c = i / O;
    float w1v = W[(long)o * 2 * Cin + c];
    float w2v = W[(long)o * 2 * Cin + Cin + c];
    At[(long)c * O + o]  = w1v - w2v;
    W2t[(long)c * O + o] = w2v;
  }
}

// ------------------------------ GEMM: out[b][n][o] = sum_c Wt[c][o] in[b][c][n]
__global__ __launch_bounds__(256) void gemm_cn_no(const float* __restrict__ Wt,
                                                  int C, int O,
                                                  const float* __restrict__ in,
                                                  long in_bstride, int N,
                                                  float* __restrict__ out) {
  const int tid = threadIdx.x;
  const int n0 = blockIdx.x * 64, o0 = blockIdx.y * 64, b = blockIdx.z;
  __shared__ float wT[128][64];
  __shared__ float inT[128][64];
  for (int i = tid; i < C * 64; i += 256) {
    int c = i >> 6, j = i & 63;
    wT[c][j]  = Wt[(long)c * O + o0 + j];
    inT[c][j] = in[(long)b * in_bstride + (long)c * N + n0 + j];
  }
  __syncthreads();
  const int tr = tid >> 4, tc = tid & 15;
  float acc[4][4];
  #pragma unroll
  for (int i = 0; i < 4; ++i)
    #pragma unroll
    for (int j = 0; j < 4; ++j) acc[i][j] = 0.f;
  for (int c = 0; c < C; ++c) {
    float4 a4 = *reinterpret_cast<const float4*>(&wT[c][4 * tr]);
    float4 b4 = *reinterpret_cast<const float4*>(&inT[c][4 * tc]);
    float av[4] = {a4.x, a4.y, a4.z, a4.w};
    float bv[4] = {b4.x, b4.y, b4.z, b4.w};
    #pragma unroll
    for (int i = 0; i < 4; ++i)
      #pragma unroll
      for (int j = 0; j < 4; ++j) acc[i][j] = fmaf(av[i], bv[j], acc[i][j]);
  }
  #pragma unroll
  for (int j = 0; j < 4; ++j) {
    float4 st = make_float4(acc[0][j], acc[1][j], acc[2][j], acc[3][j]);
    *reinterpret_cast<float4*>(&out[((long)b * N + n0 + 4 * tc + j) * O + o0 + 4 * tr]) = st;
  }
}

// ------------------- single gather pass: stats + hmax + hmin per (n,o) ------
__global__ __launch_bounds__(256) void edge_pass(const float* __restrict__ u,
                                                 const float* __restrict__ v,
                                                 const int* __restrict__ idx,
                                                 int O, int N,
                                                 float* __restrict__ hmax,
                                                 float* __restrict__ hmin,
                                                 double* __restrict__ S1,
                                                 double* __restrict__ S2) {
  const int tid = threadIdx.x;
  const int n0 = blockIdx.x * 64, o0 = blockIdx.y * 64, b = blockIdx.z;
  __shared__ int sidx[64][9];
  __shared__ float4 redA[4][16];
  __shared__ float4 redB[4][16];
  for (int i = tid; i < 576; i += 256)
    ((int*)sidx)[i] = idx[((long)b * N + n0) * 9 + i];
  __syncthreads();
  const int nl = tid >> 4, oq = tid & 15;
  const long base = (long)b * N;
  const int ocol = o0 + 4 * oq;
  float4 s1 = make_float4(0.f, 0.f, 0.f, 0.f);
  float4 s2 = make_float4(0.f, 0.f, 0.f, 0.f);
  for (int g = 0; g < 4; ++g) {
    const int n = g * 16 + nl;
    const float4 u4 = *reinterpret_cast<const float4*>(&u[(base + n0 + n) * O + ocol]);
    float4 mx = make_float4(-3.0e38f, -3.0e38f, -3.0e38f, -3.0e38f);
    float4 mn = make_float4(3.0e38f, 3.0e38f, 3.0e38f, 3.0e38f);
    #pragma unroll
    for (int k = 0; k < 9; ++k) {
      int m = sidx[n][k];
      const float4 v4 = *reinterpret_cast<const float4*>(&v[(base + m) * O + ocol]);
      float hx = u4.x + v4.x, hy = u4.y + v4.y, hz = u4.z + v4.z, hw = u4.w + v4.w;
      s1.x += hx; s1.y += hy; s1.z += hz; s1.w += hw;
      s2.x = fmaf(hx, hx, s2.x); s2.y = fmaf(hy, hy, s2.y);
      s2.z = fmaf(hz, hz, s2.z); s2.w = fmaf(hw, hw, s2.w);
      mx.x = fmaxf(mx.x, hx); mx.y = fmaxf(mx.y, hy); mx.z = fmaxf(mx.z, hz); mx.w = fmaxf(mx.w, hw);
      mn.x = fminf(mn.x, hx); mn.y = fminf(mn.y, hy); mn.z = fminf(mn.z, hz); mn.w = fminf(mn.w, hw);
    }
    *reinterpret_cast<float4*>(&hmax[(base + n0 + n) * O + ocol]) = mx;
    *reinterpret_cast<float4*>(&hmin[(base + n0 + n) * O + ocol]) = mn;
  }
  s1.x += __shfl_xor(s1.x, 16); s1.y += __shfl_xor(s1.y, 16);
  s1.z += __shfl_xor(s1.z, 16); s1.w += __shfl_xor(s1.w, 16);
  s2.x += __shfl_xor(s2.x, 16); s2.y += __shfl_xor(s2.y, 16);
  s2.z += __shfl_xor(s2.z, 16); s2.w += __shfl_xor(s2.w, 16);
  s1.x += __shfl_xor(s1.x, 32); s1.y += __shfl_xor(s1.y, 32);
  s1.z += __shfl_xor(s1.z, 32); s1.w += __shfl_xor(s1.w, 32);
  s2.x += __shfl_xor(s2.x, 32); s2.y += __shfl_xor(s2.y, 32);
  s2.z += __shfl_xor(s2.z, 32); s2.w += __shfl_xor(s2.w, 32);
  if ((tid & 48) == 0) { redA[tid >> 6][oq] = s1; redB[tid >> 6][oq] = s2; }
  __syncthreads();
  if (tid < 16) {
    float4 a = redA[0][tid], bb = redB[0][tid];
    #pragma unroll
    for (int ww = 1; ww < 4; ++ww) {
      float4 t1 = redA[ww][tid], t2 = redB[ww][tid];
      a.x += t1.x; a.y += t1.y; a.z += t1.z; a.w += t1.w;
      bb.x += t2.x; bb.y += t2.y; bb.z += t2.z; bb.w += t2.w;
    }
    int o = o0 + 4 * tid;
    atomicAdd(&S1[o + 0], (double)a.x);  atomicAdd(&S1[o + 1], (double)a.y);
    atomicAdd(&S1[o + 2], (double)a.z);  atomicAdd(&S1[o + 3], (double)a.w);
    atomicAdd(&S2[o + 0], (double)bb.x); atomicAdd(&S2[o + 1], (double)bb.y);
    atomicAdd(&S2[o + 2], (double)bb.z); atomicAdd(&S2[o + 3], (double)bb.w);
  }
}

__global__ void finalize_scale(const double* __restrict__ S1, const double* __restrict__ S2,
                               const float* __restrict__ g, const float* __restrict__ beta,
                               double invM, int O, float* __restrict__ scale,
                               float* __restrict__ shift) {
  int o = blockIdx.x * 256 + threadIdx.x;
  if (o < O) {
    double mean = S1[o] * invM;
    double var = S2[o] * invM - mean * mean;
    double sc = (double)g[o] / sqrt(var + 1e-5);
    scale[o] = (float)sc;
    shift[o] = (float)((double)beta[o] - mean * sc);
  }
}

// ------------------- elementwise finalize + transpose to (B,O,N) ------------
__global__ __launch_bounds__(256) void edge_out(const float* __restrict__ hmax,
                                                const float* __restrict__ hmin,
                                                const float* __restrict__ scale,
                                                const float* __restrict__ shift,
                                                int O, int N,
                                                float* __restrict__ outp, long out_bstride) {
  const int tid = threadIdx.x;
  const int b = blockIdx.y, n0 = blockIdx.x * 64;
  __shared__ float yt[64][65];
  const int ol = tid & 63, nl = tid >> 6;
  const long base = (long)b * N;
  for (int oc = 0; oc < O; oc += 64) {
    float sc = scale[oc + ol], sh = shift[oc + ol];
    __syncthreads();
    for (int ng = 0; ng < 16; ++ng) {
      int n = ng * 4 + nl;
      long off = (base + n0 + n) * O + oc + ol;
      float hv = (sc >= 0.f) ? hmax[off] : hmin[off];
      float y = sc * hv + sh;
      yt[ol][n] = LEAKY(y);
    }
    __syncthreads();
    for (int rr = 0; rr < 16; ++rr) {
      int r = rr * 4 + nl;
      outp[(long)b * out_bstride + (long)(oc + r) * N + n0 + ol] = yt[r][ol];
    }
  }
}

// ----------------- fusion packs: weights (A-pattern), feat (B-pattern) ------
__global__ __launch_bounds__(256) void pack3_wf(const float* __restrict__ wf,
                                                ushort* __restrict__ packW) {
  __shared__ float wt[32][129];
  const int po = blockIdx.x;
  const int tid = threadIdx.x;
  for (int c0 = 0; c0 < 512; c0 += 128) {
    __syncthreads();
    for (int i = tid; i < 32 * 128; i += 256) {
      int o = i >> 7, c = i & 127;
      wt[o][c] = wf[(long)(po * 32 + o) * 512 + c0 + c];
    }
    __syncthreads();
    #pragma unroll
    for (int s = 0; s < 3; ++s) {
      int kc0 = (s * 512 + c0) >> 4;
      for (int it = tid; it < 8 * 64; it += 256) {
        int kcl = it >> 6, l = it & 63;
        union { ushort u[8]; short8v v; } P;
        #pragma unroll
        for (int e = 0; e < 8; ++e) {
          int kp = (kc0 + kcl) * 16 + ((l >> 5) << 3) + e;
          int c = kp - s * 512 - c0;
          float xv = wt[l & 31][c];
          ushort hi = f2bf(xv);
          if (s == 1) {
            float hif = __uint_as_float((unsigned)hi << 16);
            P.u[e] = f2bf(xv - hif);
          } else P.u[e] = hi;
        }
        *reinterpret_cast<short8v*>(&packW[((long)po * 96 + kc0 + kcl) * 512 + l * 8]) = P.v;
      }
    }
  }
}

__global__ __launch_bounds__(256) void pack3_feat(const float* __restrict__ feat, int N,
                                                  ushort* __restrict__ packB) {
  __shared__ float xt[64][33];
  const int pb = blockIdx.x, b = blockIdx.y;
  const int tid = threadIdx.x;
  const int PB = N >> 5;
  for (int c0 = 0; c0 < 512; c0 += 64) {
    __syncthreads();
    for (int i = tid; i < 64 * 32; i += 256) {
      int c = i >> 5, j = i & 31;
      xt[c][j] = feat[((long)b * 512 + c0 + c) * N + pb * 32 + j];
    }
    __syncthreads();
    #pragma unroll
    for (int s = 0; s < 3; ++s) {
      int kc0 = (s * 512 + c0) >> 4;
      for (int it = tid; it < 4 * 64; it += 256) {
        int kcl = it >> 6, l = it & 63;
        union { ushort u[8]; short8v v; } P;
        #pragma unroll
        for (int e = 0; e < 8; ++e) {
          int kp = (kc0 + kcl) * 16 + ((l >> 5) << 3) + e;
          int c = kp - s * 512 - c0;
          float xv = xt[c][l & 31];
          ushort hi = f2bf(xv);
          if (s == 2) {
            float hif = __uint_as_float((unsigned)hi << 16);
            P.u[e] = f2bf(xv - hif);
          } else P.u[e] = hi;
        }
        *reinterpret_cast<short8v*>(
            &packB[(((long)b * PB + pb) * 96 + kc0 + kcl) * 512 + l * 8]) = P.v;
      }
    }
  }
}

// --------- fusion MFMA single pass: f32 stats partials + bf16 h store -------
#define FUS_EPI(ACC, Q)                                                          \
  _Pragma("unroll")                                                              \
  for (int reg = 0; reg < 16; ++reg) {                                           \
    int o = ((z * 16 + (Q) * 4 + w) << 5) + (reg & 3) + 8 * (reg >> 2) + 4 * hf; \
    float h = ACC[reg] + bfb[o];                                                 \
    hbf[((long)b * 1024 + o) * 4096 + (nt << 5) + lane31] = f2bf(h);             \
    float s1 = h, s2 = h * h;                                                    \
    _Pragma("unroll")                                                            \
    for (int off = 1; off < 32; off <<= 1) {                                     \
      s1 += __shfl_xor(s1, off);                                                 \
      s2 += __shfl_xor(s2, off);                                                 \
    }                                                                            \
    if (lane31 == 0) {                                                           \
      p1[(long)o * 1024 + b * 128 + nt] = s1;                                    \
      p2[(long)o * 1024 + b * 128 + nt] = s2;                                    \
    }                                                                            \
  }

__global__ __launch_bounds__(256) void fusion_gemm_store(const ushort* __restrict__ packW,
                                                         const ushort* __restrict__ packB,
                                                         const float* __restrict__ bfb,
                                                         int N,
                                                         ushort* __restrict__ hbf,
                                                         float* __restrict__ p1,
                                                         float* __restrict__ p2) {
  __shared__ ushort sB[2][12 * 512];
  const int tid = threadIdx.x;
  const int nt = blockIdx.x, z = blockIdx.y, b = blockIdx.z;
  const int w = tid >> 6, l = tid & 63;
  const int lane31 = l & 31, hf = l >> 5;
  const int PB = N >> 5;
  const ushort* srcB = packB + (((long)b * PB + nt) * 96) * 512;

  for (int i = tid * 8; i < 12 * 512; i += 2048)
    __builtin_amdgcn_global_load_lds(
        (const __attribute__((address_space(1))) void*)(srcB + i),
        (__attribute__((address_space(3))) void*)(&sB[0][i]), 16, 0, 0);
  __syncthreads();

  f32x16 acc0 = {}, acc1 = {}, acc2 = {}, acc3 = {};
  const ushort* aw0 = packW + ((long)(z * 16 + 0 + w) * 96) * 512 + l * 8;
  const ushort* aw1 = packW + ((long)(z * 16 + 4 + w) * 96) * 512 + l * 8;
  const ushort* aw2 = packW + ((long)(z * 16 + 8 + w) * 96) * 512 + l * 8;
  const ushort* aw3 = packW + ((long)(z * 16 + 12 + w) * 96) * 512 + l * 8;

  int cur = 0;
  for (int ch = 0; ch < 8; ++ch) {
    if (ch + 1 < 8) {
      const ushort* src = srcB + (ch + 1) * 12 * 512;
      for (int i = tid * 8; i < 12 * 512; i += 2048)
        __builtin_amdgcn_global_load_lds(
            (const __attribute__((address_space(1))) void*)(src + i),
            (__attribute__((address_space(3))) void*)(&sB[cur ^ 1][i]), 16, 0, 0);
    }
    #pragma unroll
    for (int kcl = 0; kcl < 12; ++kcl) {
      const int kc = ch * 12 + kcl;
      bf16x8 bf = *reinterpret_cast<const bf16x8*>(&sB[cur][kcl * 512 + l * 8]);
      bf16x8 a0 = *reinterpret_cast<const bf16x8*>(aw0 + (long)kc * 512);
      acc0 = __builtin_amdgcn_mfma_f32_32x32x16_bf16(a0, bf, acc0, 0, 0, 0);
      bf16x8 a1 = *reinterpret_cast<const bf16x8*>(aw1 + (long)kc * 512);
      acc1 = __builtin_amdgcn_mfma_f32_32x32x16_bf16(a1, bf, acc1, 0, 0, 0);
      bf16x8 a2 = *reinterpret_cast<const bf16x8*>(aw2 + (long)kc * 512);
      acc2 = __builtin_amdgcn_mfma_f32_32x32x16_bf16(a2, bf, acc2, 0, 0, 0);
      bf16x8 a3 = *reinterpret_cast<const bf16x8*>(aw3 + (long)kc * 512);
      acc3 = __builtin_amdgcn_mfma_f32_32x32x16_bf16(a3, bf, acc3, 0, 0, 0);
    }
    __syncthreads();
    cur ^= 1;
  }

  FUS_EPI(acc0, 0)
  FUS_EPI(acc1, 1)
  FUS_EPI(acc2, 2)
  FUS_EPI(acc3, 3)
}

__global__ void finalize_fusion(const float* __restrict__ ps1, const float* __restrict__ ps2,
                                const float* __restrict__ g, const float* __restrict__ beta,
                                float* __restrict__ scale, float* __restrict__ shift) {
  int o = blockIdx.x * 256 + threadIdx.x;
  if (o < 1024) {
    double s1 = 0.0, s2 = 0.0;
    for (int k = 0; k < 1024; ++k) {
      s1 += (double)ps1[(long)o * 1024 + k];
      s2 += (double)ps2[(long)o * 1024 + k];
    }
    double invM = 1.0 / 32768.0;
    double mean = s1 * invM;
    double var = s2 * invM - mean * mean;
    double sc = (double)g[o] / sqrt(var + 1e-5);
    scale[o] = (float)sc;
    shift[o] = (float)((double)beta[o] - mean * sc);
  }
}

// --------------- BN+leaky+max/mean pool over bf16 h, one wave per (b,o) -----
__global__ __launch_bounds__(256) void pool_bf16(const ushort* __restrict__ hbf,
                                                 const float* __restrict__ scale,
                                                 const float* __restrict__ shift,
                                                 float* __restrict__ x1x2) {
  int gw = (blockIdx.x * 256 + threadIdx.x) >> 6;
  int lane = threadIdx.x & 63;
  int b = gw >> 10, o = gw & 1023;
  const ushort* row = hbf + ((long)b * 1024 + o) * 4096;
  float sc = scale[o], sh = shift[o];
  float mx = -3.0e38f, sm = 0.f;
  for (int j = 0; j < 8; ++j) {
    union { ushort u[8]; short8v v; } hv;
    hv.v = *reinterpret_cast<const short8v*>(row + ((j << 6) + lane) * 8);
    #pragma unroll
    for (int e = 0; e < 8; ++e) {
      float h = __uint_as_float((unsigned)hv.u[e] << 16);
      float y = fmaf(sc, h, sh);
      y = LEAKY(y);
      mx = fmaxf(mx, y);
      sm += y;
    }
  }
  #pragma unroll
  for (int off = 1; off < 64; off <<= 1) {
    mx = fmaxf(mx, __shfl_xor(mx, off));
    sm += __shfl_xor(sm, off);
  }
  if (lane == 0) {
    x1x2[(long)b * 2048 + o] = mx;
    x1x2[(long)b * 2048 + 1024 + o] = sm * (1.f / 4096.f);
  }
}

// ----------------------------------------------------------- classifier -----
__global__ __launch_bounds__(256) void fc_kernel(const float* __restrict__ in, int Cin, int O,
                                                 const float* __restrict__ W,
                                                 const float* __restrict__ bias,
                                                 const float* __restrict__ g,
                                                 const float* __restrict__ beta,
                                                 float* __restrict__ outp, int do_bn) {
  const int tid = threadIdx.x;
  const int o = blockIdx.x * 32 + (tid >> 3);
  const int bb = tid & 7;
  const int oc = (o < O) ? o : (O - 1);
  const float* ir = in + (long)bb * Cin;
  const float* wr = W + (long)oc * Cin;
  float dot = 0.f;
  for (int c = 0; c < Cin; c += 4) {
    float4 a = *reinterpret_cast<const float4*>(&ir[c]);
    float4 w = *reinterpret_cast<const float4*>(&wr[c]);
    dot += a.x * w.x + a.y * w.y + a.z * w.z + a.w * w.w;
  }
  float h = dot + bias[oc];
  if (do_bn) {
    float s = h;
    s += __shfl_xor(s, 1, 8); s += __shfl_xor(s, 2, 8); s += __shfl_xor(s, 4, 8);
    float mean = s * 0.125f;
    float dv = (h - mean) * (h - mean);
    dv += __shfl_xor(dv, 1, 8); dv += __shfl_xor(dv, 2, 8); dv += __shfl_xor(dv, 4, 8);
    float var = dv * 0.125f;
    float y = (h - mean) * (float)(1.0 / sqrt((double)var + 1e-5)) * g[oc] + beta[oc];
    h = LEAKY(y);
  }
  if (o < O) outp[(long)bb * O + o] = h;
}

// ---------------------------------------------------------------- driver ----
extern "C" void kernel_launch(void* const* d_in, const int* in_sizes, int n_in,
                              void* d_out, int out_size, void* d_ws, size_t ws_size,
                              hipStream_t stream) {
  const int B = 8, N = 4096;
  const float* x   = (const float*)d_in[0];
  const float* w1 = (const float*)d_in[2];  const float* g1 = (const float*)d_in[3];  const float* b1 = (const float*)d_in[4];
  const float* w2 = (const float*)d_in[5];  const float* g2 = (const float*)d_in[6];  const float* b2 = (const float*)d_in[7];
  const float* w3 = (const float*)d_in[8];  const float* g3 = (const float*)d_in[9];  const float* b3 = (const float*)d_in[10];
  const float* w4 = (const float*)d_in[11]; const float* g4 = (const float*)d_in[12]; const float* b4 = (const float*)d_in[13];
  const float* wf = (const float*)d_in[14]; const float* bfv = (const float*)d_in[15];
  const float* gf = (const float*)d_in[16]; const float* betaf = (const float*)d_in[17];
  const float* wc1 = (const float*)d_in[18]; const float* bc1 = (const float*)d_in[19];
  const float* gc1 = (const float*)d_in[20]; const float* betac1 = (const float*)d_in[21];
  const float* wc2 = (const float*)d_in[22]; const float* bc2 = (const float*)d_in[23];
  const float* gc2 = (const float*)d_in[24]; const float* betac2 = (const float*)d_in[25];
  const float* wc3 = (const float*)d_in[26]; const float* bc3 = (const float*)d_in[27];

  char* p = (char*)d_ws;
  auto alloc = [&](size_t bytes) -> char* {
    char* r = p;
    p += (bytes + 255) & ~(size_t)255;
    return r;
  };
  float* feat  = (float*)alloc((size_t)B * 512 * N * 4);   // 67.1MB; fusion: bf16 h overlay
  int*   idx   = (int*)  alloc((size_t)B * N * 9 * 4);
  int*   cand  = (int*)  alloc((size_t)B * N * 64 * 4);
  float* xxg   = (float*)alloc((size_t)B * N * 4);
  float* u     = (float*)alloc((size_t)B * N * 256 * 4);
  float* v     = (float*)alloc((size_t)B * N * 256 * 4);
  float* hmax  = (float*)alloc((size_t)B * N * 256 * 4);
  float* hmin  = (float*)alloc((size_t)B * N * 256 * 4);
  ushort* packR = (ushort*)u;
  ushort* packC = (ushort*)hmax;
  float*  xpm   = hmin;
  ushort* packB = (ushort*)u;
  ushort* hbf   = (ushort*)feat;
  float*  ps1   = hmin;
  float*  ps2   = hmin + 1048576;
  float* At    = (float*)alloc(128 * 256 * 4);
  float* W2t   = (float*)alloc(128 * 256 * 4);
  ushort* packW = (ushort*)alloc((size_t)32 * 96 * 512 * 2);
  double* S1   = (double*)alloc(1024 * 8);
  double* S2   = (double*)alloc(1024 * 8);
  float* scale = (float*)alloc(1024 * 4);
  float* shift = (float*)alloc(1024 * 4);
  float* x1x2  = (float*)alloc((size_t)B * 2048 * 4);
  float* h1    = (float*)alloc((size_t)B * 512 * 4);
  float* h2    = (float*)alloc((size_t)B * 256 * 4);

  dim3 gpack(N / 32, B);
  dim3 gknn4(N / 128, B, 4);
  dim3 gknn2(N / 128, B, 2);
  dim3 grr40(N / 8, B);
  dim3 grr20(N / 16, B);
  dim3 gxx(N / 256, B);

  pack3_wf<<<32, 256, 0, stream>>>(wf, packW);

  auto edge = [&](const float* inp, long in_bstride, int Cin, int O, const float* W,
                  const float* g, const float* beta, int c0) {
    prep_wt<<<(O * Cin + 255) / 256, 256, 0, stream>>>(W, Cin, O, At, W2t);
    dim3 gg(N / 64, O / 64, B);
    gemm_cn_no<<<gg, 256, 0, stream>>>(At, Cin, O, inp, in_bstride, N, u);
    gemm_cn_no<<<gg, 256, 0, stream>>>(W2t, Cin, O, inp, in_bstride, N, v);
    hipMemsetAsync(S1, 0, O * 8, stream);
    hipMemsetAsync(S2, 0, O * 8, stream);
    edge_pass<<<gg, 256, 0, stream>>>(u, v, idx, O, N, hmax, hmin, S1, S2);
    finalize_scale<<<(O + 255) / 256, 256, 0, stream>>>(S1, S2, g, beta,
                                                        1.0 / ((double)B * N * 9), O, scale, shift);
    edge_out<<<dim3(N / 64, B), 256, 0, stream>>>(hmax, hmin, scale, shift, O, N,
                                                  feat + (long)c0 * N, (long)512 * N);
  };

  xx_kernel<3><<<gxx, 256, 0, stream>>>(x, (long)3 * N, N, xxg);
  pack3_kernel<3, 1><<<gpack, 256, 0, stream>>>(x, (long)3 * N, N, xxg, packR, packC, xpm);
  knn_v5<1, 4, 4><<<gknn4, 256, 0, stream>>>(packR, packC, xxg, N, cand);
  rerank_kernel<3, 40><<<grr40, 320, 0, stream>>>(xpm, N, xxg, cand, idx);
  edge(x, (long)3 * N, 3, 64, w1, g1, b1, 0);

  xx_kernel<64><<<gxx, 256, 0, stream>>>(feat, (long)512 * N, N, xxg);
  pack3_kernel<64, 13><<<gpack, 256, 0, stream>>>(feat, (long)512 * N, N, xxg, packR, packC, xpm);
  knn_v5<13, 3, 4><<<gknn4, 256, 0, stream>>>(packR, packC, xxg, N, cand);
  rerank_kernel<64, 40><<<grr40, 320, 0, stream>>>(xpm, N, xxg, cand, idx);
  edge(feat, (long)512 * N, 64, 64, w2, g2, b2, 64);

  xx_kernel<64><<<gxx, 256, 0, stream>>>(feat + (long)64 * N, (long)512 * N, N, xxg);
  pack3_kernel<64, 13><<<gpack, 256, 0, stream>>>(feat + (long)64 * N, (long)512 * N, N, xxg,
                                                  packR, packC, xpm);
  knn_v5<13, 3, 4><<<gknn4, 256, 0, stream>>>(packR, packC, xxg, N, cand);
  rerank_kernel<64, 40><<<grr40, 320, 0, stream>>>(xpm, N, xxg, cand, idx);
  edge(feat + (long)64 * N, (long)512 * N, 64, 128, w3, g3, b3, 128);

  xx_kernel<128><<<gxx, 256, 0, stream>>>(feat + (long)128 * N, (long)512 * N, N, xxg);
  pack3_kernel<128, 25><<<gpack, 256, 0, stream>>>(feat + (long)128 * N, (long)512 * N, N, xxg,
                                                   packR, packC, xpm);
  knn_v5<25, 3, 2><<<gknn2, 256, 0, stream>>>(packR, packC, xxg, N, cand);
  rerank_kernel<128, 20><<<grr20, 320, 0, stream>>>(xpm, N, xxg, cand, idx);
  edge(feat + (long)128 * N, (long)512 * N, 128, 256, w4, g4, b4, 256);

  // fusion conv 512->1024: single MFMA pass (stats + bf16 h), then pool sweep
  pack3_feat<<<dim3(N / 32, B), 256, 0, stream>>>(feat, N, packB);
  dim3 gfu(N / 32, 2, B);
  fusion_gemm_store<<<gfu, 256, 0, stream>>>(packW, packB, bfv, N, hbf, ps1, ps2);
  finalize_fusion<<<4, 256, 0, stream>>>(ps1, ps2, gf, betaf, scale, shift);
  pool_bf16<<<2048, 256, 0, stream>>>(hbf, scale, shift, x1x2);

  fc_kernel<<<16, 256, 0, stream>>>(x1x2, 2048, 512, wc1, bc1, gc1, betac1, h1, 1);
  fc_kernel<<<8, 256, 0, stream>>>(h1, 512, 256, wc2, bc2, gc2, betac2, h2, 1);
  fc_kernel<<<2, 256, 0, stream>>>(h2, 256, 40, wc3, bc3, nullptr, nullptr, (float*)d_out, 0);
}